// Round 9
// baseline (596.577 us; speedup 1.0000x reference)
//
#include <hip/hip_runtime.h>

#define NN 20000
#define TT 2
#define HH 128
#define LL 4
#define EE 320000
#define FF 514
#define CN 3
#define CG 2
#define MP 20096  // rows per ti-half, padded to multiple of 128

typedef __bf16 bf16x8 __attribute__((ext_vector_type(8)));
typedef __bf16 bf16x4 __attribute__((ext_vector_type(4)));
typedef __bf16 bf16x2 __attribute__((ext_vector_type(2)));
typedef float f32x4 __attribute__((ext_vector_type(4)));

struct __align__(16) Edge16 { int src; float ea0, ea1; int pad; };

// ---------------- wave helpers ----------------
__device__ inline float wave_sum(float v) {
#pragma unroll
  for (int off = 32; off; off >>= 1) v += __shfl_xor(v, off);
  return v;
}
__device__ inline float red16(float v) {  // reduce across fr = lane&15
  v += __shfl_xor(v, 1); v += __shfl_xor(v, 2);
  v += __shfl_xor(v, 4); v += __shfl_xor(v, 8);
  return v;
}

__device__ __forceinline__ float fexp2(float x) {
#if __has_builtin(__builtin_amdgcn_exp2f)
  return __builtin_amdgcn_exp2f(x);
#else
  return exp2f(x);
#endif
}

__device__ __forceinline__ void gload_lds16(const void* g, void* l) {
  __builtin_amdgcn_global_load_lds(
      (const __attribute__((address_space(1))) unsigned int*)g,
      (__attribute__((address_space(3))) unsigned int*)l, 16, 0, 0);
}

// ---------------- fused encoder GEMM + XCD-routed edge scatter --------------
#define ENCB (MP / 64)
#define SCB 2500
#define CHUNK 5000  // 2*NN/8 gnodes per XCD chunk
__global__ __launch_bounds__(256) void enc_scatter_kernel(
    const __bf16* __restrict__ A, const __bf16* __restrict__ BT,
    const float* __restrict__ bias, float* __restrict__ C,
    const int* __restrict__ edge_index, const float* __restrict__ edge_attr,
    int* __restrict__ cursor, Edge16* __restrict__ edges) {
  __shared__ __bf16 As[2][64][32];
  __shared__ __bf16 Bs[2][128][32];
  const int tid = threadIdx.x;
  if (blockIdx.x >= ENCB) {
    int chunk = blockIdx.x & 7;
    int i = ((blockIdx.x - ENCB) >> 3) * 256 + tid;
    if (i >= 2 * EE) return;
    int ti = (i >= EE) ? 1 : 0;
    int e = i - ti * EE;
    const int* srcp = edge_index + (size_t)ti * 2 * EE;
    int d = srcp[EE + e];
    int gnode = ti * NN + d;
    if (gnode / CHUNK != chunk) return;
    int s = srcp[e];
    float2 ea = ((const float2*)edge_attr)[(size_t)ti * EE + e];
    int pos = atomicAdd(&cursor[gnode], 1);
    Edge16 ed;
    ed.src = s + ti * MP;
    ed.ea0 = ea.x; ed.ea1 = ea.y; ed.pad = 0;
    __builtin_memcpy(&edges[pos], &ed, sizeof(Edge16));
    return;
  }
  const int K = 576;
  const int lane = tid & 63, w = tid >> 6;
  const int bm = blockIdx.x * 64;
  const int wr = (w >> 1) * 32, wc = (w & 1) * 64;
  const int fr = lane & 15, fq = lane >> 4;
  const int rowA = tid >> 2, chA = (tid & 3) * 8;
  const __bf16* Ab = A + (size_t)(bm + rowA) * K + chA;
  const __bf16* Bb = BT + (size_t)rowA * K + chA;
  const __bf16* Bb2 = Bb + (size_t)64 * K;
  f32x4 acc[2][4] = {};
#define STAGE(buf, k0)                                  \
  do {                                                  \
    gload_lds16(Ab + (k0), &As[buf][rowA][chA]);        \
    gload_lds16(Bb + (k0), &Bs[buf][rowA][chA]);        \
    gload_lds16(Bb2 + (k0), &Bs[buf][rowA + 64][chA]);  \
  } while (0)
  STAGE(0, 0);
  __syncthreads();
  int cur = 0;
  for (int k0 = 0; k0 < K; k0 += 32) {
    if (k0 + 32 < K) STAGE(cur ^ 1, k0 + 32);
    bf16x8 af[2], bq[4];
#pragma unroll
    for (int m = 0; m < 2; ++m)
      af[m] = *(const bf16x8*)&As[cur][wr + m * 16 + fr][fq * 8];
#pragma unroll
    for (int n = 0; n < 4; ++n)
      bq[n] = *(const bf16x8*)&Bs[cur][wc + n * 16 + fr][fq * 8];
#pragma unroll
    for (int m = 0; m < 2; ++m)
#pragma unroll
      for (int n = 0; n < 4; ++n)
        acc[m][n] =
            __builtin_amdgcn_mfma_f32_16x16x32_bf16(af[m], bq[n], acc[m][n], 0, 0, 0);
    __syncthreads();
    cur ^= 1;
  }
#undef STAGE
#pragma unroll
  for (int m = 0; m < 2; ++m) {
#pragma unroll
    for (int n = 0; n < 4; ++n) {
#pragma unroll
      for (int j = 0; j < 4; ++j) {
        int gm = bm + wr + m * 16 + fq * 4 + j;
        int gn = wc + n * 16 + fr;
        if (gm < NN) {
          float c = acc[m][n][j] + bias[gn];
          C[(size_t)gm * 128 + gn] = c;
          C[(size_t)(gm + MP) * 128 + gn] = c;
        }
      }
    }
  }
}

// ---------------- fused 256-wide GEMM (BM=64, BN=256, full row per wave) ----
template <int EPI>
__global__ __launch_bounds__(256) void gemm256(
    const __bf16* __restrict__ A, const __bf16* __restrict__ BT,
    const float* __restrict__ bias, const float* __restrict__ g,
    const float* __restrict__ be, const float* __restrict__ W2h,
    const float* __restrict__ b2h, void* __restrict__ outp, int M, int K) {
  __shared__ __bf16 As[2][64][32];
  __shared__ __bf16 Bs[2][256][32];
  const int tid = threadIdx.x;
  const int lane = tid & 63, w = tid >> 6;
  const int bm = blockIdx.x * 64;
  const int wr = w * 16;
  const int fr = lane & 15, fq = lane >> 4;
  const int rowA = tid >> 2, chA = (tid & 3) * 8;
  const __bf16* Ab = A + (size_t)(bm + rowA) * K + chA;
  const __bf16* Bb = BT + (size_t)rowA * K + chA;
  f32x4 acc[16] = {};

#define STG(buf, k0)                                                \
  do {                                                              \
    gload_lds16(Ab + (k0), &As[buf][rowA][chA]);                    \
    _Pragma("unroll") for (int r = 0; r < 4; ++r)                   \
        gload_lds16(Bb + (size_t)(r * 64) * K + (k0),               \
                    &Bs[buf][rowA + r * 64][chA]);                  \
  } while (0)

  STG(0, 0);
  __syncthreads();
  int cur = 0;
  for (int k0 = 0; k0 < K; k0 += 32) {
    if (k0 + 32 < K) STG(cur ^ 1, k0 + 32);
    bf16x8 af = *(const bf16x8*)&As[cur][wr + fr][fq * 8];
#pragma unroll
    for (int n = 0; n < 16; ++n) {
      bf16x8 bq = *(const bf16x8*)&Bs[cur][n * 16 + fr][fq * 8];
      acc[n] = __builtin_amdgcn_mfma_f32_16x16x32_bf16(af, bq, acc[n], 0, 0, 0);
    }
    __syncthreads();
    cur ^= 1;
  }
#undef STG

  float cb[16];
#pragma unroll
  for (int n = 0; n < 16; ++n) cb[n] = bias[n * 16 + fr];

  if constexpr (EPI == 0) {
    float gv[16], bev[16];
#pragma unroll
    for (int n = 0; n < 16; ++n) {
      gv[n] = g[n * 16 + fr];
      bev[n] = be[n * 16 + fr];
    }
    __bf16* outb = (__bf16*)outp;
#pragma unroll
    for (int j = 0; j < 4; ++j) {
      float cj[16], s = 0.f, s2 = 0.f;
#pragma unroll
      for (int n = 0; n < 16; ++n) {
        float c = acc[n][j] + cb[n];
        cj[n] = c; s += c; s2 += c * c;
      }
      s = red16(s); s2 = red16(s2);
      float mu = s * (1.f / 256);
      float var = fmaxf(s2 * (1.f / 256) - mu * mu, 0.f);
      float rr = rsqrtf(var + 1e-5f);
      int gm = bm + wr + fq * 4 + j;
      __bf16* op = outb + (size_t)gm * 256;
#pragma unroll
      for (int n = 0; n < 16; ++n) {
        float y = (cj[n] - mu) * rr * gv[n] + bev[n];
        op[n * 16 + fr] = (__bf16)fmaxf(y, 0.f);
      }
    }
  } else {
    float w0[16], w1[16], w2[16];
#pragma unroll
    for (int n = 0; n < 16; ++n) {
      int col = n * 16 + fr;
      w0[n] = W2h[col * 3 + 0];
      w1[n] = W2h[col * 3 + 1];
      w2[n] = W2h[col * 3 + 2];
    }
    float* outf = (float*)outp;
#pragma unroll
    for (int j = 0; j < 4; ++j) {
      float p0 = 0.f, p1 = 0.f, p2 = 0.f;
#pragma unroll
      for (int n = 0; n < 16; ++n) {
        float h = fmaxf(acc[n][j] + cb[n], 0.f);
        p0 += h * w0[n]; p1 += h * w1[n]; p2 += h * w2[n];
      }
      p0 = red16(p0); p1 = red16(p1); p2 = red16(p2);
      int gm = bm + wr + fq * 4 + j;
      if (fr == 0 && gm < M) {
        float l0 = p0 + b2h[0], l1 = p1 + b2h[1], l2 = p2 + b2h[2];
        float m = fmaxf(l0, fmaxf(l1, l2));
        float lse = m + logf(__expf(l0 - m) + __expf(l1 - m) + __expf(l2 - m));
        outf[(size_t)gm * 3 + 0] = l0 - lse;
        outf[(size_t)gm * 3 + 1] = l1 - lse;
        outf[(size_t)gm * 3 + 2] = l2 - lse;
      }
    }
  }
}

// ---------------- lin2 GEMM + residual + fused LayerNorm+ReLU --------------
// MODE 0: write xres (no add) + LN->relu->f32 hb      (layer 0)
// MODE 1: add xres, write xres + LN->relu->f32 hb     (layers 1..L-2)
// MODE 2: add xres, LN->relu->f32 emb[node*256+half*128+col] (last layer)
template <int MODE>
__global__ __launch_bounds__(256) void gemm_lin2(
    const __bf16* __restrict__ A, const __bf16* __restrict__ BT,
    const float* __restrict__ bias, float* __restrict__ xres,
    const float* __restrict__ g, const float* __restrict__ be,
    float* __restrict__ lnout) {
  __shared__ __bf16 As[2][64][32];
  __shared__ __bf16 Bs[2][128][32];
  __shared__ float redS[64][2], redS2[64][2];
  const int tid = threadIdx.x;
  const int lane = tid & 63, w = tid >> 6;
  const int bm = blockIdx.x * 64;
  const int wr = (w >> 1) * 32, wc = (w & 1) * 64;
  const int fr = lane & 15, fq = lane >> 4;
  const int rowA = tid >> 2, chA = (tid & 3) * 8;
  const __bf16* Ab = A + (size_t)(bm + rowA) * 256 + chA;
  const __bf16* Bb = BT + (size_t)rowA * 256 + chA;
  const __bf16* Bb2 = Bb + (size_t)64 * 256;
  f32x4 acc[2][4] = {};

#define STAGE(buf, k0)                                  \
  do {                                                  \
    gload_lds16(Ab + (k0), &As[buf][rowA][chA]);        \
    gload_lds16(Bb + (k0), &Bs[buf][rowA][chA]);        \
    gload_lds16(Bb2 + (k0), &Bs[buf][rowA + 64][chA]);  \
  } while (0)

  STAGE(0, 0);
  __syncthreads();
  int cur = 0;
  for (int k0 = 0; k0 < 256; k0 += 32) {
    if (k0 + 32 < 256) STAGE(cur ^ 1, k0 + 32);
    bf16x8 af[2], bq[4];
#pragma unroll
    for (int m = 0; m < 2; ++m)
      af[m] = *(const bf16x8*)&As[cur][wr + m * 16 + fr][fq * 8];
#pragma unroll
    for (int n = 0; n < 4; ++n)
      bq[n] = *(const bf16x8*)&Bs[cur][wc + n * 16 + fr][fq * 8];
#pragma unroll
    for (int m = 0; m < 2; ++m)
#pragma unroll
      for (int n = 0; n < 4; ++n)
        acc[m][n] =
            __builtin_amdgcn_mfma_f32_16x16x32_bf16(af[m], bq[n], acc[m][n], 0, 0, 0);
    __syncthreads();
    cur ^= 1;
  }
#undef STAGE

  float cv[2][4][4];
#pragma unroll
  for (int m = 0; m < 2; ++m) {
    int r0 = wr + m * 16 + fq * 4;
#pragma unroll
    for (int j = 0; j < 4; ++j) {
      int gm = bm + r0 + j;
      float s = 0.f, s2 = 0.f;
#pragma unroll
      for (int n = 0; n < 4; ++n) {
        float c = acc[m][n][j] + bias[wc + n * 16 + fr];
        if (MODE != 0) c += xres[(size_t)gm * 128 + wc + n * 16 + fr];
        cv[m][n][j] = c;
        s += c; s2 += c * c;
      }
      s = red16(s); s2 = red16(s2);
      if (fr == 0) {
        redS[r0 + j][w & 1] = s;
        redS2[r0 + j][w & 1] = s2;
      }
    }
  }
  __syncthreads();
#pragma unroll
  for (int m = 0; m < 2; ++m) {
    int r0 = wr + m * 16 + fq * 4;
#pragma unroll
    for (int j = 0; j < 4; ++j) {
      int r = r0 + j;
      int gm = bm + r;
      float S = redS[r][0] + redS[r][1];
      float S2 = redS2[r][0] + redS2[r][1];
      float mu = S * (1.f / 128);
      float var = fmaxf(S2 * (1.f / 128) - mu * mu, 0.f);
      float rr = rsqrtf(var + 1e-5f);
      if constexpr (MODE < 2) {
        float* xp = xres + (size_t)gm * 128;
        float* hp = lnout + (size_t)gm * 128;
#pragma unroll
        for (int n = 0; n < 4; ++n) {
          int col = wc + n * 16 + fr;
          float c = cv[m][n][j];
          xp[col] = c;
          float y = (c - mu) * rr * g[col] + be[col];
          hp[col] = fmaxf(y, 0.f);
        }
      } else {
        int half = gm >= MP;
        int node = gm - half * MP;
        if (node < NN) {
          float* ep = lnout + (size_t)node * 256 + half * 128;
#pragma unroll
          for (int n = 0; n < 4; ++n) {
            int col = wc + n * 16 + fr;
            float y = (cv[m][n][j] - mu) * rr * g[col] + be[col];
            ep[col] = fmaxf(y, 0.f);
          }
        }
      }
    }
  }
}

// ---------------- fused prologue (vectorized) -------------------------------
struct WtDesc { const float* src; __bf16* dst; int K, N, Kpad; };
struct WtDescs { WtDesc d[10]; };
#define NF2B 20079  // ceil(NN*FF/2 / 256)
#define PADB 2422   // ceil(NN*31 / 256)
#define WTB 2880
#define CNTB 2500

__global__ void prep_kernel(const float* __restrict__ nf_src,
                            __bf16* __restrict__ nf_dst, WtDescs descs,
                            const int* __restrict__ edge_index,
                            int* __restrict__ deg, float* __restrict__ gp_sum) {
  int b = blockIdx.x, tid = threadIdx.x;
  if (b < NF2B) {
    int i = b * 256 + tid;  // float2 index
    if (i >= NN * FF / 2) return;
    int row = i / 257;
    int col = (i - row * 257) * 2;
    float2 v = ((const float2*)nf_src)[i];
    bf16x2 o; o[0] = (__bf16)v.x; o[1] = (__bf16)v.y;
    *(bf16x2*)(nf_dst + (size_t)row * 576 + col) = o;
  } else if (b < NF2B + PADB) {
    int i = (b - NF2B) * 256 + tid;
    if (i >= NN * 31) return;
    int row = i / 31, j = i - row * 31;
    bf16x2 z; z[0] = (__bf16)0.f; z[1] = (__bf16)0.f;
    *(bf16x2*)(nf_dst + (size_t)row * 576 + 514 + 2 * j) = z;
  } else if (b < NF2B + PADB + WTB) {
    int wb = b - NF2B - PADB;
    WtDesc de = descs.d[wb / 288];
    int idx = (wb % 288) * 256 + tid;
    if (idx >= de.N * de.Kpad) return;
    int n = idx / de.Kpad, k = idx - n * de.Kpad;
    float v = (k < de.K) ? de.src[(size_t)k * de.N + n] : 0.f;
    de.dst[idx] = (__bf16)v;
  } else if (b < NF2B + PADB + WTB + CNTB) {
    int i = (b - NF2B - PADB - WTB) * 256 + tid;
    if (i >= 2 * EE) return;
    int ti = (i >= EE) ? 1 : 0;
    int e = i - ti * EE;
    int d = edge_index[(size_t)ti * 2 * EE + EE + e];
    atomicAdd(&deg[ti * NN + d], 1);
  } else {
    gp_sum[tid] = 0.f;
  }
}

// ---------------- CSR scan (block per ti) ----------------
__global__ __launch_bounds__(1024) void scan2_kernel(
    const int* __restrict__ deg_all, int* __restrict__ rowptr,
    int* __restrict__ cursor) {
  const int ti = blockIdx.x;
  const int* deg = deg_all + ti * NN;
  __shared__ int sums[1024];
  int tid = threadIdx.x;
  int chunk = (NN + 1023) / 1024;
  int begin = tid * chunk, end = min(begin + chunk, NN);
  int s = 0;
  for (int i = begin; i < end; ++i) s += deg[i];
  sums[tid] = s;
  __syncthreads();
  for (int off = 1; off < 1024; off <<= 1) {
    int v = (tid >= off) ? sums[tid - off] : 0;
    __syncthreads();
    sums[tid] += v;
    __syncthreads();
  }
  int running = ti * EE + sums[tid] - s;
  for (int i = begin; i < end; ++i) {
    rowptr[ti * NN + i] = running;
    cursor[ti * NN + i] = running;
    running += deg[i];
  }
  if (tid == 0 && ti == 1) rowptr[2 * NN] = 2 * EE;
}

// ---------------- GENConv softmax aggregation + residual -------------------
// 8 quadrant-groups g = ti*4 + ch-quarter -> XCD g (per-XCD x slice 2.57 MB
// < 4 MB L2). 8 lanes/edge x float4 (f32 xin, no converts); 8 edges in
// flight per wave; pre-scaled weights fold t and log2e into the fma chain.
__global__ __launch_bounds__(256) void agg_kernel(
    const float* __restrict__ xin, const int* __restrict__ rowptr,
    const Edge16* __restrict__ edges, const float* __restrict__ Wee,
    const float* __restrict__ bee, const float* __restrict__ tptr, int layer,
    __bf16* __restrict__ out) {
  int wave = threadIdx.x >> 6, lane = threadIdx.x & 63;
  int b = blockIdx.x;  // 40000 blocks
  int g8 = b & 7;
  int ti = g8 >> 2, cq = g8 & 3;
  int node = (b >> 3) * 4 + wave;  // 0..19999
  int gnode = ti * NN + node;
  int xrow = ti * MP + node;
  float t = tptr[layer];
  float t2 = t * 1.4426950408889634f;
  int slot = lane >> 3, cl = lane & 7;  // 8 edge-slots x 8 ch-lanes
  int c0 = cq * 32 + cl * 4;
  float den[4] = {}, num[4] = {};
  int e = rowptr[gnode];
  const int e1 = rowptr[gnode + 1];

  if (t2 > 0.f) {
    float w0p[4], w1p[4], bvp[4];
#pragma unroll
    for (int i = 0; i < 4; ++i) {
      w0p[i] = Wee[c0 + i] * t2;
      w1p[i] = Wee[HH + c0 + i] * t2;
      bvp[i] = bee[c0 + i] * t2;
    }
#define MLPF(E)                                                         \
  do {                                                                  \
    f32x4 xv = *(const f32x4*)(xin + (size_t)(E).src * HH + c0);        \
    _Pragma("unroll") for (int i = 0; i < 4; ++i) {                     \
      float te = fmaf((E).ea0, w0p[i], fmaf((E).ea1, w1p[i], bvp[i]));  \
      float sm = fmaxf(fmaf(xv[i], t2, te), 0.f);                       \
      float ex = fexp2(sm);                                             \
      den[i] += ex; num[i] += sm * ex;                                  \
    }                                                                   \
  } while (0)
    for (; e + 8 <= e1; e += 8) {
      Edge16 E = edges[e + slot];
      MLPF(E);
    }
    if (e + slot < e1) {
      Edge16 E = edges[e + slot];
      MLPF(E);
    }
#undef MLPF
    // num here is sum sm*ex = t2 * sum m*ex; fold 1/t2 into the divide below.
#pragma unroll
    for (int i = 0; i < 4; ++i) {
      den[i] += __shfl_xor(den[i], 8);
      den[i] += __shfl_xor(den[i], 16);
      den[i] += __shfl_xor(den[i], 32);
      num[i] += __shfl_xor(num[i], 8);
      num[i] += __shfl_xor(num[i], 16);
      num[i] += __shfl_xor(num[i], 32);
    }
    if (slot == 0) {
      f32x4 xr = *(const f32x4*)(xin + (size_t)xrow * HH + c0);
      bf16x4 o;
#pragma unroll
      for (int i = 0; i < 4; ++i)
        o[i] = (__bf16)(num[i] / (t2 * (den[i] + 1e-16f)) + xr[i]);
      *(bf16x4*)(out + (size_t)xrow * HH + c0) = o;
    }
  } else {
    // general (t2 <= 0) fallback: reference formula per edge
    float w0[4], w1[4], bv[4];
#pragma unroll
    for (int i = 0; i < 4; ++i) {
      w0[i] = Wee[c0 + i];
      w1[i] = Wee[HH + c0 + i];
      bv[i] = bee[c0 + i];
    }
    for (; e + slot < e1; e += 8) {
      Edge16 E = edges[e + slot];
      f32x4 xv = *(const f32x4*)(xin + (size_t)E.src * HH + c0);
#pragma unroll
      for (int i = 0; i < 4; ++i) {
        float m = fmaxf(xv[i] + E.ea0 * w0[i] + E.ea1 * w1[i] + bv[i], 0.f) + 1e-7f;
        float ex = fexp2(m * t2);
        den[i] += ex; num[i] += m * ex;
      }
    }
#pragma unroll
    for (int i = 0; i < 4; ++i) {
      den[i] += __shfl_xor(den[i], 8);
      den[i] += __shfl_xor(den[i], 16);
      den[i] += __shfl_xor(den[i], 32);
      num[i] += __shfl_xor(num[i], 8);
      num[i] += __shfl_xor(num[i], 16);
      num[i] += __shfl_xor(num[i], 32);
    }
    if (slot == 0) {
      f32x4 xr = *(const f32x4*)(xin + (size_t)xrow * HH + c0);
      bf16x4 o;
#pragma unroll
      for (int i = 0; i < 4; ++i)
        o[i] = (__bf16)(num[i] / (den[i] + 1e-16f) + xr[i]);
      *(bf16x4*)(out + (size_t)xrow * HH + c0) = o;
    }
  }
}

// ---------------- fused channel attention (node out + graph partial-pool) --
__global__ __launch_bounds__(256) void attn2_kernel(
    const float* __restrict__ emb, const float* __restrict__ Wq_n,
    const float* __restrict__ Wk_n, const float* __restrict__ Wv_n,
    const float* __restrict__ gn, const float* __restrict__ Wq_g,
    const float* __restrict__ Wk_g, const float* __restrict__ Wv_g,
    const float* __restrict__ gg, __bf16* __restrict__ outn,
    float* __restrict__ partial) {
  __shared__ float gsum[4][256];
  int wave = threadIdx.x >> 6, lane = threadIdx.x & 63;
  int tid = threadIdx.x;
  int n = blockIdx.x * 4 + wave;  // NN % 4 == 0: always valid
  int c0 = lane * 2;
  const float* base = emb + (size_t)n * (2 * HH);
  float2 x0 = *(const float2*)(base + c0);
  float2 x1 = *(const float2*)(base + HH + c0);

#define ATTN_BODY(Wq, Wk, Wv, GAM, O0A, O0B, O1A, O1B)                        \
  {                                                                           \
    float gamma = *(GAM);                                                     \
    float wq00 = Wq[0], wq01 = Wq[1], wq10 = Wq[2], wq11 = Wq[3];             \
    float wk00 = Wk[0], wk01 = Wk[1], wk10 = Wk[2], wk11 = Wk[3];             \
    float wv00 = Wv[0], wv01 = Wv[1], wv10 = Wv[2], wv11 = Wv[3];             \
    float q0a = wq00 * x0.x + wq01 * x1.x, q0b = wq00 * x0.y + wq01 * x1.y;   \
    float q1a = wq10 * x0.x + wq11 * x1.x, q1b = wq10 * x0.y + wq11 * x1.y;   \
    float k0a = wk00 * x0.x + wk01 * x1.x, k0b = wk00 * x0.y + wk01 * x1.y;   \
    float k1a = wk10 * x0.x + wk11 * x1.x, k1b = wk10 * x0.y + wk11 * x1.y;   \
    float v0a = wv00 * x0.x + wv01 * x1.x, v0b = wv00 * x0.y + wv01 * x1.y;   \
    float v1a = wv10 * x0.x + wv11 * x1.x, v1b = wv10 * x0.y + wv11 * x1.y;   \
    float s00 = wave_sum(q0a * k0a + q0b * k0b);                              \
    float s01 = wave_sum(q0a * k1a + q0b * k1b);                              \
    float s10 = wave_sum(q1a * k0a + q1b * k0b);                              \
    float s11 = wave_sum(q1a * k1a + q1b * k1b);                              \
    float m0 = fmaxf(s00, s01);                                               \
    float e00 = __expf(s00 - m0), e01 = __expf(s01 - m0);                     \
    float i0 = 1.f / (e00 + e01);                                             \
    float a00 = e00 * i0, a01 = e01 * i0;                                     \
    float m1 = fmaxf(s10, s11);                                               \
    float e10 = __expf(s10 - m1), e11 = __expf(s11 - m1);                     \
    float i1 = 1.f / (e10 + e11);                                             \
    float a10 = e10 * i1, a11 = e11 * i1;                                     \
    O0A = gamma * (a00 * v0a + a01 * v1a) + x0.x;                             \
    O0B = gamma * (a00 * v0b + a01 * v1b) + x0.y;                             \
    O1A = gamma * (a10 * v0a + a11 * v1a) + x1.x;                             \
    O1B = gamma * (a10 * v0b + a11 * v1b) + x1.y;                             \
  }

  float n0a, n0b, n1a, n1b;
  ATTN_BODY(Wq_n, Wk_n, Wv_n, gn, n0a, n0b, n1a, n1b);
  __bf16* opn = outn + (size_t)n * (2 * HH);
  bf16x2 t0; t0[0] = (__bf16)n0a; t0[1] = (__bf16)n0b;
  bf16x2 t1; t1[0] = (__bf16)n1a; t1[1] = (__bf16)n1b;
  *(bf16x2*)(opn + c0) = t0;
  *(bf16x2*)(opn + HH + c0) = t1;

  float g0a, g0b, g1a, g1b;
  ATTN_BODY(Wq_g, Wk_g, Wv_g, gg, g0a, g0b, g1a, g1b);
  gsum[wave][c0] = g0a;
  gsum[wave][c0 + 1] = g0b;
  gsum[wave][128 + c0] = g1a;
  gsum[wave][129 + c0] = g1b;
  __syncthreads();
  partial[(size_t)blockIdx.x * 256 + tid] =
      gsum[0][tid] + gsum[1][tid] + gsum[2][tid] + gsum[3][tid];
#undef ATTN_BODY
}

// ---------------- pool over per-block partials ----------------
__global__ __launch_bounds__(256) void pool_kernel(const float* __restrict__ partial,
                                                   float* __restrict__ gp_sum,
                                                   int nRows) {
  int c = threadIdx.x;
  float s = 0.f;
  for (int r = blockIdx.x; r < nRows; r += gridDim.x)
    s += partial[(size_t)r * 256 + c];
  atomicAdd(&gp_sum[c], s);
}

// ---------------- graph head (single block) ----------------
__global__ __launch_bounds__(256) void graph_head_kernel(
    const float* __restrict__ gp_sum, const float* __restrict__ Wg1,
    const float* __restrict__ bg1, const float* __restrict__ Wg2,
    const float* __restrict__ bg2, float* __restrict__ outp, float invN) {
  __shared__ float gp[256];
  __shared__ float h1[256];
  __shared__ float lg[2];
  int tid = threadIdx.x;
  gp[tid] = gp_sum[tid] * invN;
  __syncthreads();
  float acc = bg1[tid];
  for (int k = 0; k < 256; ++k) acc += gp[k] * Wg1[k * 256 + tid];
  h1[tid] = fmaxf(acc, 0.f);
  __syncthreads();
  if (tid < 2) {
    float l = bg2[tid];
    for (int c = 0; c < 256; ++c) l += h1[c] * Wg2[c * 2 + tid];
    lg[tid] = l;
  }
  __syncthreads();
  if (tid == 0) {
    float m = fmaxf(lg[0], lg[1]);
    float lse = m + logf(__expf(lg[0] - m) + __expf(lg[1] - m));
    outp[0] = lg[0] - lse;
    outp[1] = lg[1] - lse;
  }
}

// ---------------- launch ----------------
extern "C" void kernel_launch(void* const* d_in, const int* in_sizes, int n_in,
                              void* d_out, int out_size, void* d_ws, size_t ws_size,
                              hipStream_t stream) {
  (void)in_sizes; (void)n_in; (void)out_size; (void)ws_size;
  const float* node_feature = (const float*)d_in[0];
  const int* edge_index = (const int*)d_in[1];
  const float* edge_attr = (const float*)d_in[2];
  const float* Wne = (const float*)d_in[3];
  const float* bne = (const float*)d_in[4];
  const float* Wee = (const float*)d_in[5];
  const float* bee = (const float*)d_in[6];
  const float* W1 = (const float*)d_in[7];
  const float* b1 = (const float*)d_in[8];
  const float* g1 = (const float*)d_in[9];
  const float* be1 = (const float*)d_in[10];
  const float* W2 = (const float*)d_in[11];
  const float* b2 = (const float*)d_in[12];
  const float* dg = (const float*)d_in[13];
  const float* db = (const float*)d_in[14];
  const float* tpar = (const float*)d_in[15];
  const float* Wq_n = (const float*)d_in[16];
  const float* Wk_n = (const float*)d_in[17];
  const float* Wv_n = (const float*)d_in[18];
  const float* gamma_n = (const float*)d_in[19];
  const float* Wn1 = (const float*)d_in[20];
  const float* bn1 = (const float*)d_in[21];
  const float* Wn2 = (const float*)d_in[22];
  const float* bn2 = (const float*)d_in[23];
  const float* Wq_g = (const float*)d_in[24];
  const float* Wk_g = (const float*)d_in[25];
  const float* Wv_g = (const float*)d_in[26];
  const float* gamma_g = (const float*)d_in[27];
  const float* Wg1 = (const float*)d_in[28];
  const float* bg1 = (const float*)d_in[29];
  const float* Wg2 = (const float*)d_in[30];
  const float* bg2 = (const float*)d_in[31];
  float* out = (float*)d_out;

  // ---- workspace carve-out (256B-aligned regions) ----
  char* pc = (char*)d_ws;
  auto alloc = [&](size_t bytes) {
    char* r = pc;
    pc += (bytes + 255) & ~(size_t)255;
    return r;
  };
  float* xbuf = (float*)alloc((size_t)2 * MP * HH * 4);       // f32 residual
  float* hbuf = (float*)alloc((size_t)2 * MP * HH * 4);       // f32 LN'd agg in
  __bf16* t256_b = (__bf16*)alloc((size_t)2 * MP * 256 * 2);  // lin1+LN out
  float* emb = (float*)alloc((size_t)NN * 2 * HH * 4);        // [N,T,H] f32
  __bf16* aggout_b = (__bf16*)alloc((size_t)2 * MP * HH * 2); // agg out (bf16)
  __bf16* nf_b = (__bf16*)emb;  // 23.0MB <= emb(20.5)+aggout(10.3)
  __bf16* attnb = t256_b;       // alias: node-attn out (after last lin2)
  float* partial = xbuf;        // alias: graph-attn partials [5000][256]
  __bf16* wt_ne = (__bf16*)alloc((size_t)128 * 576 * 2);
  __bf16* wt1 = (__bf16*)alloc((size_t)4 * 256 * 128 * 2);
  __bf16* wt2 = (__bf16*)alloc((size_t)4 * 128 * 256 * 2);
  __bf16* wtn1 = (__bf16*)alloc((size_t)256 * 256 * 2);
  float* gp_sum = (float*)alloc(256 * 4);
  int* deg = (int*)alloc((size_t)2 * NN * 4);
  int* cursor = (int*)alloc((size_t)2 * NN * 4);
  int* rowptr = (int*)alloc((size_t)(2 * NN + 2) * 4);
  Edge16* edges = (Edge16*)alloc((size_t)2 * EE * 16);

  const int gRows2 = 2 * MP / 64;  // 628 row-blocks, stacked GEMMs

  WtDescs wd;
  wd.d[0] = {Wne, wt_ne, FF, HH, 576};
  for (int l = 0; l < 4; ++l)
    wd.d[1 + l] = {W1 + (size_t)l * HH * 256, wt1 + (size_t)l * 256 * HH, HH, 256, HH};
  for (int l = 0; l < 4; ++l)
    wd.d[5 + l] = {W2 + (size_t)l * 256 * HH, wt2 + (size_t)l * HH * 256, 256, HH, 256};
  wd.d[9] = {Wn1, wtn1, 256, 256, 256};

  // prologue: deg zero; converts (vectorized) + degree count + gp_sum zero
  hipMemsetAsync(deg, 0, 2 * NN * sizeof(int), stream);
  prep_kernel<<<NF2B + PADB + WTB + CNTB + 1, 256, 0, stream>>>(
      node_feature, nf_b, wd, edge_index, deg, gp_sum);
  scan2_kernel<<<2, 1024, 0, stream>>>(deg, rowptr, cursor);
  // encoder GEMM (dup to both halves, f32 out) fused with XCD-routed scatter
  enc_scatter_kernel<<<ENCB + 8 * SCB, 256, 0, stream>>>(
      nf_b, wt_ne, bne, hbuf, edge_index, edge_attr, cursor, edges);

  // layer loop, both ti at once
  for (int l = 0; l < LL; ++l) {
    agg_kernel<<<8 * (NN / 4), 256, 0, stream>>>(hbuf, rowptr, edges, Wee, bee,
                                                 tpar, l, aggout_b);
    gemm256<0><<<gRows2, 256, 0, stream>>>(aggout_b, wt1 + (size_t)l * 256 * HH,
                                           b1 + l * 2 * HH, g1 + l * 2 * HH,
                                           be1 + l * 2 * HH, nullptr, nullptr, t256_b,
                                           2 * MP, HH);
    const __bf16* w2l = wt2 + (size_t)l * HH * 256;
    const float* b2l = b2 + l * HH;
    if (l == 0)
      gemm_lin2<0><<<gRows2, 256, 0, stream>>>(t256_b, w2l, b2l, xbuf, dg + 1 * HH,
                                               db + 1 * HH, hbuf);
    else if (l < LL - 1)
      gemm_lin2<1><<<gRows2, 256, 0, stream>>>(t256_b, w2l, b2l, xbuf,
                                               dg + (l + 1) * HH, db + (l + 1) * HH,
                                               hbuf);
    else
      gemm_lin2<2><<<gRows2, 256, 0, stream>>>(t256_b, w2l, b2l, xbuf, dg, db, emb);
  }

  // fused node+graph attention (one emb read; graph branch -> LDS partials)
  attn2_kernel<<<NN / 4, 256, 0, stream>>>(emb, Wq_n, Wk_n, Wv_n, gamma_n, Wq_g,
                                           Wk_g, Wv_g, gamma_g, attnb, partial);
  // node head: lin1+relu+Wn2+log_softmax fused
  gemm256<1><<<MP / 64, 256, 0, stream>>>(attnb, wtn1, bn1, nullptr, nullptr, Wn2,
                                          bn2, out, NN, 256);
  // graph head
  pool_kernel<<<128, 256, 0, stream>>>(partial, gp_sum, NN / 4);
  graph_head_kernel<<<1, 256, 0, stream>>>(gp_sum, Wg1, bg1, Wg2, bg2,
                                           out + (size_t)NN * CN, 1.0f / NN);
}

// Round 10
// 488.372 us; speedup vs baseline: 1.2216x; 1.2216x over previous
//
#include <hip/hip_runtime.h>

#define NN 20000
#define TT 2
#define HH 128
#define LL 4
#define EE 320000
#define FF 514
#define CN 3
#define CG 2
#define MP 20096  // rows per ti-half, padded to multiple of 128

typedef __bf16 bf16x8 __attribute__((ext_vector_type(8)));
typedef __bf16 bf16x4 __attribute__((ext_vector_type(4)));
typedef __bf16 bf16x2 __attribute__((ext_vector_type(2)));
typedef float f32x4 __attribute__((ext_vector_type(4)));

struct __align__(8) Edge { int src; __bf16 ea0, ea1; };

// ---------------- wave helpers ----------------
__device__ inline float wave_sum(float v) {
#pragma unroll
  for (int off = 32; off; off >>= 1) v += __shfl_xor(v, off);
  return v;
}
__device__ inline float red16(float v) {  // reduce across fr = lane&15
  v += __shfl_xor(v, 1); v += __shfl_xor(v, 2);
  v += __shfl_xor(v, 4); v += __shfl_xor(v, 8);
  return v;
}

__device__ __forceinline__ float fexp2(float x) {
#if __has_builtin(__builtin_amdgcn_exp2f)
  return __builtin_amdgcn_exp2f(x);
#else
  return exp2f(x);
#endif
}

__device__ __forceinline__ void gload_lds16(const void* g, void* l) {
  __builtin_amdgcn_global_load_lds(
      (const __attribute__((address_space(1))) unsigned int*)g,
      (__attribute__((address_space(3))) unsigned int*)l, 16, 0, 0);
}

// ---------------- fused encoder GEMM + XCD-routed edge scatter --------------
#define ENCB (MP / 64)
#define SCB 2500
#define CHUNK 5000  // 2*NN/8 gnodes per XCD chunk
__global__ __launch_bounds__(256) void enc_scatter_kernel(
    const __bf16* __restrict__ A, const __bf16* __restrict__ BT,
    const float* __restrict__ bias, __bf16* __restrict__ C,
    const int* __restrict__ edge_index, const float* __restrict__ edge_attr,
    int* __restrict__ cursor, Edge* __restrict__ edges) {
  __shared__ __bf16 As[2][64][32];
  __shared__ __bf16 Bs[2][128][32];
  const int tid = threadIdx.x;
  if (blockIdx.x >= ENCB) {
    int chunk = blockIdx.x & 7;
    int i = ((blockIdx.x - ENCB) >> 3) * 256 + tid;
    if (i >= 2 * EE) return;
    int ti = (i >= EE) ? 1 : 0;
    int e = i - ti * EE;
    const int* srcp = edge_index + (size_t)ti * 2 * EE;
    int d = srcp[EE + e];
    int gnode = ti * NN + d;
    if (gnode / CHUNK != chunk) return;
    int s = srcp[e];
    float2 ea = ((const float2*)edge_attr)[(size_t)ti * EE + e];
    int pos = atomicAdd(&cursor[gnode], 1);
    Edge ed;
    ed.src = s + ti * MP;
    ed.ea0 = (__bf16)ea.x; ed.ea1 = (__bf16)ea.y;
    __builtin_memcpy(&edges[pos], &ed, sizeof(Edge));
    return;
  }
  const int K = 576;
  const int lane = tid & 63, w = tid >> 6;
  const int bm = blockIdx.x * 64;
  const int wr = (w >> 1) * 32, wc = (w & 1) * 64;
  const int fr = lane & 15, fq = lane >> 4;
  const int rowA = tid >> 2, chA = (tid & 3) * 8;
  const __bf16* Ab = A + (size_t)(bm + rowA) * K + chA;
  const __bf16* Bb = BT + (size_t)rowA * K + chA;
  const __bf16* Bb2 = Bb + (size_t)64 * K;
  f32x4 acc[2][4] = {};
#define STAGE(buf, k0)                                  \
  do {                                                  \
    gload_lds16(Ab + (k0), &As[buf][rowA][chA]);        \
    gload_lds16(Bb + (k0), &Bs[buf][rowA][chA]);        \
    gload_lds16(Bb2 + (k0), &Bs[buf][rowA + 64][chA]);  \
  } while (0)
  STAGE(0, 0);
  __syncthreads();
  int cur = 0;
  for (int k0 = 0; k0 < K; k0 += 32) {
    if (k0 + 32 < K) STAGE(cur ^ 1, k0 + 32);
    bf16x8 af[2], bq[4];
#pragma unroll
    for (int m = 0; m < 2; ++m)
      af[m] = *(const bf16x8*)&As[cur][wr + m * 16 + fr][fq * 8];
#pragma unroll
    for (int n = 0; n < 4; ++n)
      bq[n] = *(const bf16x8*)&Bs[cur][wc + n * 16 + fr][fq * 8];
#pragma unroll
    for (int m = 0; m < 2; ++m)
#pragma unroll
      for (int n = 0; n < 4; ++n)
        acc[m][n] =
            __builtin_amdgcn_mfma_f32_16x16x32_bf16(af[m], bq[n], acc[m][n], 0, 0, 0);
    __syncthreads();
    cur ^= 1;
  }
#undef STAGE
#pragma unroll
  for (int m = 0; m < 2; ++m) {
#pragma unroll
    for (int n = 0; n < 4; ++n) {
#pragma unroll
      for (int j = 0; j < 4; ++j) {
        int gm = bm + wr + m * 16 + fq * 4 + j;
        int gn = wc + n * 16 + fr;
        if (gm < NN) {
          __bf16 c = (__bf16)(acc[m][n][j] + bias[gn]);
          C[(size_t)gm * 128 + gn] = c;
          C[(size_t)(gm + MP) * 128 + gn] = c;
        }
      }
    }
  }
}

// ---------------- fused 256-wide GEMM (BM=64, BN=256, full row per wave) ----
template <int EPI>
__global__ __launch_bounds__(256) void gemm256(
    const __bf16* __restrict__ A, const __bf16* __restrict__ BT,
    const float* __restrict__ bias, const float* __restrict__ g,
    const float* __restrict__ be, const float* __restrict__ W2h,
    const float* __restrict__ b2h, void* __restrict__ outp, int M, int K) {
  __shared__ __bf16 As[2][64][32];
  __shared__ __bf16 Bs[2][256][32];
  const int tid = threadIdx.x;
  const int lane = tid & 63, w = tid >> 6;
  const int bm = blockIdx.x * 64;
  const int wr = w * 16;
  const int fr = lane & 15, fq = lane >> 4;
  const int rowA = tid >> 2, chA = (tid & 3) * 8;
  const __bf16* Ab = A + (size_t)(bm + rowA) * K + chA;
  const __bf16* Bb = BT + (size_t)rowA * K + chA;
  f32x4 acc[16] = {};

#define STG(buf, k0)                                                \
  do {                                                              \
    gload_lds16(Ab + (k0), &As[buf][rowA][chA]);                    \
    _Pragma("unroll") for (int r = 0; r < 4; ++r)                   \
        gload_lds16(Bb + (size_t)(r * 64) * K + (k0),               \
                    &Bs[buf][rowA + r * 64][chA]);                  \
  } while (0)

  STG(0, 0);
  __syncthreads();
  int cur = 0;
  for (int k0 = 0; k0 < K; k0 += 32) {
    if (k0 + 32 < K) STG(cur ^ 1, k0 + 32);
    bf16x8 af = *(const bf16x8*)&As[cur][wr + fr][fq * 8];
#pragma unroll
    for (int n = 0; n < 16; ++n) {
      bf16x8 bq = *(const bf16x8*)&Bs[cur][n * 16 + fr][fq * 8];
      acc[n] = __builtin_amdgcn_mfma_f32_16x16x32_bf16(af, bq, acc[n], 0, 0, 0);
    }
    __syncthreads();
    cur ^= 1;
  }
#undef STG

  float cb[16];
#pragma unroll
  for (int n = 0; n < 16; ++n) cb[n] = bias[n * 16 + fr];

  if constexpr (EPI == 0) {
    float gv[16], bev[16];
#pragma unroll
    for (int n = 0; n < 16; ++n) {
      gv[n] = g[n * 16 + fr];
      bev[n] = be[n * 16 + fr];
    }
    __bf16* outb = (__bf16*)outp;
#pragma unroll
    for (int j = 0; j < 4; ++j) {
      float cj[16], s = 0.f, s2 = 0.f;
#pragma unroll
      for (int n = 0; n < 16; ++n) {
        float c = acc[n][j] + cb[n];
        cj[n] = c; s += c; s2 += c * c;
      }
      s = red16(s); s2 = red16(s2);
      float mu = s * (1.f / 256);
      float var = fmaxf(s2 * (1.f / 256) - mu * mu, 0.f);
      float rr = rsqrtf(var + 1e-5f);
      int gm = bm + wr + fq * 4 + j;
      __bf16* op = outb + (size_t)gm * 256;
#pragma unroll
      for (int n = 0; n < 16; ++n) {
        float y = (cj[n] - mu) * rr * gv[n] + bev[n];
        op[n * 16 + fr] = (__bf16)fmaxf(y, 0.f);
      }
    }
  } else {
    float w0[16], w1[16], w2[16];
#pragma unroll
    for (int n = 0; n < 16; ++n) {
      int col = n * 16 + fr;
      w0[n] = W2h[col * 3 + 0];
      w1[n] = W2h[col * 3 + 1];
      w2[n] = W2h[col * 3 + 2];
    }
    float* outf = (float*)outp;
#pragma unroll
    for (int j = 0; j < 4; ++j) {
      float p0 = 0.f, p1 = 0.f, p2 = 0.f;
#pragma unroll
      for (int n = 0; n < 16; ++n) {
        float h = fmaxf(acc[n][j] + cb[n], 0.f);
        p0 += h * w0[n]; p1 += h * w1[n]; p2 += h * w2[n];
      }
      p0 = red16(p0); p1 = red16(p1); p2 = red16(p2);
      int gm = bm + wr + fq * 4 + j;
      if (fr == 0 && gm < M) {
        float l0 = p0 + b2h[0], l1 = p1 + b2h[1], l2 = p2 + b2h[2];
        float m = fmaxf(l0, fmaxf(l1, l2));
        float lse = m + logf(__expf(l0 - m) + __expf(l1 - m) + __expf(l2 - m));
        outf[(size_t)gm * 3 + 0] = l0 - lse;
        outf[(size_t)gm * 3 + 1] = l1 - lse;
        outf[(size_t)gm * 3 + 2] = l2 - lse;
      }
    }
  }
}

// ---------------- lin2 GEMM + residual + fused LayerNorm+ReLU --------------
// MODE 0: write xres (no add) + LN->relu->bf16 hb      (layer 0)
// MODE 1: add xres, write xres + LN->relu->bf16 hb     (layers 1..L-2)
// MODE 2: add xres, LN->relu->f32 emb[node*256+half*128+col] (last layer)
template <int MODE>
__global__ __launch_bounds__(256) void gemm_lin2(
    const __bf16* __restrict__ A, const __bf16* __restrict__ BT,
    const float* __restrict__ bias, float* __restrict__ xres,
    const float* __restrict__ g, const float* __restrict__ be,
    void* __restrict__ lnout) {
  __shared__ __bf16 As[2][64][32];
  __shared__ __bf16 Bs[2][128][32];
  __shared__ float redS[64][2], redS2[64][2];
  const int tid = threadIdx.x;
  const int lane = tid & 63, w = tid >> 6;
  const int bm = blockIdx.x * 64;
  const int wr = (w >> 1) * 32, wc = (w & 1) * 64;
  const int fr = lane & 15, fq = lane >> 4;
  const int rowA = tid >> 2, chA = (tid & 3) * 8;
  const __bf16* Ab = A + (size_t)(bm + rowA) * 256 + chA;
  const __bf16* Bb = BT + (size_t)rowA * 256 + chA;
  const __bf16* Bb2 = Bb + (size_t)64 * 256;
  f32x4 acc[2][4] = {};

#define STAGE(buf, k0)                                  \
  do {                                                  \
    gload_lds16(Ab + (k0), &As[buf][rowA][chA]);        \
    gload_lds16(Bb + (k0), &Bs[buf][rowA][chA]);        \
    gload_lds16(Bb2 + (k0), &Bs[buf][rowA + 64][chA]);  \
  } while (0)

  STAGE(0, 0);
  __syncthreads();
  int cur = 0;
  for (int k0 = 0; k0 < 256; k0 += 32) {
    if (k0 + 32 < 256) STAGE(cur ^ 1, k0 + 32);
    bf16x8 af[2], bq[4];
#pragma unroll
    for (int m = 0; m < 2; ++m)
      af[m] = *(const bf16x8*)&As[cur][wr + m * 16 + fr][fq * 8];
#pragma unroll
    for (int n = 0; n < 4; ++n)
      bq[n] = *(const bf16x8*)&Bs[cur][wc + n * 16 + fr][fq * 8];
#pragma unroll
    for (int m = 0; m < 2; ++m)
#pragma unroll
      for (int n = 0; n < 4; ++n)
        acc[m][n] =
            __builtin_amdgcn_mfma_f32_16x16x32_bf16(af[m], bq[n], acc[m][n], 0, 0, 0);
    __syncthreads();
    cur ^= 1;
  }
#undef STAGE

  float cv[2][4][4];
#pragma unroll
  for (int m = 0; m < 2; ++m) {
    int r0 = wr + m * 16 + fq * 4;
#pragma unroll
    for (int j = 0; j < 4; ++j) {
      int gm = bm + r0 + j;
      float s = 0.f, s2 = 0.f;
#pragma unroll
      for (int n = 0; n < 4; ++n) {
        float c = acc[m][n][j] + bias[wc + n * 16 + fr];
        if (MODE != 0) c += xres[(size_t)gm * 128 + wc + n * 16 + fr];
        cv[m][n][j] = c;
        s += c; s2 += c * c;
      }
      s = red16(s); s2 = red16(s2);
      if (fr == 0) {
        redS[r0 + j][w & 1] = s;
        redS2[r0 + j][w & 1] = s2;
      }
    }
  }
  __syncthreads();
#pragma unroll
  for (int m = 0; m < 2; ++m) {
    int r0 = wr + m * 16 + fq * 4;
#pragma unroll
    for (int j = 0; j < 4; ++j) {
      int r = r0 + j;
      int gm = bm + r;
      float S = redS[r][0] + redS[r][1];
      float S2 = redS2[r][0] + redS2[r][1];
      float mu = S * (1.f / 128);
      float var = fmaxf(S2 * (1.f / 128) - mu * mu, 0.f);
      float rr = rsqrtf(var + 1e-5f);
      if constexpr (MODE < 2) {
        float* xp = xres + (size_t)gm * 128;
        __bf16* hp = (__bf16*)lnout + (size_t)gm * 128;
#pragma unroll
        for (int n = 0; n < 4; ++n) {
          int col = wc + n * 16 + fr;
          float c = cv[m][n][j];
          xp[col] = c;
          float y = (c - mu) * rr * g[col] + be[col];
          hp[col] = (__bf16)fmaxf(y, 0.f);
        }
      } else {
        int half = gm >= MP;
        int node = gm - half * MP;
        if (node < NN) {
          float* ep = (float*)lnout + (size_t)node * 256 + half * 128;
#pragma unroll
          for (int n = 0; n < 4; ++n) {
            int col = wc + n * 16 + fr;
            float y = (cv[m][n][j] - mu) * rr * g[col] + be[col];
            ep[col] = fmaxf(y, 0.f);
          }
        }
      }
    }
  }
}

// ---------------- fused prologue (vectorized) -------------------------------
struct WtDesc { const float* src; __bf16* dst; int K, N, Kpad; };
struct WtDescs { WtDesc d[10]; };
#define NF2B 20079  // ceil(NN*FF/2 / 256)
#define PADB 2422   // ceil(NN*31 / 256)
#define WTB 2880
#define CNTB 2500

__global__ void prep_kernel(const float* __restrict__ nf_src,
                            __bf16* __restrict__ nf_dst, WtDescs descs,
                            const int* __restrict__ edge_index,
                            int* __restrict__ deg, float* __restrict__ gp_sum) {
  int b = blockIdx.x, tid = threadIdx.x;
  if (b < NF2B) {
    int i = b * 256 + tid;  // float2 index
    if (i >= NN * FF / 2) return;
    int row = i / 257;
    int col = (i - row * 257) * 2;
    float2 v = ((const float2*)nf_src)[i];
    bf16x2 o; o[0] = (__bf16)v.x; o[1] = (__bf16)v.y;
    *(bf16x2*)(nf_dst + (size_t)row * 576 + col) = o;
  } else if (b < NF2B + PADB) {
    int i = (b - NF2B) * 256 + tid;
    if (i >= NN * 31) return;
    int row = i / 31, j = i - row * 31;
    bf16x2 z; z[0] = (__bf16)0.f; z[1] = (__bf16)0.f;
    *(bf16x2*)(nf_dst + (size_t)row * 576 + 514 + 2 * j) = z;
  } else if (b < NF2B + PADB + WTB) {
    int wb = b - NF2B - PADB;
    WtDesc de = descs.d[wb / 288];
    int idx = (wb % 288) * 256 + tid;
    if (idx >= de.N * de.Kpad) return;
    int n = idx / de.Kpad, k = idx - n * de.Kpad;
    float v = (k < de.K) ? de.src[(size_t)k * de.N + n] : 0.f;
    de.dst[idx] = (__bf16)v;
  } else if (b < NF2B + PADB + WTB + CNTB) {
    int i = (b - NF2B - PADB - WTB) * 256 + tid;
    if (i >= 2 * EE) return;
    int ti = (i >= EE) ? 1 : 0;
    int e = i - ti * EE;
    int d = edge_index[(size_t)ti * 2 * EE + EE + e];
    atomicAdd(&deg[ti * NN + d], 1);
  } else {
    gp_sum[tid] = 0.f;
  }
}

// ---------------- CSR scan (block per ti) ----------------
__global__ __launch_bounds__(1024) void scan2_kernel(
    const int* __restrict__ deg_all, int* __restrict__ rowptr,
    int* __restrict__ cursor) {
  const int ti = blockIdx.x;
  const int* deg = deg_all + ti * NN;
  __shared__ int sums[1024];
  int tid = threadIdx.x;
  int chunk = (NN + 1023) / 1024;
  int begin = tid * chunk, end = min(begin + chunk, NN);
  int s = 0;
  for (int i = begin; i < end; ++i) s += deg[i];
  sums[tid] = s;
  __syncthreads();
  for (int off = 1; off < 1024; off <<= 1) {
    int v = (tid >= off) ? sums[tid - off] : 0;
    __syncthreads();
    sums[tid] += v;
    __syncthreads();
  }
  int running = ti * EE + sums[tid] - s;
  for (int i = begin; i < end; ++i) {
    rowptr[ti * NN + i] = running;
    cursor[ti * NN + i] = running;
    running += deg[i];
  }
  if (tid == 0 && ti == 1) rowptr[2 * NN] = 2 * EE;
}

// ---------------- GENConv softmax aggregation + residual -------------------
// R8 structure (proven 16.8 MB FETCH): quadrant q = ti*2 + ch-half on XCD
// pair; 16 lanes x bf16x4 per edge (4 edge slots/wave), e+=8 loop.
// R9 math (proven accurate): weights pre-scaled by t*log2e, exp2, no eps,
// 1/t2 folded into the final divide.
__global__ __launch_bounds__(256) void agg_kernel(
    const __bf16* __restrict__ xin, const int* __restrict__ rowptr,
    const Edge* __restrict__ edges, const float* __restrict__ Wee,
    const float* __restrict__ bee, const float* __restrict__ tptr, int layer,
    __bf16* __restrict__ out) {
  int wave = threadIdx.x >> 6, lane = threadIdx.x & 63;
  int b = blockIdx.x;  // 2500 * 8 blocks
  int x8 = b & 7;
  int q = x8 >> 1;              // quadrant = ti*2 + chh
  int par = x8 & 1;
  int ti = q >> 1, chh = q & 1;
  int group = (b >> 3) * 2 + par;  // 0..4999
  int node = group * 4 + wave;     // 0..19999
  int gnode = ti * NN + node;
  int xrow = ti * MP + node;
  float t2 = tptr[layer] * 1.4426950408889634f;
  int qq = lane >> 4, c15 = lane & 15;
  int c0 = chh * 64 + c15 * 4;
  float den[4] = {}, num[4] = {};
  int e = rowptr[gnode];
  const int e1 = rowptr[gnode + 1];

  if (t2 > 0.f) {
    float w0p[4], w1p[4], bvp[4];
#pragma unroll
    for (int i = 0; i < 4; ++i) {
      w0p[i] = Wee[c0 + i] * t2;
      w1p[i] = Wee[HH + c0 + i] * t2;
      bvp[i] = bee[c0 + i] * t2;
    }
#define MLPF(XV, ED)                                                      \
  do {                                                                    \
    float eax = (float)(ED).ea0, eay = (float)(ED).ea1;                   \
    _Pragma("unroll") for (int i = 0; i < 4; ++i) {                       \
      float te = fmaf(eax, w0p[i], fmaf(eay, w1p[i], bvp[i]));            \
      float sm = fmaxf(fmaf((float)(XV)[i], t2, te), 0.f);                \
      float ex = fexp2(sm);                                               \
      den[i] += ex; num[i] = fmaf(sm, ex, num[i]);                        \
    }                                                                     \
  } while (0)
    for (; e + 8 <= e1; e += 8) {
      Edge E0 = edges[e + qq];
      Edge E1 = edges[e + 4 + qq];
      bf16x4 x0 = *(const bf16x4*)(xin + (size_t)E0.src * HH + c0);
      bf16x4 x1 = *(const bf16x4*)(xin + (size_t)E1.src * HH + c0);
      MLPF(x0, E0);
      MLPF(x1, E1);
    }
    if (e + qq < e1) {
      Edge E0 = edges[e + qq];
      bf16x4 x0 = *(const bf16x4*)(xin + (size_t)E0.src * HH + c0);
      MLPF(x0, E0);
    }
    if (e + 4 + qq < e1) {
      Edge E0 = edges[e + 4 + qq];
      bf16x4 x0 = *(const bf16x4*)(xin + (size_t)E0.src * HH + c0);
      MLPF(x0, E0);
    }
#undef MLPF
#pragma unroll
    for (int i = 0; i < 4; ++i) {
      den[i] += __shfl_xor(den[i], 16);
      den[i] += __shfl_xor(den[i], 32);
      num[i] += __shfl_xor(num[i], 16);
      num[i] += __shfl_xor(num[i], 32);
    }
    if (qq == 0) {
      bf16x4 xr = *(const bf16x4*)(xin + (size_t)xrow * HH + c0);
      bf16x4 o;
#pragma unroll
      for (int i = 0; i < 4; ++i)
        o[i] = (__bf16)(num[i] / (t2 * (den[i] + 1e-16f)) + (float)xr[i]);
      *(bf16x4*)(out + (size_t)xrow * HH + c0) = o;
    }
  } else {
    // general (t2 <= 0) fallback: reference formula
    float w0[4], w1[4], bv[4];
#pragma unroll
    for (int i = 0; i < 4; ++i) {
      w0[i] = Wee[c0 + i];
      w1[i] = Wee[HH + c0 + i];
      bv[i] = bee[c0 + i];
    }
    for (; e + qq < e1; e += 4) {
      Edge E0 = edges[e + qq];
      bf16x4 xv = *(const bf16x4*)(xin + (size_t)E0.src * HH + c0);
      float eax = (float)E0.ea0, eay = (float)E0.ea1;
#pragma unroll
      for (int i = 0; i < 4; ++i) {
        float m =
            fmaxf((float)xv[i] + eax * w0[i] + eay * w1[i] + bv[i], 0.f) + 1e-7f;
        float ex = fexp2(m * t2);
        den[i] += ex; num[i] += m * ex;
      }
    }
#pragma unroll
    for (int i = 0; i < 4; ++i) {
      den[i] += __shfl_xor(den[i], 16);
      den[i] += __shfl_xor(den[i], 32);
      num[i] += __shfl_xor(num[i], 16);
      num[i] += __shfl_xor(num[i], 32);
    }
    if (qq == 0) {
      bf16x4 xr = *(const bf16x4*)(xin + (size_t)xrow * HH + c0);
      bf16x4 o;
#pragma unroll
      for (int i = 0; i < 4; ++i)
        o[i] = (__bf16)(num[i] / (den[i] + 1e-16f) + (float)xr[i]);
      *(bf16x4*)(out + (size_t)xrow * HH + c0) = o;
    }
  }
}

// ---------------- fused channel attention (node out + graph partial-pool) --
__global__ __launch_bounds__(256) void attn2_kernel(
    const float* __restrict__ emb, const float* __restrict__ Wq_n,
    const float* __restrict__ Wk_n, const float* __restrict__ Wv_n,
    const float* __restrict__ gn, const float* __restrict__ Wq_g,
    const float* __restrict__ Wk_g, const float* __restrict__ Wv_g,
    const float* __restrict__ gg, __bf16* __restrict__ outn,
    float* __restrict__ partial) {
  __shared__ float gsum[4][256];
  int wave = threadIdx.x >> 6, lane = threadIdx.x & 63;
  int tid = threadIdx.x;
  int n = blockIdx.x * 4 + wave;  // NN % 4 == 0: always valid
  int c0 = lane * 2;
  const float* base = emb + (size_t)n * (2 * HH);
  float2 x0 = *(const float2*)(base + c0);
  float2 x1 = *(const float2*)(base + HH + c0);

#define ATTN_BODY(Wq, Wk, Wv, GAM, O0A, O0B, O1A, O1B)                        \
  {                                                                           \
    float gamma = *(GAM);                                                     \
    float wq00 = Wq[0], wq01 = Wq[1], wq10 = Wq[2], wq11 = Wq[3];             \
    float wk00 = Wk[0], wk01 = Wk[1], wk10 = Wk[2], wk11 = Wk[3];             \
    float wv00 = Wv[0], wv01 = Wv[1], wv10 = Wv[2], wv11 = Wv[3];             \
    float q0a = wq00 * x0.x + wq01 * x1.x, q0b = wq00 * x0.y + wq01 * x1.y;   \
    float q1a = wq10 * x0.x + wq11 * x1.x, q1b = wq10 * x0.y + wq11 * x1.y;   \
    float k0a = wk00 * x0.x + wk01 * x1.x, k0b = wk00 * x0.y + wk01 * x1.y;   \
    float k1a = wk10 * x0.x + wk11 * x1.x, k1b = wk10 * x0.y + wk11 * x1.y;   \
    float v0a = wv00 * x0.x + wv01 * x1.x, v0b = wv00 * x0.y + wv01 * x1.y;   \
    float v1a = wv10 * x0.x + wv11 * x1.x, v1b = wv10 * x0.y + wv11 * x1.y;   \
    float s00 = wave_sum(q0a * k0a + q0b * k0b);                              \
    float s01 = wave_sum(q0a * k1a + q0b * k1b);                              \
    float s10 = wave_sum(q1a * k0a + q1b * k0b);                              \
    float s11 = wave_sum(q1a * k1a + q1b * k1b);                              \
    float m0 = fmaxf(s00, s01);                                               \
    float e00 = __expf(s00 - m0), e01 = __expf(s01 - m0);                     \
    float i0 = 1.f / (e00 + e01);                                             \
    float a00 = e00 * i0, a01 = e01 * i0;                                     \
    float m1 = fmaxf(s10, s11);                                               \
    float e10 = __expf(s10 - m1), e11 = __expf(s11 - m1);                     \
    float i1 = 1.f / (e10 + e11);                                             \
    float a10 = e10 * i1, a11 = e11 * i1;                                     \
    O0A = gamma * (a00 * v0a + a01 * v1a) + x0.x;                             \
    O0B = gamma * (a00 * v0b + a01 * v1b) + x0.y;                             \
    O1A = gamma * (a10 * v0a + a11 * v1a) + x1.x;                             \
    O1B = gamma * (a10 * v0b + a11 * v1b) + x1.y;                             \
  }

  float n0a, n0b, n1a, n1b;
  ATTN_BODY(Wq_n, Wk_n, Wv_n, gn, n0a, n0b, n1a, n1b);
  __bf16* opn = outn + (size_t)n * (2 * HH);
  bf16x2 t0; t0[0] = (__bf16)n0a; t0[1] = (__bf16)n0b;
  bf16x2 t1; t1[0] = (__bf16)n1a; t1[1] = (__bf16)n1b;
  *(bf16x2*)(opn + c0) = t0;
  *(bf16x2*)(opn + HH + c0) = t1;

  float g0a, g0b, g1a, g1b;
  ATTN_BODY(Wq_g, Wk_g, Wv_g, gg, g0a, g0b, g1a, g1b);
  gsum[wave][c0] = g0a;
  gsum[wave][c0 + 1] = g0b;
  gsum[wave][128 + c0] = g1a;
  gsum[wave][129 + c0] = g1b;
  __syncthreads();
  partial[(size_t)blockIdx.x * 256 + tid] =
      gsum[0][tid] + gsum[1][tid] + gsum[2][tid] + gsum[3][tid];
#undef ATTN_BODY
}

// ---------------- pool over per-block partials ----------------
__global__ __launch_bounds__(256) void pool_kernel(const float* __restrict__ partial,
                                                   float* __restrict__ gp_sum,
                                                   int nRows) {
  int c = threadIdx.x;
  float s = 0.f;
  for (int r = blockIdx.x; r < nRows; r += gridDim.x)
    s += partial[(size_t)r * 256 + c];
  atomicAdd(&gp_sum[c], s);
}

// ---------------- graph head (single block) ----------------
__global__ __launch_bounds__(256) void graph_head_kernel(
    const float* __restrict__ gp_sum, const float* __restrict__ Wg1,
    const float* __restrict__ bg1, const float* __restrict__ Wg2,
    const float* __restrict__ bg2, float* __restrict__ outp, float invN) {
  __shared__ float gp[256];
  __shared__ float h1[256];
  __shared__ float lg[2];
  int tid = threadIdx.x;
  gp[tid] = gp_sum[tid] * invN;
  __syncthreads();
  float acc = bg1[tid];
  for (int k = 0; k < 256; ++k) acc += gp[k] * Wg1[k * 256 + tid];
  h1[tid] = fmaxf(acc, 0.f);
  __syncthreads();
  if (tid < 2) {
    float l = bg2[tid];
    for (int c = 0; c < 256; ++c) l += h1[c] * Wg2[c * 2 + tid];
    lg[tid] = l;
  }
  __syncthreads();
  if (tid == 0) {
    float m = fmaxf(lg[0], lg[1]);
    float lse = m + logf(__expf(lg[0] - m) + __expf(lg[1] - m));
    outp[0] = lg[0] - lse;
    outp[1] = lg[1] - lse;
  }
}

// ---------------- launch ----------------
extern "C" void kernel_launch(void* const* d_in, const int* in_sizes, int n_in,
                              void* d_out, int out_size, void* d_ws, size_t ws_size,
                              hipStream_t stream) {
  (void)in_sizes; (void)n_in; (void)out_size; (void)ws_size;
  const float* node_feature = (const float*)d_in[0];
  const int* edge_index = (const int*)d_in[1];
  const float* edge_attr = (const float*)d_in[2];
  const float* Wne = (const float*)d_in[3];
  const float* bne = (const float*)d_in[4];
  const float* Wee = (const float*)d_in[5];
  const float* bee = (const float*)d_in[6];
  const float* W1 = (const float*)d_in[7];
  const float* b1 = (const float*)d_in[8];
  const float* g1 = (const float*)d_in[9];
  const float* be1 = (const float*)d_in[10];
  const float* W2 = (const float*)d_in[11];
  const float* b2 = (const float*)d_in[12];
  const float* dg = (const float*)d_in[13];
  const float* db = (const float*)d_in[14];
  const float* tpar = (const float*)d_in[15];
  const float* Wq_n = (const float*)d_in[16];
  const float* Wk_n = (const float*)d_in[17];
  const float* Wv_n = (const float*)d_in[18];
  const float* gamma_n = (const float*)d_in[19];
  const float* Wn1 = (const float*)d_in[20];
  const float* bn1 = (const float*)d_in[21];
  const float* Wn2 = (const float*)d_in[22];
  const float* bn2 = (const float*)d_in[23];
  const float* Wq_g = (const float*)d_in[24];
  const float* Wk_g = (const float*)d_in[25];
  const float* Wv_g = (const float*)d_in[26];
  const float* gamma_g = (const float*)d_in[27];
  const float* Wg1 = (const float*)d_in[28];
  const float* bg1 = (const float*)d_in[29];
  const float* Wg2 = (const float*)d_in[30];
  const float* bg2 = (const float*)d_in[31];
  float* out = (float*)d_out;

  // ---- workspace carve-out (256B-aligned regions) ----
  char* pc = (char*)d_ws;
  auto alloc = [&](size_t bytes) {
    char* r = pc;
    pc += (bytes + 255) & ~(size_t)255;
    return r;
  };
  float* xbuf = (float*)alloc((size_t)2 * MP * HH * 4);       // f32 residual
  __bf16* hbuf_b = (__bf16*)alloc((size_t)2 * MP * HH * 2);   // LN'd agg input
  __bf16* t256_b = (__bf16*)alloc((size_t)2 * MP * 256 * 2);  // lin1+LN out
  float* emb = (float*)alloc((size_t)NN * 2 * HH * 4);        // [N,T,H] f32
  __bf16* aggout_b = (__bf16*)alloc((size_t)2 * MP * HH * 2); // agg out
  __bf16* nf_b = (__bf16*)emb;  // 23.0MB <= emb(20.5)+aggout(10.3)
  __bf16* attnb = t256_b;       // alias: node-attn out (after last lin2)
  float* partial = xbuf;        // alias: graph-attn partials [5000][256]
  __bf16* wt_ne = (__bf16*)alloc((size_t)128 * 576 * 2);
  __bf16* wt1 = (__bf16*)alloc((size_t)4 * 256 * 128 * 2);
  __bf16* wt2 = (__bf16*)alloc((size_t)4 * 128 * 256 * 2);
  __bf16* wtn1 = (__bf16*)alloc((size_t)256 * 256 * 2);
  float* gp_sum = (float*)alloc(256 * 4);
  int* deg = (int*)alloc((size_t)2 * NN * 4);
  int* cursor = (int*)alloc((size_t)2 * NN * 4);
  int* rowptr = (int*)alloc((size_t)(2 * NN + 2) * 4);
  Edge* edges = (Edge*)alloc((size_t)2 * EE * 8);

  const int gRows2 = 2 * MP / 64;  // 628 row-blocks, stacked GEMMs

  WtDescs wd;
  wd.d[0] = {Wne, wt_ne, FF, HH, 576};
  for (int l = 0; l < 4; ++l)
    wd.d[1 + l] = {W1 + (size_t)l * HH * 256, wt1 + (size_t)l * 256 * HH, HH, 256, HH};
  for (int l = 0; l < 4; ++l)
    wd.d[5 + l] = {W2 + (size_t)l * 256 * HH, wt2 + (size_t)l * HH * 256, 256, HH, 256};
  wd.d[9] = {Wn1, wtn1, 256, 256, 256};

  // prologue: deg zero; converts (vectorized) + degree count + gp_sum zero
  hipMemsetAsync(deg, 0, 2 * NN * sizeof(int), stream);
  prep_kernel<<<NF2B + PADB + WTB + CNTB + 1, 256, 0, stream>>>(
      node_feature, nf_b, wd, edge_index, deg, gp_sum);
  scan2_kernel<<<2, 1024, 0, stream>>>(deg, rowptr, cursor);
  // encoder GEMM (dup to both halves) fused with XCD-routed edge scatter
  enc_scatter_kernel<<<ENCB + 8 * SCB, 256, 0, stream>>>(
      nf_b, wt_ne, bne, hbuf_b, edge_index, edge_attr, cursor, edges);

  // layer loop, both ti at once
  for (int l = 0; l < LL; ++l) {
    agg_kernel<<<2500 * 8, 256, 0, stream>>>(hbuf_b, rowptr, edges, Wee, bee, tpar,
                                             l, aggout_b);
    gemm256<0><<<gRows2, 256, 0, stream>>>(aggout_b, wt1 + (size_t)l * 256 * HH,
                                           b1 + l * 2 * HH, g1 + l * 2 * HH,
                                           be1 + l * 2 * HH, nullptr, nullptr, t256_b,
                                           2 * MP, HH);
    const __bf16* w2l = wt2 + (size_t)l * HH * 256;
    const float* b2l = b2 + l * HH;
    if (l == 0)
      gemm_lin2<0><<<gRows2, 256, 0, stream>>>(t256_b, w2l, b2l, xbuf, dg + 1 * HH,
                                               db + 1 * HH, hbuf_b);
    else if (l < LL - 1)
      gemm_lin2<1><<<gRows2, 256, 0, stream>>>(t256_b, w2l, b2l, xbuf,
                                               dg + (l + 1) * HH, db + (l + 1) * HH,
                                               hbuf_b);
    else
      gemm_lin2<2><<<gRows2, 256, 0, stream>>>(t256_b, w2l, b2l, xbuf, dg, db, emb);
  }

  // fused node+graph attention (one emb read; graph branch -> LDS partials)
  attn2_kernel<<<NN / 4, 256, 0, stream>>>(emb, Wq_n, Wk_n, Wv_n, gamma_n, Wq_g,
                                           Wk_g, Wv_g, gamma_g, attnb, partial);
  // node head: lin1+relu+Wn2+log_softmax fused
  gemm256<1><<<MP / 64, 256, 0, stream>>>(attnb, wtn1, bn1, nullptr, nullptr, Wn2,
                                          bn2, out, NN, 256);
  // graph head
  pool_kernel<<<128, 256, 0, stream>>>(partial, gp_sum, NN / 4);
  graph_head_kernel<<<1, 256, 0, stream>>>(gp_sum, Wg1, bg1, Wg2, bg2,
                                           out + (size_t)NN * CN, 1.0f / NN);
}

// Round 11
// 443.559 us; speedup vs baseline: 1.3450x; 1.1010x over previous
//
#include <hip/hip_runtime.h>

#define NN 20000
#define TT 2
#define HH 128
#define LL 4
#define EE 320000
#define FF 514
#define CN 3
#define CG 2
#define MP 20096  // rows per ti-half, padded to multiple of 128

typedef __bf16 bf16x8 __attribute__((ext_vector_type(8)));
typedef __bf16 bf16x4 __attribute__((ext_vector_type(4)));
typedef __bf16 bf16x2 __attribute__((ext_vector_type(2)));
typedef float f32x4 __attribute__((ext_vector_type(4)));

struct __align__(8) Edge { int src; __bf16 ea0, ea1; };

// ---------------- wave helpers ----------------
__device__ inline float wave_sum(float v) {
#pragma unroll
  for (int off = 32; off; off >>= 1) v += __shfl_xor(v, off);
  return v;
}
__device__ inline float red16(float v) {  // reduce across fr = lane&15
  v += __shfl_xor(v, 1); v += __shfl_xor(v, 2);
  v += __shfl_xor(v, 4); v += __shfl_xor(v, 8);
  return v;
}

__device__ __forceinline__ float fexp2(float x) {
#if __has_builtin(__builtin_amdgcn_exp2f)
  return __builtin_amdgcn_exp2f(x);
#else
  return exp2f(x);
#endif
}

__device__ __forceinline__ void gload_lds16(const void* g, void* l) {
  __builtin_amdgcn_global_load_lds(
      (const __attribute__((address_space(1))) unsigned int*)g,
      (__attribute__((address_space(3))) unsigned int*)l, 16, 0, 0);
}

// ---------------- fused encoder GEMM + XCD-routed edge scatter --------------
#define ENCB (MP / 64)
#define SCB 2500
#define CHUNK 5000  // 2*NN/8 gnodes per XCD chunk
__global__ __launch_bounds__(256) void enc_scatter_kernel(
    const __bf16* __restrict__ A, const __bf16* __restrict__ BT,
    const float* __restrict__ bias, __bf16* __restrict__ C,
    const int* __restrict__ edge_index, const float* __restrict__ edge_attr,
    int* __restrict__ cursor, Edge* __restrict__ edges) {
  __shared__ __bf16 As[2][64][32];
  __shared__ __bf16 Bs[2][128][32];
  const int tid = threadIdx.x;
  if (blockIdx.x >= ENCB) {
    int chunk = blockIdx.x & 7;
    int i = ((blockIdx.x - ENCB) >> 3) * 256 + tid;
    if (i >= 2 * EE) return;
    int ti = (i >= EE) ? 1 : 0;
    int e = i - ti * EE;
    const int* srcp = edge_index + (size_t)ti * 2 * EE;
    int d = srcp[EE + e];
    int gnode = ti * NN + d;
    if (gnode / CHUNK != chunk) return;
    int s = srcp[e];
    float2 ea = ((const float2*)edge_attr)[(size_t)ti * EE + e];
    int pos = atomicAdd(&cursor[gnode], 1);
    Edge ed;
    ed.src = s + ti * MP;
    ed.ea0 = (__bf16)ea.x; ed.ea1 = (__bf16)ea.y;
    __builtin_memcpy(&edges[pos], &ed, sizeof(Edge));
    return;
  }
  const int K = 576;
  const int lane = tid & 63, w = tid >> 6;
  const int bm = blockIdx.x * 64;
  const int wr = (w >> 1) * 32, wc = (w & 1) * 64;
  const int fr = lane & 15, fq = lane >> 4;
  const int rowA = tid >> 2, chA = (tid & 3) * 8;
  const __bf16* Ab = A + (size_t)(bm + rowA) * K + chA;
  const __bf16* Bb = BT + (size_t)rowA * K + chA;
  const __bf16* Bb2 = Bb + (size_t)64 * K;
  f32x4 acc[2][4] = {};
#define STAGE(buf, k0)                                  \
  do {                                                  \
    gload_lds16(Ab + (k0), &As[buf][rowA][chA]);        \
    gload_lds16(Bb + (k0), &Bs[buf][rowA][chA]);        \
    gload_lds16(Bb2 + (k0), &Bs[buf][rowA + 64][chA]);  \
  } while (0)
  STAGE(0, 0);
  __syncthreads();
  int cur = 0;
  for (int k0 = 0; k0 < K; k0 += 32) {
    if (k0 + 32 < K) STAGE(cur ^ 1, k0 + 32);
    bf16x8 af[2], bq[4];
#pragma unroll
    for (int m = 0; m < 2; ++m)
      af[m] = *(const bf16x8*)&As[cur][wr + m * 16 + fr][fq * 8];
#pragma unroll
    for (int n = 0; n < 4; ++n)
      bq[n] = *(const bf16x8*)&Bs[cur][wc + n * 16 + fr][fq * 8];
#pragma unroll
    for (int m = 0; m < 2; ++m)
#pragma unroll
      for (int n = 0; n < 4; ++n)
        acc[m][n] =
            __builtin_amdgcn_mfma_f32_16x16x32_bf16(af[m], bq[n], acc[m][n], 0, 0, 0);
    __syncthreads();
    cur ^= 1;
  }
#undef STAGE
#pragma unroll
  for (int m = 0; m < 2; ++m) {
#pragma unroll
    for (int n = 0; n < 4; ++n) {
#pragma unroll
      for (int j = 0; j < 4; ++j) {
        int gm = bm + wr + m * 16 + fq * 4 + j;
        int gn = wc + n * 16 + fr;
        if (gm < NN) {
          __bf16 c = (__bf16)(acc[m][n][j] + bias[gn]);
          C[(size_t)gm * 128 + gn] = c;
          C[(size_t)(gm + MP) * 128 + gn] = c;
        }
      }
    }
  }
}

// ---------------- fused 256-wide GEMM (BM=64, BN=256, full row per wave) ----
template <int EPI>
__global__ __launch_bounds__(256) void gemm256(
    const __bf16* __restrict__ A, const __bf16* __restrict__ BT,
    const float* __restrict__ bias, const float* __restrict__ g,
    const float* __restrict__ be, const float* __restrict__ W2h,
    const float* __restrict__ b2h, void* __restrict__ outp, int M, int K) {
  __shared__ __bf16 As[2][64][32];
  __shared__ __bf16 Bs[2][256][32];
  const int tid = threadIdx.x;
  const int lane = tid & 63, w = tid >> 6;
  const int bm = blockIdx.x * 64;
  const int wr = w * 16;
  const int fr = lane & 15, fq = lane >> 4;
  const int rowA = tid >> 2, chA = (tid & 3) * 8;
  const __bf16* Ab = A + (size_t)(bm + rowA) * K + chA;
  const __bf16* Bb = BT + (size_t)rowA * K + chA;
  f32x4 acc[16] = {};

#define STG(buf, k0)                                                \
  do {                                                              \
    gload_lds16(Ab + (k0), &As[buf][rowA][chA]);                    \
    _Pragma("unroll") for (int r = 0; r < 4; ++r)                   \
        gload_lds16(Bb + (size_t)(r * 64) * K + (k0),               \
                    &Bs[buf][rowA + r * 64][chA]);                  \
  } while (0)

  STG(0, 0);
  __syncthreads();
  int cur = 0;
  for (int k0 = 0; k0 < K; k0 += 32) {
    if (k0 + 32 < K) STG(cur ^ 1, k0 + 32);
    bf16x8 af = *(const bf16x8*)&As[cur][wr + fr][fq * 8];
#pragma unroll
    for (int n = 0; n < 16; ++n) {
      bf16x8 bq = *(const bf16x8*)&Bs[cur][n * 16 + fr][fq * 8];
      acc[n] = __builtin_amdgcn_mfma_f32_16x16x32_bf16(af, bq, acc[n], 0, 0, 0);
    }
    __syncthreads();
    cur ^= 1;
  }
#undef STG

  float cb[16];
#pragma unroll
  for (int n = 0; n < 16; ++n) cb[n] = bias[n * 16 + fr];

  if constexpr (EPI == 0) {
    float gv[16], bev[16];
#pragma unroll
    for (int n = 0; n < 16; ++n) {
      gv[n] = g[n * 16 + fr];
      bev[n] = be[n * 16 + fr];
    }
    __bf16* outb = (__bf16*)outp;
#pragma unroll
    for (int j = 0; j < 4; ++j) {
      float cj[16], s = 0.f, s2 = 0.f;
#pragma unroll
      for (int n = 0; n < 16; ++n) {
        float c = acc[n][j] + cb[n];
        cj[n] = c; s += c; s2 += c * c;
      }
      s = red16(s); s2 = red16(s2);
      float mu = s * (1.f / 256);
      float var = fmaxf(s2 * (1.f / 256) - mu * mu, 0.f);
      float rr = rsqrtf(var + 1e-5f);
      int gm = bm + wr + fq * 4 + j;
      __bf16* op = outb + (size_t)gm * 256;
#pragma unroll
      for (int n = 0; n < 16; ++n) {
        float y = (cj[n] - mu) * rr * gv[n] + bev[n];
        op[n * 16 + fr] = (__bf16)fmaxf(y, 0.f);
      }
    }
  } else {
    float w0[16], w1[16], w2[16];
#pragma unroll
    for (int n = 0; n < 16; ++n) {
      int col = n * 16 + fr;
      w0[n] = W2h[col * 3 + 0];
      w1[n] = W2h[col * 3 + 1];
      w2[n] = W2h[col * 3 + 2];
    }
    float* outf = (float*)outp;
#pragma unroll
    for (int j = 0; j < 4; ++j) {
      float p0 = 0.f, p1 = 0.f, p2 = 0.f;
#pragma unroll
      for (int n = 0; n < 16; ++n) {
        float h = fmaxf(acc[n][j] + cb[n], 0.f);
        p0 += h * w0[n]; p1 += h * w1[n]; p2 += h * w2[n];
      }
      p0 = red16(p0); p1 = red16(p1); p2 = red16(p2);
      int gm = bm + wr + fq * 4 + j;
      if (fr == 0 && gm < M) {
        float l0 = p0 + b2h[0], l1 = p1 + b2h[1], l2 = p2 + b2h[2];
        float m = fmaxf(l0, fmaxf(l1, l2));
        float lse = m + logf(__expf(l0 - m) + __expf(l1 - m) + __expf(l2 - m));
        outf[(size_t)gm * 3 + 0] = l0 - lse;
        outf[(size_t)gm * 3 + 1] = l1 - lse;
        outf[(size_t)gm * 3 + 2] = l2 - lse;
      }
    }
  }
}

// ---------------- lin2 GEMM + residual + fused LayerNorm+ReLU --------------
// MODE 0: write xres (no add) + LN->relu->bf16 hb      (layer 0)
// MODE 1: add xres, write xres + LN->relu->bf16 hb     (layers 1..L-2)
// MODE 2: add xres, LN->relu->f32 emb[node*256+half*128+col] (last layer)
template <int MODE>
__global__ __launch_bounds__(256) void gemm_lin2(
    const __bf16* __restrict__ A, const __bf16* __restrict__ BT,
    const float* __restrict__ bias, float* __restrict__ xres,
    const float* __restrict__ g, const float* __restrict__ be,
    void* __restrict__ lnout) {
  __shared__ __bf16 As[2][64][32];
  __shared__ __bf16 Bs[2][128][32];
  __shared__ float redS[64][2], redS2[64][2];
  const int tid = threadIdx.x;
  const int lane = tid & 63, w = tid >> 6;
  const int bm = blockIdx.x * 64;
  const int wr = (w >> 1) * 32, wc = (w & 1) * 64;
  const int fr = lane & 15, fq = lane >> 4;
  const int rowA = tid >> 2, chA = (tid & 3) * 8;
  const __bf16* Ab = A + (size_t)(bm + rowA) * 256 + chA;
  const __bf16* Bb = BT + (size_t)rowA * 256 + chA;
  const __bf16* Bb2 = Bb + (size_t)64 * 256;
  f32x4 acc[2][4] = {};

#define STAGE(buf, k0)                                  \
  do {                                                  \
    gload_lds16(Ab + (k0), &As[buf][rowA][chA]);        \
    gload_lds16(Bb + (k0), &Bs[buf][rowA][chA]);        \
    gload_lds16(Bb2 + (k0), &Bs[buf][rowA + 64][chA]);  \
  } while (0)

  STAGE(0, 0);
  __syncthreads();
  int cur = 0;
  for (int k0 = 0; k0 < 256; k0 += 32) {
    if (k0 + 32 < 256) STAGE(cur ^ 1, k0 + 32);
    bf16x8 af[2], bq[4];
#pragma unroll
    for (int m = 0; m < 2; ++m)
      af[m] = *(const bf16x8*)&As[cur][wr + m * 16 + fr][fq * 8];
#pragma unroll
    for (int n = 0; n < 4; ++n)
      bq[n] = *(const bf16x8*)&Bs[cur][wc + n * 16 + fr][fq * 8];
#pragma unroll
    for (int m = 0; m < 2; ++m)
#pragma unroll
      for (int n = 0; n < 4; ++n)
        acc[m][n] =
            __builtin_amdgcn_mfma_f32_16x16x32_bf16(af[m], bq[n], acc[m][n], 0, 0, 0);
    __syncthreads();
    cur ^= 1;
  }
#undef STAGE

  float cv[2][4][4];
#pragma unroll
  for (int m = 0; m < 2; ++m) {
    int r0 = wr + m * 16 + fq * 4;
#pragma unroll
    for (int j = 0; j < 4; ++j) {
      int gm = bm + r0 + j;
      float s = 0.f, s2 = 0.f;
#pragma unroll
      for (int n = 0; n < 4; ++n) {
        float c = acc[m][n][j] + bias[wc + n * 16 + fr];
        if (MODE != 0) c += xres[(size_t)gm * 128 + wc + n * 16 + fr];
        cv[m][n][j] = c;
        s += c; s2 += c * c;
      }
      s = red16(s); s2 = red16(s2);
      if (fr == 0) {
        redS[r0 + j][w & 1] = s;
        redS2[r0 + j][w & 1] = s2;
      }
    }
  }
  __syncthreads();
#pragma unroll
  for (int m = 0; m < 2; ++m) {
    int r0 = wr + m * 16 + fq * 4;
#pragma unroll
    for (int j = 0; j < 4; ++j) {
      int r = r0 + j;
      int gm = bm + r;
      float S = redS[r][0] + redS[r][1];
      float S2 = redS2[r][0] + redS2[r][1];
      float mu = S * (1.f / 128);
      float var = fmaxf(S2 * (1.f / 128) - mu * mu, 0.f);
      float rr = rsqrtf(var + 1e-5f);
      if constexpr (MODE < 2) {
        float* xp = xres + (size_t)gm * 128;
        __bf16* hp = (__bf16*)lnout + (size_t)gm * 128;
#pragma unroll
        for (int n = 0; n < 4; ++n) {
          int col = wc + n * 16 + fr;
          float c = cv[m][n][j];
          xp[col] = c;
          float y = (c - mu) * rr * g[col] + be[col];
          hp[col] = (__bf16)fmaxf(y, 0.f);
        }
      } else {
        int half = gm >= MP;
        int node = gm - half * MP;
        if (node < NN) {
          float* ep = (float*)lnout + (size_t)node * 256 + half * 128;
#pragma unroll
          for (int n = 0; n < 4; ++n) {
            int col = wc + n * 16 + fr;
            float y = (cv[m][n][j] - mu) * rr * g[col] + be[col];
            ep[col] = fmaxf(y, 0.f);
          }
        }
      }
    }
  }
}

// ---------------- fused prologue (vectorized) -------------------------------
struct WtDesc { const float* src; __bf16* dst; int K, N, Kpad; };
struct WtDescs { WtDesc d[10]; };
#define NF2B 20079  // ceil(NN*FF/2 / 256)
#define PADB 2422   // ceil(NN*31 / 256)
#define WTB 2880
#define CNTB 2500

__global__ void prep_kernel(const float* __restrict__ nf_src,
                            __bf16* __restrict__ nf_dst, WtDescs descs,
                            const int* __restrict__ edge_index,
                            int* __restrict__ deg, float* __restrict__ gp_sum) {
  int b = blockIdx.x, tid = threadIdx.x;
  if (b < NF2B) {
    int i = b * 256 + tid;  // float2 index
    if (i >= NN * FF / 2) return;
    int row = i / 257;
    int col = (i - row * 257) * 2;
    float2 v = ((const float2*)nf_src)[i];
    bf16x2 o; o[0] = (__bf16)v.x; o[1] = (__bf16)v.y;
    *(bf16x2*)(nf_dst + (size_t)row * 576 + col) = o;
  } else if (b < NF2B + PADB) {
    int i = (b - NF2B) * 256 + tid;
    if (i >= NN * 31) return;
    int row = i / 31, j = i - row * 31;
    bf16x2 z; z[0] = (__bf16)0.f; z[1] = (__bf16)0.f;
    *(bf16x2*)(nf_dst + (size_t)row * 576 + 514 + 2 * j) = z;
  } else if (b < NF2B + PADB + WTB) {
    int wb = b - NF2B - PADB;
    WtDesc de = descs.d[wb / 288];
    int idx = (wb % 288) * 256 + tid;
    if (idx >= de.N * de.Kpad) return;
    int n = idx / de.Kpad, k = idx - n * de.Kpad;
    float v = (k < de.K) ? de.src[(size_t)k * de.N + n] : 0.f;
    de.dst[idx] = (__bf16)v;
  } else if (b < NF2B + PADB + WTB + CNTB) {
    int i = (b - NF2B - PADB - WTB) * 256 + tid;
    if (i >= 2 * EE) return;
    int ti = (i >= EE) ? 1 : 0;
    int e = i - ti * EE;
    int d = edge_index[(size_t)ti * 2 * EE + EE + e];
    atomicAdd(&deg[ti * NN + d], 1);
  } else {
    gp_sum[tid] = 0.f;
  }
}

// ---------------- CSR scan (block per ti) ----------------
__global__ __launch_bounds__(1024) void scan2_kernel(
    const int* __restrict__ deg_all, int* __restrict__ rowptr,
    int* __restrict__ cursor) {
  const int ti = blockIdx.x;
  const int* deg = deg_all + ti * NN;
  __shared__ int sums[1024];
  int tid = threadIdx.x;
  int chunk = (NN + 1023) / 1024;
  int begin = tid * chunk, end = min(begin + chunk, NN);
  int s = 0;
  for (int i = begin; i < end; ++i) s += deg[i];
  sums[tid] = s;
  __syncthreads();
  for (int off = 1; off < 1024; off <<= 1) {
    int v = (tid >= off) ? sums[tid - off] : 0;
    __syncthreads();
    sums[tid] += v;
    __syncthreads();
  }
  int running = ti * EE + sums[tid] - s;
  for (int i = begin; i < end; ++i) {
    rowptr[ti * NN + i] = running;
    cursor[ti * NN + i] = running;
    running += deg[i];
  }
  if (tid == 0 && ti == 1) rowptr[2 * NN] = 2 * EE;
}

// ---------------- GENConv softmax aggregation + residual -------------------
// 4 nodes per wave: each 16-lane quarter owns ONE node and serially walks
// its edge list (2-edge unroll -> 2 gathers in flight). Channels are
// lane-owned (c15*4 within the ch-half) so NO cross-lane reduction at all.
// Per-wave setup (weights, t) amortized over 4 nodes. XCD quadrant pinning
// (ti, ch-half) via blockIdx&7 kept from R8 (FETCH == compulsory).
__global__ __launch_bounds__(256) void agg_kernel(
    const __bf16* __restrict__ xin, const int* __restrict__ rowptr,
    const Edge* __restrict__ edges, const float* __restrict__ Wee,
    const float* __restrict__ bee, const float* __restrict__ tptr, int layer,
    __bf16* __restrict__ out) {
  int wave = threadIdx.x >> 6, lane = threadIdx.x & 63;
  int b = blockIdx.x;  // 625 * 8 blocks
  int x8 = b & 7;
  int q = x8 >> 1;              // quadrant = ti*2 + chh
  int par = x8 & 1;
  int ti = q >> 1, chh = q & 1;
  int group = (b >> 3) * 2 + par;  // 0..1249, 16 nodes each
  int qq = lane >> 4, c15 = lane & 15;
  int node = group * 16 + wave * 4 + qq;  // 0..19999 (NN = 1250*16)
  int gnode = ti * NN + node;
  int xrow = ti * MP + node;
  float t2 = tptr[layer] * 1.4426950408889634f;
  int c0 = chh * 64 + c15 * 4;
  float den[4] = {}, num[4] = {};
  int e = rowptr[gnode];
  const int e1 = rowptr[gnode + 1];

  if (t2 > 0.f) {
    float w0p[4], w1p[4], bvp[4];
#pragma unroll
    for (int i = 0; i < 4; ++i) {
      w0p[i] = Wee[c0 + i] * t2;
      w1p[i] = Wee[HH + c0 + i] * t2;
      bvp[i] = bee[c0 + i] * t2;
    }
#define MLPF(XV, ED)                                                      \
  do {                                                                    \
    float eax = (float)(ED).ea0, eay = (float)(ED).ea1;                   \
    _Pragma("unroll") for (int i = 0; i < 4; ++i) {                       \
      float te = fmaf(eax, w0p[i], fmaf(eay, w1p[i], bvp[i]));            \
      float sm = fmaxf(fmaf((float)(XV)[i], t2, te), 0.f);                \
      float ex = fexp2(sm);                                               \
      den[i] += ex; num[i] = fmaf(sm, ex, num[i]);                        \
    }                                                                     \
  } while (0)
    for (; e + 2 <= e1; e += 2) {
      Edge E0 = edges[e];
      Edge E1 = edges[e + 1];
      bf16x4 x0 = *(const bf16x4*)(xin + (size_t)E0.src * HH + c0);
      bf16x4 x1 = *(const bf16x4*)(xin + (size_t)E1.src * HH + c0);
      MLPF(x0, E0);
      MLPF(x1, E1);
    }
    if (e < e1) {
      Edge E0 = edges[e];
      bf16x4 x0 = *(const bf16x4*)(xin + (size_t)E0.src * HH + c0);
      MLPF(x0, E0);
    }
#undef MLPF
    bf16x4 xr = *(const bf16x4*)(xin + (size_t)xrow * HH + c0);
    bf16x4 o;
#pragma unroll
    for (int i = 0; i < 4; ++i)
      o[i] = (__bf16)(num[i] / (t2 * (den[i] + 1e-16f)) + (float)xr[i]);
    *(bf16x4*)(out + (size_t)xrow * HH + c0) = o;
  } else {
    // general (t2 <= 0) fallback: reference formula
    float w0[4], w1[4], bv[4];
#pragma unroll
    for (int i = 0; i < 4; ++i) {
      w0[i] = Wee[c0 + i];
      w1[i] = Wee[HH + c0 + i];
      bv[i] = bee[c0 + i];
    }
    for (; e < e1; ++e) {
      Edge E0 = edges[e];
      bf16x4 xv = *(const bf16x4*)(xin + (size_t)E0.src * HH + c0);
      float eax = (float)E0.ea0, eay = (float)E0.ea1;
#pragma unroll
      for (int i = 0; i < 4; ++i) {
        float m =
            fmaxf((float)xv[i] + eax * w0[i] + eay * w1[i] + bv[i], 0.f) + 1e-7f;
        float ex = fexp2(m * t2);
        den[i] += ex; num[i] += m * ex;
      }
    }
    bf16x4 xr = *(const bf16x4*)(xin + (size_t)xrow * HH + c0);
    bf16x4 o;
#pragma unroll
    for (int i = 0; i < 4; ++i)
      o[i] = (__bf16)(num[i] / (den[i] + 1e-16f) + (float)xr[i]);
    *(bf16x4*)(out + (size_t)xrow * HH + c0) = o;
  }
}

// ---------------- fused channel attention (node out + graph partial-pool) --
__global__ __launch_bounds__(256) void attn2_kernel(
    const float* __restrict__ emb, const float* __restrict__ Wq_n,
    const float* __restrict__ Wk_n, const float* __restrict__ Wv_n,
    const float* __restrict__ gn, const float* __restrict__ Wq_g,
    const float* __restrict__ Wk_g, const float* __restrict__ Wv_g,
    const float* __restrict__ gg, __bf16* __restrict__ outn,
    float* __restrict__ partial) {
  __shared__ float gsum[4][256];
  int wave = threadIdx.x >> 6, lane = threadIdx.x & 63;
  int tid = threadIdx.x;
  int n = blockIdx.x * 4 + wave;  // NN % 4 == 0: always valid
  int c0 = lane * 2;
  const float* base = emb + (size_t)n * (2 * HH);
  float2 x0 = *(const float2*)(base + c0);
  float2 x1 = *(const float2*)(base + HH + c0);

#define ATTN_BODY(Wq, Wk, Wv, GAM, O0A, O0B, O1A, O1B)                        \
  {                                                                           \
    float gamma = *(GAM);                                                     \
    float wq00 = Wq[0], wq01 = Wq[1], wq10 = Wq[2], wq11 = Wq[3];             \
    float wk00 = Wk[0], wk01 = Wk[1], wk10 = Wk[2], wk11 = Wk[3];             \
    float wv00 = Wv[0], wv01 = Wv[1], wv10 = Wv[2], wv11 = Wv[3];             \
    float q0a = wq00 * x0.x + wq01 * x1.x, q0b = wq00 * x0.y + wq01 * x1.y;   \
    float q1a = wq10 * x0.x + wq11 * x1.x, q1b = wq10 * x0.y + wq11 * x1.y;   \
    float k0a = wk00 * x0.x + wk01 * x1.x, k0b = wk00 * x0.y + wk01 * x1.y;   \
    float k1a = wk10 * x0.x + wk11 * x1.x, k1b = wk10 * x0.y + wk11 * x1.y;   \
    float v0a = wv00 * x0.x + wv01 * x1.x, v0b = wv00 * x0.y + wv01 * x1.y;   \
    float v1a = wv10 * x0.x + wv11 * x1.x, v1b = wv10 * x0.y + wv11 * x1.y;   \
    float s00 = wave_sum(q0a * k0a + q0b * k0b);                              \
    float s01 = wave_sum(q0a * k1a + q0b * k1b);                              \
    float s10 = wave_sum(q1a * k0a + q1b * k0b);                              \
    float s11 = wave_sum(q1a * k1a + q1b * k1b);                              \
    float m0 = fmaxf(s00, s01);                                               \
    float e00 = __expf(s00 - m0), e01 = __expf(s01 - m0);                     \
    float i0 = 1.f / (e00 + e01);                                             \
    float a00 = e00 * i0, a01 = e01 * i0;                                     \
    float m1 = fmaxf(s10, s11);                                               \
    float e10 = __expf(s10 - m1), e11 = __expf(s11 - m1);                     \
    float i1 = 1.f / (e10 + e11);                                             \
    float a10 = e10 * i1, a11 = e11 * i1;                                     \
    O0A = gamma * (a00 * v0a + a01 * v1a) + x0.x;                             \
    O0B = gamma * (a00 * v0b + a01 * v1b) + x0.y;                             \
    O1A = gamma * (a10 * v0a + a11 * v1a) + x1.x;                             \
    O1B = gamma * (a10 * v0b + a11 * v1b) + x1.y;                             \
  }

  float n0a, n0b, n1a, n1b;
  ATTN_BODY(Wq_n, Wk_n, Wv_n, gn, n0a, n0b, n1a, n1b);
  __bf16* opn = outn + (size_t)n * (2 * HH);
  bf16x2 t0; t0[0] = (__bf16)n0a; t0[1] = (__bf16)n0b;
  bf16x2 t1; t1[0] = (__bf16)n1a; t1[1] = (__bf16)n1b;
  *(bf16x2*)(opn + c0) = t0;
  *(bf16x2*)(opn + HH + c0) = t1;

  float g0a, g0b, g1a, g1b;
  ATTN_BODY(Wq_g, Wk_g, Wv_g, gg, g0a, g0b, g1a, g1b);
  gsum[wave][c0] = g0a;
  gsum[wave][c0 + 1] = g0b;
  gsum[wave][128 + c0] = g1a;
  gsum[wave][129 + c0] = g1b;
  __syncthreads();
  partial[(size_t)blockIdx.x * 256 + tid] =
      gsum[0][tid] + gsum[1][tid] + gsum[2][tid] + gsum[3][tid];
#undef ATTN_BODY
}

// ---------------- pool over per-block partials ----------------
__global__ __launch_bounds__(256) void pool_kernel(const float* __restrict__ partial,
                                                   float* __restrict__ gp_sum,
                                                   int nRows) {
  int c = threadIdx.x;
  float s = 0.f;
  for (int r = blockIdx.x; r < nRows; r += gridDim.x)
    s += partial[(size_t)r * 256 + c];
  atomicAdd(&gp_sum[c], s);
}

// ---------------- graph head (single block) ----------------
__global__ __launch_bounds__(256) void graph_head_kernel(
    const float* __restrict__ gp_sum, const float* __restrict__ Wg1,
    const float* __restrict__ bg1, const float* __restrict__ Wg2,
    const float* __restrict__ bg2, float* __restrict__ outp, float invN) {
  __shared__ float gp[256];
  __shared__ float h1[256];
  __shared__ float lg[2];
  int tid = threadIdx.x;
  gp[tid] = gp_sum[tid] * invN;
  __syncthreads();
  float acc = bg1[tid];
  for (int k = 0; k < 256; ++k) acc += gp[k] * Wg1[k * 256 + tid];
  h1[tid] = fmaxf(acc, 0.f);
  __syncthreads();
  if (tid < 2) {
    float l = bg2[tid];
    for (int c = 0; c < 256; ++c) l += h1[c] * Wg2[c * 2 + tid];
    lg[tid] = l;
  }
  __syncthreads();
  if (tid == 0) {
    float m = fmaxf(lg[0], lg[1]);
    float lse = m + logf(__expf(lg[0] - m) + __expf(lg[1] - m));
    outp[0] = lg[0] - lse;
    outp[1] = lg[1] - lse;
  }
}

// ---------------- launch ----------------
extern "C" void kernel_launch(void* const* d_in, const int* in_sizes, int n_in,
                              void* d_out, int out_size, void* d_ws, size_t ws_size,
                              hipStream_t stream) {
  (void)in_sizes; (void)n_in; (void)out_size; (void)ws_size;
  const float* node_feature = (const float*)d_in[0];
  const int* edge_index = (const int*)d_in[1];
  const float* edge_attr = (const float*)d_in[2];
  const float* Wne = (const float*)d_in[3];
  const float* bne = (const float*)d_in[4];
  const float* Wee = (const float*)d_in[5];
  const float* bee = (const float*)d_in[6];
  const float* W1 = (const float*)d_in[7];
  const float* b1 = (const float*)d_in[8];
  const float* g1 = (const float*)d_in[9];
  const float* be1 = (const float*)d_in[10];
  const float* W2 = (const float*)d_in[11];
  const float* b2 = (const float*)d_in[12];
  const float* dg = (const float*)d_in[13];
  const float* db = (const float*)d_in[14];
  const float* tpar = (const float*)d_in[15];
  const float* Wq_n = (const float*)d_in[16];
  const float* Wk_n = (const float*)d_in[17];
  const float* Wv_n = (const float*)d_in[18];
  const float* gamma_n = (const float*)d_in[19];
  const float* Wn1 = (const float*)d_in[20];
  const float* bn1 = (const float*)d_in[21];
  const float* Wn2 = (const float*)d_in[22];
  const float* bn2 = (const float*)d_in[23];
  const float* Wq_g = (const float*)d_in[24];
  const float* Wk_g = (const float*)d_in[25];
  const float* Wv_g = (const float*)d_in[26];
  const float* gamma_g = (const float*)d_in[27];
  const float* Wg1 = (const float*)d_in[28];
  const float* bg1 = (const float*)d_in[29];
  const float* Wg2 = (const float*)d_in[30];
  const float* bg2 = (const float*)d_in[31];
  float* out = (float*)d_out;

  // ---- workspace carve-out (256B-aligned regions) ----
  char* pc = (char*)d_ws;
  auto alloc = [&](size_t bytes) {
    char* r = pc;
    pc += (bytes + 255) & ~(size_t)255;
    return r;
  };
  float* xbuf = (float*)alloc((size_t)2 * MP * HH * 4);       // f32 residual
  __bf16* hbuf_b = (__bf16*)alloc((size_t)2 * MP * HH * 2);   // LN'd agg input
  __bf16* t256_b = (__bf16*)alloc((size_t)2 * MP * 256 * 2);  // lin1+LN out
  float* emb = (float*)alloc((size_t)NN * 2 * HH * 4);        // [N,T,H] f32
  __bf16* aggout_b = (__bf16*)alloc((size_t)2 * MP * HH * 2); // agg out
  __bf16* nf_b = (__bf16*)emb;  // 23.0MB <= emb(20.5)+aggout(10.3)
  __bf16* attnb = t256_b;       // alias: node-attn out (after last lin2)
  float* partial = xbuf;        // alias: graph-attn partials [5000][256]
  __bf16* wt_ne = (__bf16*)alloc((size_t)128 * 576 * 2);
  __bf16* wt1 = (__bf16*)alloc((size_t)4 * 256 * 128 * 2);
  __bf16* wt2 = (__bf16*)alloc((size_t)4 * 128 * 256 * 2);
  __bf16* wtn1 = (__bf16*)alloc((size_t)256 * 256 * 2);
  float* gp_sum = (float*)alloc(256 * 4);
  int* deg = (int*)alloc((size_t)2 * NN * 4);
  int* cursor = (int*)alloc((size_t)2 * NN * 4);
  int* rowptr = (int*)alloc((size_t)(2 * NN + 2) * 4);
  Edge* edges = (Edge*)alloc((size_t)2 * EE * 8);

  const int gRows2 = 2 * MP / 64;  // 628 row-blocks, stacked GEMMs

  WtDescs wd;
  wd.d[0] = {Wne, wt_ne, FF, HH, 576};
  for (int l = 0; l < 4; ++l)
    wd.d[1 + l] = {W1 + (size_t)l * HH * 256, wt1 + (size_t)l * 256 * HH, HH, 256, HH};
  for (int l = 0; l < 4; ++l)
    wd.d[5 + l] = {W2 + (size_t)l * 256 * HH, wt2 + (size_t)l * HH * 256, 256, HH, 256};
  wd.d[9] = {Wn1, wtn1, 256, 256, 256};

  // prologue: deg zero; converts (vectorized) + degree count + gp_sum zero
  hipMemsetAsync(deg, 0, 2 * NN * sizeof(int), stream);
  prep_kernel<<<NF2B + PADB + WTB + CNTB + 1, 256, 0, stream>>>(
      node_feature, nf_b, wd, edge_index, deg, gp_sum);
  scan2_kernel<<<2, 1024, 0, stream>>>(deg, rowptr, cursor);
  // encoder GEMM (dup to both halves) fused with XCD-routed edge scatter
  enc_scatter_kernel<<<ENCB + 8 * SCB, 256, 0, stream>>>(
      nf_b, wt_ne, bne, hbuf_b, edge_index, edge_attr, cursor, edges);

  // layer loop, both ti at once
  for (int l = 0; l < LL; ++l) {
    agg_kernel<<<625 * 8, 256, 0, stream>>>(hbuf_b, rowptr, edges, Wee, bee, tpar,
                                            l, aggout_b);
    gemm256<0><<<gRows2, 256, 0, stream>>>(aggout_b, wt1 + (size_t)l * 256 * HH,
                                           b1 + l * 2 * HH, g1 + l * 2 * HH,
                                           be1 + l * 2 * HH, nullptr, nullptr, t256_b,
                                           2 * MP, HH);
    const __bf16* w2l = wt2 + (size_t)l * HH * 256;
    const float* b2l = b2 + l * HH;
    if (l == 0)
      gemm_lin2<0><<<gRows2, 256, 0, stream>>>(t256_b, w2l, b2l, xbuf, dg + 1 * HH,
                                               db + 1 * HH, hbuf_b);
    else if (l < LL - 1)
      gemm_lin2<1><<<gRows2, 256, 0, stream>>>(t256_b, w2l, b2l, xbuf,
                                               dg + (l + 1) * HH, db + (l + 1) * HH,
                                               hbuf_b);
    else
      gemm_lin2<2><<<gRows2, 256, 0, stream>>>(t256_b, w2l, b2l, xbuf, dg, db, emb);
  }

  // fused node+graph attention (one emb read; graph branch -> LDS partials)
  attn2_kernel<<<NN / 4, 256, 0, stream>>>(emb, Wq_n, Wk_n, Wv_n, gamma_n, Wq_g,
                                           Wk_g, Wv_g, gamma_g, attnb, partial);
  // node head: lin1+relu+Wn2+log_softmax fused
  gemm256<1><<<MP / 64, 256, 0, stream>>>(attnb, wtn1, bn1, nullptr, nullptr, Wn2,
                                          bn2, out, NN, 256);
  // graph head
  pool_kernel<<<128, 256, 0, stream>>>(partial, gp_sum, NN / 4);
  graph_head_kernel<<<1, 256, 0, stream>>>(gp_sum, Wg1, bg1, Wg2, bg2,
                                           out + (size_t)NN * CN, 1.0f / NN);
}

// Round 12
// 442.478 us; speedup vs baseline: 1.3483x; 1.0024x over previous
//
#include <hip/hip_runtime.h>

#define NN 20000
#define TT 2
#define HH 128
#define LL 4
#define EE 320000
#define FF 514
#define CN 3
#define CG 2
#define MP 20096  // rows per ti-half, padded to multiple of 128

typedef __bf16 bf16x8 __attribute__((ext_vector_type(8)));
typedef __bf16 bf16x4 __attribute__((ext_vector_type(4)));
typedef __bf16 bf16x2 __attribute__((ext_vector_type(2)));
typedef float f32x4 __attribute__((ext_vector_type(4)));

struct __align__(8) Edge { int src; __bf16 ea0, ea1; };

// ---------------- wave helpers ----------------
__device__ inline float wave_sum(float v) {
#pragma unroll
  for (int off = 32; off; off >>= 1) v += __shfl_xor(v, off);
  return v;
}
__device__ inline float red16(float v) {  // reduce across fr = lane&15
  v += __shfl_xor(v, 1); v += __shfl_xor(v, 2);
  v += __shfl_xor(v, 4); v += __shfl_xor(v, 8);
  return v;
}

__device__ __forceinline__ float fexp2(float x) {
#if __has_builtin(__builtin_amdgcn_exp2f)
  return __builtin_amdgcn_exp2f(x);
#else
  return exp2f(x);
#endif
}

__device__ __forceinline__ void gload_lds16(const void* g, void* l) {
  __builtin_amdgcn_global_load_lds(
      (const __attribute__((address_space(1))) unsigned int*)g,
      (__attribute__((address_space(3))) unsigned int*)l, 16, 0, 0);
}

// ---------------- fused encoder GEMM + XCD-routed edge scatter --------------
// blocks [0, ENCB): encoder GEMM (BM=64, K=576), dup rows to both halves.
// blocks [ENCB, ENCB+8*SSB): scatter. Block = (slice, chunk); thread owns 8
// consecutive edges of the slice: reads dst x8 once (32 B), loads src/ea only
// for edges whose dst-chunk == chunk (XCD-local L2 writes).
#define ENCB (MP / 64)
#define SSB 313   // ceil(2*EE / (256*8))
#define CHUNK 5000  // 2*NN/8 gnodes per XCD chunk
__global__ __launch_bounds__(256) void enc_scatter_kernel(
    const __bf16* __restrict__ A, const __bf16* __restrict__ BT,
    const float* __restrict__ bias, __bf16* __restrict__ C,
    const int* __restrict__ edge_index, const float* __restrict__ edge_attr,
    int* __restrict__ cursor, Edge* __restrict__ edges) {
  __shared__ __bf16 As[2][64][32];
  __shared__ __bf16 Bs[2][128][32];
  const int tid = threadIdx.x;
  if (blockIdx.x >= ENCB) {
    int sb = blockIdx.x - ENCB;
    int chunk = sb & 7;
    int slice = sb >> 3;
    int i0 = slice * 2048 + tid * 8;  // multiple of 8; EE%8==0 so no ti straddle
    if (i0 >= 2 * EE) return;
    int ti = (i0 >= EE) ? 1 : 0;
    int e0 = i0 - ti * EE;
    const int* srcp = edge_index + (size_t)ti * 2 * EE;
    int dst8[8];
    __builtin_memcpy(dst8, srcp + EE + e0, 32);
#pragma unroll
    for (int j = 0; j < 8; ++j) {
      int gnode = ti * NN + dst8[j];
      if (gnode / CHUNK != chunk) continue;
      int s = srcp[e0 + j];
      float2 ea = ((const float2*)edge_attr)[(size_t)ti * EE + e0 + j];
      int pos = atomicAdd(&cursor[gnode], 1);
      Edge ed;
      ed.src = s + ti * MP;
      ed.ea0 = (__bf16)ea.x; ed.ea1 = (__bf16)ea.y;
      __builtin_memcpy(&edges[pos], &ed, sizeof(Edge));
    }
    return;
  }
  const int K = 576;
  const int lane = tid & 63, w = tid >> 6;
  const int bm = blockIdx.x * 64;
  const int wr = (w >> 1) * 32, wc = (w & 1) * 64;
  const int fr = lane & 15, fq = lane >> 4;
  const int rowA = tid >> 2, chA = (tid & 3) * 8;
  const __bf16* Ab = A + (size_t)(bm + rowA) * K + chA;
  const __bf16* Bb = BT + (size_t)rowA * K + chA;
  const __bf16* Bb2 = Bb + (size_t)64 * K;
  f32x4 acc[2][4] = {};
#define STAGE(buf, k0)                                  \
  do {                                                  \
    gload_lds16(Ab + (k0), &As[buf][rowA][chA]);        \
    gload_lds16(Bb + (k0), &Bs[buf][rowA][chA]);        \
    gload_lds16(Bb2 + (k0), &Bs[buf][rowA + 64][chA]);  \
  } while (0)
  STAGE(0, 0);
  __syncthreads();
  int cur = 0;
  for (int k0 = 0; k0 < K; k0 += 32) {
    if (k0 + 32 < K) STAGE(cur ^ 1, k0 + 32);
    bf16x8 af[2], bq[4];
#pragma unroll
    for (int m = 0; m < 2; ++m)
      af[m] = *(const bf16x8*)&As[cur][wr + m * 16 + fr][fq * 8];
#pragma unroll
    for (int n = 0; n < 4; ++n)
      bq[n] = *(const bf16x8*)&Bs[cur][wc + n * 16 + fr][fq * 8];
#pragma unroll
    for (int m = 0; m < 2; ++m)
#pragma unroll
      for (int n = 0; n < 4; ++n)
        acc[m][n] =
            __builtin_amdgcn_mfma_f32_16x16x32_bf16(af[m], bq[n], acc[m][n], 0, 0, 0);
    __syncthreads();
    cur ^= 1;
  }
#undef STAGE
#pragma unroll
  for (int m = 0; m < 2; ++m) {
#pragma unroll
    for (int n = 0; n < 4; ++n) {
#pragma unroll
      for (int j = 0; j < 4; ++j) {
        int gm = bm + wr + m * 16 + fq * 4 + j;
        int gn = wc + n * 16 + fr;
        if (gm < NN) {
          __bf16 c = (__bf16)(acc[m][n][j] + bias[gn]);
          C[(size_t)gm * 128 + gn] = c;
          C[(size_t)(gm + MP) * 128 + gn] = c;
        }
      }
    }
  }
}

// ---------------- fused 256-wide GEMM (BM=64, BN=256, full row per wave) ----
template <int EPI>
__global__ __launch_bounds__(256) void gemm256(
    const __bf16* __restrict__ A, const __bf16* __restrict__ BT,
    const float* __restrict__ bias, const float* __restrict__ g,
    const float* __restrict__ be, const float* __restrict__ W2h,
    const float* __restrict__ b2h, void* __restrict__ outp, int M, int K) {
  __shared__ __bf16 As[2][64][32];
  __shared__ __bf16 Bs[2][256][32];
  const int tid = threadIdx.x;
  const int lane = tid & 63, w = tid >> 6;
  const int bm = blockIdx.x * 64;
  const int wr = w * 16;
  const int fr = lane & 15, fq = lane >> 4;
  const int rowA = tid >> 2, chA = (tid & 3) * 8;
  const __bf16* Ab = A + (size_t)(bm + rowA) * K + chA;
  const __bf16* Bb = BT + (size_t)rowA * K + chA;
  f32x4 acc[16] = {};

#define STG(buf, k0)                                                \
  do {                                                              \
    gload_lds16(Ab + (k0), &As[buf][rowA][chA]);                    \
    _Pragma("unroll") for (int r = 0; r < 4; ++r)                   \
        gload_lds16(Bb + (size_t)(r * 64) * K + (k0),               \
                    &Bs[buf][rowA + r * 64][chA]);                  \
  } while (0)

  STG(0, 0);
  __syncthreads();
  int cur = 0;
  for (int k0 = 0; k0 < K; k0 += 32) {
    if (k0 + 32 < K) STG(cur ^ 1, k0 + 32);
    bf16x8 af = *(const bf16x8*)&As[cur][wr + fr][fq * 8];
#pragma unroll
    for (int n = 0; n < 16; ++n) {
      bf16x8 bq = *(const bf16x8*)&Bs[cur][n * 16 + fr][fq * 8];
      acc[n] = __builtin_amdgcn_mfma_f32_16x16x32_bf16(af, bq, acc[n], 0, 0, 0);
    }
    __syncthreads();
    cur ^= 1;
  }
#undef STG

  float cb[16];
#pragma unroll
  for (int n = 0; n < 16; ++n) cb[n] = bias[n * 16 + fr];

  if constexpr (EPI == 0) {
    float gv[16], bev[16];
#pragma unroll
    for (int n = 0; n < 16; ++n) {
      gv[n] = g[n * 16 + fr];
      bev[n] = be[n * 16 + fr];
    }
    __bf16* outb = (__bf16*)outp;
#pragma unroll
    for (int j = 0; j < 4; ++j) {
      float cj[16], s = 0.f, s2 = 0.f;
#pragma unroll
      for (int n = 0; n < 16; ++n) {
        float c = acc[n][j] + cb[n];
        cj[n] = c; s += c; s2 += c * c;
      }
      s = red16(s); s2 = red16(s2);
      float mu = s * (1.f / 256);
      float var = fmaxf(s2 * (1.f / 256) - mu * mu, 0.f);
      float rr = rsqrtf(var + 1e-5f);
      int gm = bm + wr + fq * 4 + j;
      __bf16* op = outb + (size_t)gm * 256;
#pragma unroll
      for (int n = 0; n < 16; ++n) {
        float y = (cj[n] - mu) * rr * gv[n] + bev[n];
        op[n * 16 + fr] = (__bf16)fmaxf(y, 0.f);
      }
    }
  } else {
    float w0[16], w1[16], w2[16];
#pragma unroll
    for (int n = 0; n < 16; ++n) {
      int col = n * 16 + fr;
      w0[n] = W2h[col * 3 + 0];
      w1[n] = W2h[col * 3 + 1];
      w2[n] = W2h[col * 3 + 2];
    }
    float* outf = (float*)outp;
#pragma unroll
    for (int j = 0; j < 4; ++j) {
      float p0 = 0.f, p1 = 0.f, p2 = 0.f;
#pragma unroll
      for (int n = 0; n < 16; ++n) {
        float h = fmaxf(acc[n][j] + cb[n], 0.f);
        p0 += h * w0[n]; p1 += h * w1[n]; p2 += h * w2[n];
      }
      p0 = red16(p0); p1 = red16(p1); p2 = red16(p2);
      int gm = bm + wr + fq * 4 + j;
      if (fr == 0 && gm < M) {
        float l0 = p0 + b2h[0], l1 = p1 + b2h[1], l2 = p2 + b2h[2];
        float m = fmaxf(l0, fmaxf(l1, l2));
        float lse = m + logf(__expf(l0 - m) + __expf(l1 - m) + __expf(l2 - m));
        outf[(size_t)gm * 3 + 0] = l0 - lse;
        outf[(size_t)gm * 3 + 1] = l1 - lse;
        outf[(size_t)gm * 3 + 2] = l2 - lse;
      }
    }
  }
}

// ---------------- lin2 GEMM + residual + fused LayerNorm+ReLU --------------
// MODE 0: write xres (no add) + LN->relu->bf16 hb      (layer 0)
// MODE 1: add xres, write xres + LN->relu->bf16 hb     (layers 1..L-2)
// MODE 2: add xres, LN->relu->f32 emb[node*256+half*128+col] (last layer)
template <int MODE>
__global__ __launch_bounds__(256) void gemm_lin2(
    const __bf16* __restrict__ A, const __bf16* __restrict__ BT,
    const float* __restrict__ bias, float* __restrict__ xres,
    const float* __restrict__ g, const float* __restrict__ be,
    void* __restrict__ lnout) {
  __shared__ __bf16 As[2][64][32];
  __shared__ __bf16 Bs[2][128][32];
  __shared__ float redS[64][2], redS2[64][2];
  const int tid = threadIdx.x;
  const int lane = tid & 63, w = tid >> 6;
  const int bm = blockIdx.x * 64;
  const int wr = (w >> 1) * 32, wc = (w & 1) * 64;
  const int fr = lane & 15, fq = lane >> 4;
  const int rowA = tid >> 2, chA = (tid & 3) * 8;
  const __bf16* Ab = A + (size_t)(bm + rowA) * 256 + chA;
  const __bf16* Bb = BT + (size_t)rowA * 256 + chA;
  const __bf16* Bb2 = Bb + (size_t)64 * 256;
  f32x4 acc[2][4] = {};

#define STAGE(buf, k0)                                  \
  do {                                                  \
    gload_lds16(Ab + (k0), &As[buf][rowA][chA]);        \
    gload_lds16(Bb + (k0), &Bs[buf][rowA][chA]);        \
    gload_lds16(Bb2 + (k0), &Bs[buf][rowA + 64][chA]);  \
  } while (0)

  STAGE(0, 0);
  __syncthreads();
  int cur = 0;
  for (int k0 = 0; k0 < 256; k0 += 32) {
    if (k0 + 32 < 256) STAGE(cur ^ 1, k0 + 32);
    bf16x8 af[2], bq[4];
#pragma unroll
    for (int m = 0; m < 2; ++m)
      af[m] = *(const bf16x8*)&As[cur][wr + m * 16 + fr][fq * 8];
#pragma unroll
    for (int n = 0; n < 4; ++n)
      bq[n] = *(const bf16x8*)&Bs[cur][wc + n * 16 + fr][fq * 8];
#pragma unroll
    for (int m = 0; m < 2; ++m)
#pragma unroll
      for (int n = 0; n < 4; ++n)
        acc[m][n] =
            __builtin_amdgcn_mfma_f32_16x16x32_bf16(af[m], bq[n], acc[m][n], 0, 0, 0);
    __syncthreads();
    cur ^= 1;
  }
#undef STAGE

  float cv[2][4][4];
#pragma unroll
  for (int m = 0; m < 2; ++m) {
    int r0 = wr + m * 16 + fq * 4;
#pragma unroll
    for (int j = 0; j < 4; ++j) {
      int gm = bm + r0 + j;
      float s = 0.f, s2 = 0.f;
#pragma unroll
      for (int n = 0; n < 4; ++n) {
        float c = acc[m][n][j] + bias[wc + n * 16 + fr];
        if (MODE != 0) c += xres[(size_t)gm * 128 + wc + n * 16 + fr];
        cv[m][n][j] = c;
        s += c; s2 += c * c;
      }
      s = red16(s); s2 = red16(s2);
      if (fr == 0) {
        redS[r0 + j][w & 1] = s;
        redS2[r0 + j][w & 1] = s2;
      }
    }
  }
  __syncthreads();
#pragma unroll
  for (int m = 0; m < 2; ++m) {
    int r0 = wr + m * 16 + fq * 4;
#pragma unroll
    for (int j = 0; j < 4; ++j) {
      int r = r0 + j;
      int gm = bm + r;
      float S = redS[r][0] + redS[r][1];
      float S2 = redS2[r][0] + redS2[r][1];
      float mu = S * (1.f / 128);
      float var = fmaxf(S2 * (1.f / 128) - mu * mu, 0.f);
      float rr = rsqrtf(var + 1e-5f);
      if constexpr (MODE < 2) {
        float* xp = xres + (size_t)gm * 128;
        __bf16* hp = (__bf16*)lnout + (size_t)gm * 128;
#pragma unroll
        for (int n = 0; n < 4; ++n) {
          int col = wc + n * 16 + fr;
          float c = cv[m][n][j];
          xp[col] = c;
          float y = (c - mu) * rr * g[col] + be[col];
          hp[col] = (__bf16)fmaxf(y, 0.f);
        }
      } else {
        int half = gm >= MP;
        int node = gm - half * MP;
        if (node < NN) {
          float* ep = (float*)lnout + (size_t)node * 256 + half * 128;
#pragma unroll
          for (int n = 0; n < 4; ++n) {
            int col = wc + n * 16 + fr;
            float y = (cv[m][n][j] - mu) * rr * g[col] + be[col];
            ep[col] = fmaxf(y, 0.f);
          }
        }
      }
    }
  }
}

// ---------------- fused prologue (grid-stride, 8 elem/thread) ---------------
// item space: [0, NFG) nf convert+pad (8 cols) | [NFG, +WTG) weight transpose
// (8 k's) | [+CTG) degree count (8 edges). gp_sum zeroed by block 0.
struct WtDesc { const float* src; __bf16* dst; int K, N, Kpad, gbase; };
struct WtDescs { WtDesc d[10]; };
#define NFG 1440000  // NN * 576 / 8
#define WTG 50176    // sum(N*Kpad)/8
#define CTG 80000    // 2*EE / 8
#define PREPG 2048   // grid blocks

__global__ __launch_bounds__(256) void prep_kernel(
    const float* __restrict__ nf_src, __bf16* __restrict__ nf_dst, WtDescs descs,
    const int* __restrict__ edge_index, int* __restrict__ deg,
    float* __restrict__ gp_sum) {
  const int tid = threadIdx.x;
  if (blockIdx.x == 0) gp_sum[tid] = 0.f;
  const int TOT = NFG + WTG + CTG;
  for (int g = blockIdx.x * 256 + tid; g < TOT; g += PREPG * 256) {
    if (g < NFG) {
      int row = g / 72, colg = g - row * 72;
      int col0 = colg * 8;
      bf16x8 o;
      if (col0 + 8 <= FF) {
        float v[8];
        __builtin_memcpy(v, nf_src + (size_t)row * FF + col0, 32);
#pragma unroll
        for (int i = 0; i < 8; ++i) o[i] = (__bf16)v[i];
      } else {
#pragma unroll
        for (int i = 0; i < 8; ++i) {
          int col = col0 + i;
          o[i] = (__bf16)((col < FF) ? nf_src[(size_t)row * FF + col] : 0.f);
        }
      }
      *(bf16x8*)(nf_dst + (size_t)row * 576 + col0) = o;
    } else if (g < NFG + WTG) {
      int wb = g - NFG;
      // find descriptor (<=10-step scan)
      int di = 0;
#pragma unroll
      for (int t = 1; t < 10; ++t)
        if (wb >= descs.d[t].gbase) di = t;
      WtDesc de = descs.d[di];
      int local = wb - de.gbase;
      int kg8 = de.Kpad >> 3;
      int n = local / kg8, k0 = (local - n * kg8) * 8;
      bf16x8 o;
#pragma unroll
      for (int i = 0; i < 8; ++i) {
        int k = k0 + i;
        o[i] = (__bf16)((k < de.K) ? de.src[(size_t)k * de.N + n] : 0.f);
      }
      *(bf16x8*)(de.dst + (size_t)n * de.Kpad + k0) = o;
    } else {
      int i0 = (g - NFG - WTG) * 8;  // multiple of 8; EE%8==0 -> no straddle
      int ti = (i0 >= EE) ? 1 : 0;
      int e0 = i0 - ti * EE;
      int dst8[8];
      __builtin_memcpy(dst8, edge_index + (size_t)ti * 2 * EE + EE + e0, 32);
      int* dbase = deg + ti * NN;
#pragma unroll
      for (int j = 0; j < 8; ++j) atomicAdd(&dbase[dst8[j]], 1);
    }
  }
}

// ---------------- CSR scan (block per ti) ----------------
__global__ __launch_bounds__(1024) void scan2_kernel(
    const int* __restrict__ deg_all, int* __restrict__ rowptr,
    int* __restrict__ cursor) {
  const int ti = blockIdx.x;
  const int* deg = deg_all + ti * NN;
  __shared__ int sums[1024];
  int tid = threadIdx.x;
  int chunk = (NN + 1023) / 1024;
  int begin = tid * chunk, end = min(begin + chunk, NN);
  int s = 0;
  for (int i = begin; i < end; ++i) s += deg[i];
  sums[tid] = s;
  __syncthreads();
  for (int off = 1; off < 1024; off <<= 1) {
    int v = (tid >= off) ? sums[tid - off] : 0;
    __syncthreads();
    sums[tid] += v;
    __syncthreads();
  }
  int running = ti * EE + sums[tid] - s;
  for (int i = begin; i < end; ++i) {
    rowptr[ti * NN + i] = running;
    cursor[ti * NN + i] = running;
    running += deg[i];
  }
  if (tid == 0 && ti == 1) rowptr[2 * NN] = 2 * EE;
}

// ---------------- GENConv softmax aggregation + residual -------------------
// 4 nodes per wave: each 16-lane quarter owns ONE node, serial edge walk
// (2-edge unroll), channels lane-owned -> no cross-lane reduce. XCD quadrant
// pinning (ti, ch-half) via blockIdx&7.
__global__ __launch_bounds__(256) void agg_kernel(
    const __bf16* __restrict__ xin, const int* __restrict__ rowptr,
    const Edge* __restrict__ edges, const float* __restrict__ Wee,
    const float* __restrict__ bee, const float* __restrict__ tptr, int layer,
    __bf16* __restrict__ out) {
  int wave = threadIdx.x >> 6, lane = threadIdx.x & 63;
  int b = blockIdx.x;  // 625 * 8 blocks
  int x8 = b & 7;
  int q = x8 >> 1;
  int par = x8 & 1;
  int ti = q >> 1, chh = q & 1;
  int group = (b >> 3) * 2 + par;
  int qq = lane >> 4, c15 = lane & 15;
  int node = group * 16 + wave * 4 + qq;
  int gnode = ti * NN + node;
  int xrow = ti * MP + node;
  float t2 = tptr[layer] * 1.4426950408889634f;
  int c0 = chh * 64 + c15 * 4;
  float den[4] = {}, num[4] = {};
  int e = rowptr[gnode];
  const int e1 = rowptr[gnode + 1];

  if (t2 > 0.f) {
    float w0p[4], w1p[4], bvp[4];
#pragma unroll
    for (int i = 0; i < 4; ++i) {
      w0p[i] = Wee[c0 + i] * t2;
      w1p[i] = Wee[HH + c0 + i] * t2;
      bvp[i] = bee[c0 + i] * t2;
    }
#define MLPF(XV, ED)                                                      \
  do {                                                                    \
    float eax = (float)(ED).ea0, eay = (float)(ED).ea1;                   \
    _Pragma("unroll") for (int i = 0; i < 4; ++i) {                       \
      float te = fmaf(eax, w0p[i], fmaf(eay, w1p[i], bvp[i]));            \
      float sm = fmaxf(fmaf((float)(XV)[i], t2, te), 0.f);                \
      float ex = fexp2(sm);                                               \
      den[i] += ex; num[i] = fmaf(sm, ex, num[i]);                        \
    }                                                                     \
  } while (0)
    for (; e + 2 <= e1; e += 2) {
      Edge E0 = edges[e];
      Edge E1 = edges[e + 1];
      bf16x4 x0 = *(const bf16x4*)(xin + (size_t)E0.src * HH + c0);
      bf16x4 x1 = *(const bf16x4*)(xin + (size_t)E1.src * HH + c0);
      MLPF(x0, E0);
      MLPF(x1, E1);
    }
    if (e < e1) {
      Edge E0 = edges[e];
      bf16x4 x0 = *(const bf16x4*)(xin + (size_t)E0.src * HH + c0);
      MLPF(x0, E0);
    }
#undef MLPF
    bf16x4 xr = *(const bf16x4*)(xin + (size_t)xrow * HH + c0);
    bf16x4 o;
#pragma unroll
    for (int i = 0; i < 4; ++i)
      o[i] = (__bf16)(num[i] / (t2 * (den[i] + 1e-16f)) + (float)xr[i]);
    *(bf16x4*)(out + (size_t)xrow * HH + c0) = o;
  } else {
    float w0[4], w1[4], bv[4];
#pragma unroll
    for (int i = 0; i < 4; ++i) {
      w0[i] = Wee[c0 + i];
      w1[i] = Wee[HH + c0 + i];
      bv[i] = bee[c0 + i];
    }
    for (; e < e1; ++e) {
      Edge E0 = edges[e];
      bf16x4 xv = *(const bf16x4*)(xin + (size_t)E0.src * HH + c0);
      float eax = (float)E0.ea0, eay = (float)E0.ea1;
#pragma unroll
      for (int i = 0; i < 4; ++i) {
        float m =
            fmaxf((float)xv[i] + eax * w0[i] + eay * w1[i] + bv[i], 0.f) + 1e-7f;
        float ex = fexp2(m * t2);
        den[i] += ex; num[i] += m * ex;
      }
    }
    bf16x4 xr = *(const bf16x4*)(xin + (size_t)xrow * HH + c0);
    bf16x4 o;
#pragma unroll
    for (int i = 0; i < 4; ++i)
      o[i] = (__bf16)(num[i] / (den[i] + 1e-16f) + (float)xr[i]);
    *(bf16x4*)(out + (size_t)xrow * HH + c0) = o;
  }
}

// ---------------- fused channel attention (node out + graph partial-pool) --
__global__ __launch_bounds__(256) void attn2_kernel(
    const float* __restrict__ emb, const float* __restrict__ Wq_n,
    const float* __restrict__ Wk_n, const float* __restrict__ Wv_n,
    const float* __restrict__ gn, const float* __restrict__ Wq_g,
    const float* __restrict__ Wk_g, const float* __restrict__ Wv_g,
    const float* __restrict__ gg, __bf16* __restrict__ outn,
    float* __restrict__ partial) {
  __shared__ float gsum[4][256];
  int wave = threadIdx.x >> 6, lane = threadIdx.x & 63;
  int tid = threadIdx.x;
  int n = blockIdx.x * 4 + wave;
  int c0 = lane * 2;
  const float* base = emb + (size_t)n * (2 * HH);
  float2 x0 = *(const float2*)(base + c0);
  float2 x1 = *(const float2*)(base + HH + c0);

#define ATTN_BODY(Wq, Wk, Wv, GAM, O0A, O0B, O1A, O1B)                        \
  {                                                                           \
    float gamma = *(GAM);                                                     \
    float wq00 = Wq[0], wq01 = Wq[1], wq10 = Wq[2], wq11 = Wq[3];             \
    float wk00 = Wk[0], wk01 = Wk[1], wk10 = Wk[2], wk11 = Wk[3];             \
    float wv00 = Wv[0], wv01 = Wv[1], wv10 = Wv[2], wv11 = Wv[3];             \
    float q0a = wq00 * x0.x + wq01 * x1.x, q0b = wq00 * x0.y + wq01 * x1.y;   \
    float q1a = wq10 * x0.x + wq11 * x1.x, q1b = wq10 * x0.y + wq11 * x1.y;   \
    float k0a = wk00 * x0.x + wk01 * x1.x, k0b = wk00 * x0.y + wk01 * x1.y;   \
    float k1a = wk10 * x0.x + wk11 * x1.x, k1b = wk10 * x0.y + wk11 * x1.y;   \
    float v0a = wv00 * x0.x + wv01 * x1.x, v0b = wv00 * x0.y + wv01 * x1.y;   \
    float v1a = wv10 * x0.x + wv11 * x1.x, v1b = wv10 * x0.y + wv11 * x1.y;   \
    float s00 = wave_sum(q0a * k0a + q0b * k0b);                              \
    float s01 = wave_sum(q0a * k1a + q0b * k1b);                              \
    float s10 = wave_sum(q1a * k0a + q1b * k0b);                              \
    float s11 = wave_sum(q1a * k1a + q1b * k1b);                              \
    float m0 = fmaxf(s00, s01);                                               \
    float e00 = __expf(s00 - m0), e01 = __expf(s01 - m0);                     \
    float i0 = 1.f / (e00 + e01);                                             \
    float a00 = e00 * i0, a01 = e01 * i0;                                     \
    float m1 = fmaxf(s10, s11);                                               \
    float e10 = __expf(s10 - m1), e11 = __expf(s11 - m1);                     \
    float i1 = 1.f / (e10 + e11);                                             \
    float a10 = e10 * i1, a11 = e11 * i1;                                     \
    O0A = gamma * (a00 * v0a + a01 * v1a) + x0.x;                             \
    O0B = gamma * (a00 * v0b + a01 * v1b) + x0.y;                             \
    O1A = gamma * (a10 * v0a + a11 * v1a) + x1.x;                             \
    O1B = gamma * (a10 * v0b + a11 * v1b) + x1.y;                             \
  }

  float n0a, n0b, n1a, n1b;
  ATTN_BODY(Wq_n, Wk_n, Wv_n, gn, n0a, n0b, n1a, n1b);
  __bf16* opn = outn + (size_t)n * (2 * HH);
  bf16x2 t0; t0[0] = (__bf16)n0a; t0[1] = (__bf16)n0b;
  bf16x2 t1; t1[0] = (__bf16)n1a; t1[1] = (__bf16)n1b;
  *(bf16x2*)(opn + c0) = t0;
  *(bf16x2*)(opn + HH + c0) = t1;

  float g0a, g0b, g1a, g1b;
  ATTN_BODY(Wq_g, Wk_g, Wv_g, gg, g0a, g0b, g1a, g1b);
  gsum[wave][c0] = g0a;
  gsum[wave][c0 + 1] = g0b;
  gsum[wave][128 + c0] = g1a;
  gsum[wave][129 + c0] = g1b;
  __syncthreads();
  partial[(size_t)blockIdx.x * 256 + tid] =
      gsum[0][tid] + gsum[1][tid] + gsum[2][tid] + gsum[3][tid];
#undef ATTN_BODY
}

// ---------------- pool over per-block partials ----------------
__global__ __launch_bounds__(256) void pool_kernel(const float* __restrict__ partial,
                                                   float* __restrict__ gp_sum,
                                                   int nRows) {
  int c = threadIdx.x;
  float s = 0.f;
  for (int r = blockIdx.x; r < nRows; r += gridDim.x)
    s += partial[(size_t)r * 256 + c];
  atomicAdd(&gp_sum[c], s);
}

// ---------------- graph head (single block) ----------------
__global__ __launch_bounds__(256) void graph_head_kernel(
    const float* __restrict__ gp_sum, const float* __restrict__ Wg1,
    const float* __restrict__ bg1, const float* __restrict__ Wg2,
    const float* __restrict__ bg2, float* __restrict__ outp, float invN) {
  __shared__ float gp[256];
  __shared__ float h1[256];
  __shared__ float lg[2];
  int tid = threadIdx.x;
  gp[tid] = gp_sum[tid] * invN;
  __syncthreads();
  float acc = bg1[tid];
  for (int k = 0; k < 256; ++k) acc += gp[k] * Wg1[k * 256 + tid];
  h1[tid] = fmaxf(acc, 0.f);
  __syncthreads();
  if (tid < 2) {
    float l = bg2[tid];
    for (int c = 0; c < 256; ++c) l += h1[c] * Wg2[c * 2 + tid];
    lg[tid] = l;
  }
  __syncthreads();
  if (tid == 0) {
    float m = fmaxf(lg[0], lg[1]);
    float lse = m + logf(__expf(lg[0] - m) + __expf(lg[1] - m));
    outp[0] = lg[0] - lse;
    outp[1] = lg[1] - lse;
  }
}

// ---------------- launch ----------------
extern "C" void kernel_launch(void* const* d_in, const int* in_sizes, int n_in,
                              void* d_out, int out_size, void* d_ws, size_t ws_size,
                              hipStream_t stream) {
  (void)in_sizes; (void)n_in; (void)out_size; (void)ws_size;
  const float* node_feature = (const float*)d_in[0];
  const int* edge_index = (const int*)d_in[1];
  const float* edge_attr = (const float*)d_in[2];
  const float* Wne = (const float*)d_in[3];
  const float* bne = (const float*)d_in[4];
  const float* Wee = (const float*)d_in[5];
  const float* bee = (const float*)d_in[6];
  const float* W1 = (const float*)d_in[7];
  const float* b1 = (const float*)d_in[8];
  const float* g1 = (const float*)d_in[9];
  const float* be1 = (const float*)d_in[10];
  const float* W2 = (const float*)d_in[11];
  const float* b2 = (const float*)d_in[12];
  const float* dg = (const float*)d_in[13];
  const float* db = (const float*)d_in[14];
  const float* tpar = (const float*)d_in[15];
  const float* Wq_n = (const float*)d_in[16];
  const float* Wk_n = (const float*)d_in[17];
  const float* Wv_n = (const float*)d_in[18];
  const float* gamma_n = (const float*)d_in[19];
  const float* Wn1 = (const float*)d_in[20];
  const float* bn1 = (const float*)d_in[21];
  const float* Wn2 = (const float*)d_in[22];
  const float* bn2 = (const float*)d_in[23];
  const float* Wq_g = (const float*)d_in[24];
  const float* Wk_g = (const float*)d_in[25];
  const float* Wv_g = (const float*)d_in[26];
  const float* gamma_g = (const float*)d_in[27];
  const float* Wg1 = (const float*)d_in[28];
  const float* bg1 = (const float*)d_in[29];
  const float* Wg2 = (const float*)d_in[30];
  const float* bg2 = (const float*)d_in[31];
  float* out = (float*)d_out;

  // ---- workspace carve-out (256B-aligned regions) ----
  char* pc = (char*)d_ws;
  auto alloc = [&](size_t bytes) {
    char* r = pc;
    pc += (bytes + 255) & ~(size_t)255;
    return r;
  };
  float* xbuf = (float*)alloc((size_t)2 * MP * HH * 4);       // f32 residual
  __bf16* hbuf_b = (__bf16*)alloc((size_t)2 * MP * HH * 2);   // LN'd agg input
  __bf16* t256_b = (__bf16*)alloc((size_t)2 * MP * 256 * 2);  // lin1+LN out
  float* emb = (float*)alloc((size_t)NN * 2 * HH * 4);        // [N,T,H] f32
  __bf16* aggout_b = (__bf16*)alloc((size_t)2 * MP * HH * 2); // agg out
  __bf16* nf_b = (__bf16*)emb;  // 23.0MB <= emb(20.5)+aggout(10.3)
  __bf16* attnb = t256_b;       // alias: node-attn out (after last lin2)
  float* partial = xbuf;        // alias: graph-attn partials [5000][256]
  __bf16* wt_ne = (__bf16*)alloc((size_t)128 * 576 * 2);
  __bf16* wt1 = (__bf16*)alloc((size_t)4 * 256 * 128 * 2);
  __bf16* wt2 = (__bf16*)alloc((size_t)4 * 128 * 256 * 2);
  __bf16* wtn1 = (__bf16*)alloc((size_t)256 * 256 * 2);
  float* gp_sum = (float*)alloc(256 * 4);
  int* deg = (int*)alloc((size_t)2 * NN * 4);
  int* cursor = (int*)alloc((size_t)2 * NN * 4);
  int* rowptr = (int*)alloc((size_t)(2 * NN + 2) * 4);
  Edge* edges = (Edge*)alloc((size_t)2 * EE * 8);

  const int gRows2 = 2 * MP / 64;  // 628 row-blocks, stacked GEMMs

  WtDescs wd;
  int gb = 0;
  wd.d[0] = {Wne, wt_ne, FF, HH, 576, gb}; gb += HH * 576 / 8;
  for (int l = 0; l < 4; ++l) {
    wd.d[1 + l] = {W1 + (size_t)l * HH * 256, wt1 + (size_t)l * 256 * HH, HH, 256,
                   HH, gb};
    gb += 256 * HH / 8;
  }
  for (int l = 0; l < 4; ++l) {
    wd.d[5 + l] = {W2 + (size_t)l * 256 * HH, wt2 + (size_t)l * HH * 256, 256, HH,
                   256, gb};
    gb += HH * 256 / 8;
  }
  wd.d[9] = {Wn1, wtn1, 256, 256, 256, gb};

  // prologue: deg zero; grid-stride converts + degree count + gp_sum zero
  hipMemsetAsync(deg, 0, 2 * NN * sizeof(int), stream);
  prep_kernel<<<PREPG, 256, 0, stream>>>(node_feature, nf_b, wd, edge_index, deg,
                                         gp_sum);
  scan2_kernel<<<2, 1024, 0, stream>>>(deg, rowptr, cursor);
  // encoder GEMM (dup to both halves) fused with XCD-routed edge scatter
  enc_scatter_kernel<<<ENCB + 8 * SSB, 256, 0, stream>>>(
      nf_b, wt_ne, bne, hbuf_b, edge_index, edge_attr, cursor, edges);

  // layer loop, both ti at once
  for (int l = 0; l < LL; ++l) {
    agg_kernel<<<625 * 8, 256, 0, stream>>>(hbuf_b, rowptr, edges, Wee, bee, tpar,
                                            l, aggout_b);
    gemm256<0><<<gRows2, 256, 0, stream>>>(aggout_b, wt1 + (size_t)l * 256 * HH,
                                           b1 + l * 2 * HH, g1 + l * 2 * HH,
                                           be1 + l * 2 * HH, nullptr, nullptr, t256_b,
                                           2 * MP, HH);
    const __bf16* w2l = wt2 + (size_t)l * HH * 256;
    const float* b2l = b2 + l * HH;
    if (l == 0)
      gemm_lin2<0><<<gRows2, 256, 0, stream>>>(t256_b, w2l, b2l, xbuf, dg + 1 * HH,
                                               db + 1 * HH, hbuf_b);
    else if (l < LL - 1)
      gemm_lin2<1><<<gRows2, 256, 0, stream>>>(t256_b, w2l, b2l, xbuf,
                                               dg + (l + 1) * HH, db + (l + 1) * HH,
                                               hbuf_b);
    else
      gemm_lin2<2><<<gRows2, 256, 0, stream>>>(t256_b, w2l, b2l, xbuf, dg, db, emb);
  }

  // fused node+graph attention (one emb read; graph branch -> LDS partials)
  attn2_kernel<<<NN / 4, 256, 0, stream>>>(emb, Wq_n, Wk_n, Wv_n, gamma_n, Wq_g,
                                           Wk_g, Wv_g, gamma_g, attnb, partial);
  // node head: lin1+relu+Wn2+log_softmax fused
  gemm256<1><<<MP / 64, 256, 0, stream>>>(attnb, wtn1, bn1, nullptr, nullptr, Wn2,
                                          bn2, out, NN, 256);
  // graph head
  pool_kernel<<<128, 256, 0, stream>>>(partial, gp_sum, NN / 4);
  graph_head_kernel<<<1, 256, 0, stream>>>(gp_sum, Wg1, bg1, Wg2, bg2,
                                           out + (size_t)NN * CN, 1.0f / NN);
}

// Round 13
// 433.411 us; speedup vs baseline: 1.3765x; 1.0209x over previous
//
#include <hip/hip_runtime.h>

#define NN 20000
#define TT 2
#define HH 128
#define LL 4
#define EE 320000
#define FF 514
#define CN 3
#define CG 2
#define MP 20096  // rows per ti-half, padded to multiple of 128

typedef __bf16 bf16x8 __attribute__((ext_vector_type(8)));
typedef __bf16 bf16x4 __attribute__((ext_vector_type(4)));
typedef __bf16 bf16x2 __attribute__((ext_vector_type(2)));
typedef float f32x4 __attribute__((ext_vector_type(4)));

struct __align__(8) Edge { int src; __bf16 ea0, ea1; };

// ---------------- wave helpers ----------------
__device__ inline float wave_sum(float v) {
#pragma unroll
  for (int off = 32; off; off >>= 1) v += __shfl_xor(v, off);
  return v;
}
__device__ inline float red16(float v) {  // reduce across fr = lane&15
  v += __shfl_xor(v, 1); v += __shfl_xor(v, 2);
  v += __shfl_xor(v, 4); v += __shfl_xor(v, 8);
  return v;
}

__device__ __forceinline__ float fexp2(float x) {
#if __has_builtin(__builtin_amdgcn_exp2f)
  return __builtin_amdgcn_exp2f(x);
#else
  return exp2f(x);
#endif
}

__device__ __forceinline__ void gload_lds16(const void* g, void* l) {
  __builtin_amdgcn_global_load_lds(
      (const __attribute__((address_space(1))) unsigned int*)g,
      (__attribute__((address_space(3))) unsigned int*)l, 16, 0, 0);
}

// ---------------- fused encoder GEMM + XCD-routed edge scatter --------------
#define ENCB (MP / 64)
#define SSB 313   // ceil(2*EE / (256*8))
#define CHUNK 5000  // 2*NN/8 gnodes per XCD chunk
__global__ __launch_bounds__(256) void enc_scatter_kernel(
    const __bf16* __restrict__ A, const __bf16* __restrict__ BT,
    const float* __restrict__ bias, __bf16* __restrict__ C,
    const int* __restrict__ edge_index, const float* __restrict__ edge_attr,
    int* __restrict__ cursor, Edge* __restrict__ edges) {
  __shared__ __bf16 As[2][64][32];
  __shared__ __bf16 Bs[2][128][32];
  const int tid = threadIdx.x;
  if (blockIdx.x >= ENCB) {
    int sb = blockIdx.x - ENCB;
    int chunk = sb & 7;
    int slice = sb >> 3;
    int i0 = slice * 2048 + tid * 8;
    if (i0 >= 2 * EE) return;
    int ti = (i0 >= EE) ? 1 : 0;
    int e0 = i0 - ti * EE;
    const int* srcp = edge_index + (size_t)ti * 2 * EE;
    int dst8[8];
    __builtin_memcpy(dst8, srcp + EE + e0, 32);
#pragma unroll
    for (int j = 0; j < 8; ++j) {
      int gnode = ti * NN + dst8[j];
      if (gnode / CHUNK != chunk) continue;
      int s = srcp[e0 + j];
      float2 ea = ((const float2*)edge_attr)[(size_t)ti * EE + e0 + j];
      int pos = atomicAdd(&cursor[gnode], 1);
      Edge ed;
      ed.src = s + ti * MP;
      ed.ea0 = (__bf16)ea.x; ed.ea1 = (__bf16)ea.y;
      __builtin_memcpy(&edges[pos], &ed, sizeof(Edge));
    }
    return;
  }
  const int K = 576;
  const int lane = tid & 63, w = tid >> 6;
  const int bm = blockIdx.x * 64;
  const int wr = (w >> 1) * 32, wc = (w & 1) * 64;
  const int fr = lane & 15, fq = lane >> 4;
  const int rowA = tid >> 2, chA = (tid & 3) * 8;
  const __bf16* Ab = A + (size_t)(bm + rowA) * K + chA;
  const __bf16* Bb = BT + (size_t)rowA * K + chA;
  const __bf16* Bb2 = Bb + (size_t)64 * K;
  f32x4 acc[2][4] = {};
#define STAGE(buf, k0)                                  \
  do {                                                  \
    gload_lds16(Ab + (k0), &As[buf][rowA][chA]);        \
    gload_lds16(Bb + (k0), &Bs[buf][rowA][chA]);        \
    gload_lds16(Bb2 + (k0), &Bs[buf][rowA + 64][chA]);  \
  } while (0)
  STAGE(0, 0);
  __syncthreads();
  int cur = 0;
  for (int k0 = 0; k0 < K; k0 += 32) {
    if (k0 + 32 < K) STAGE(cur ^ 1, k0 + 32);
    bf16x8 af[2], bq[4];
#pragma unroll
    for (int m = 0; m < 2; ++m)
      af[m] = *(const bf16x8*)&As[cur][wr + m * 16 + fr][fq * 8];
#pragma unroll
    for (int n = 0; n < 4; ++n)
      bq[n] = *(const bf16x8*)&Bs[cur][wc + n * 16 + fr][fq * 8];
#pragma unroll
    for (int m = 0; m < 2; ++m)
#pragma unroll
      for (int n = 0; n < 4; ++n)
        acc[m][n] =
            __builtin_amdgcn_mfma_f32_16x16x32_bf16(af[m], bq[n], acc[m][n], 0, 0, 0);
    __syncthreads();
    cur ^= 1;
  }
#undef STAGE
#pragma unroll
  for (int m = 0; m < 2; ++m) {
#pragma unroll
    for (int n = 0; n < 4; ++n) {
#pragma unroll
      for (int j = 0; j < 4; ++j) {
        int gm = bm + wr + m * 16 + fq * 4 + j;
        int gn = wc + n * 16 + fr;
        if (gm < NN) {
          __bf16 c = (__bf16)(acc[m][n][j] + bias[gn]);
          C[(size_t)gm * 128 + gn] = c;
          C[(size_t)(gm + MP) * 128 + gn] = c;
        }
      }
    }
  }
}

// ---------------- fused 256-wide GEMM (node head only) ----------------------
// relu(c) -> @W2h[256,3] + b2h -> log_softmax -> f32 out [M][3]
__global__ __launch_bounds__(256) void gemm256_head(
    const __bf16* __restrict__ A, const __bf16* __restrict__ BT,
    const float* __restrict__ bias, const float* __restrict__ W2h,
    const float* __restrict__ b2h, float* __restrict__ outf, int M, int K) {
  __shared__ __bf16 As[2][64][32];
  __shared__ __bf16 Bs[2][256][32];
  const int tid = threadIdx.x;
  const int lane = tid & 63, w = tid >> 6;
  const int bm = blockIdx.x * 64;
  const int wr = w * 16;
  const int fr = lane & 15, fq = lane >> 4;
  const int rowA = tid >> 2, chA = (tid & 3) * 8;
  const __bf16* Ab = A + (size_t)(bm + rowA) * K + chA;
  const __bf16* Bb = BT + (size_t)rowA * K + chA;
  f32x4 acc[16] = {};

#define STG(buf, k0)                                                \
  do {                                                              \
    gload_lds16(Ab + (k0), &As[buf][rowA][chA]);                    \
    _Pragma("unroll") for (int r = 0; r < 4; ++r)                   \
        gload_lds16(Bb + (size_t)(r * 64) * K + (k0),               \
                    &Bs[buf][rowA + r * 64][chA]);                  \
  } while (0)

  STG(0, 0);
  __syncthreads();
  int cur = 0;
  for (int k0 = 0; k0 < K; k0 += 32) {
    if (k0 + 32 < K) STG(cur ^ 1, k0 + 32);
    bf16x8 af = *(const bf16x8*)&As[cur][wr + fr][fq * 8];
#pragma unroll
    for (int n = 0; n < 16; ++n) {
      bf16x8 bq = *(const bf16x8*)&Bs[cur][n * 16 + fr][fq * 8];
      acc[n] = __builtin_amdgcn_mfma_f32_16x16x32_bf16(af, bq, acc[n], 0, 0, 0);
    }
    __syncthreads();
    cur ^= 1;
  }
#undef STG

  float cb[16], w0[16], w1[16], w2[16];
#pragma unroll
  for (int n = 0; n < 16; ++n) {
    int col = n * 16 + fr;
    cb[n] = bias[col];
    w0[n] = W2h[col * 3 + 0];
    w1[n] = W2h[col * 3 + 1];
    w2[n] = W2h[col * 3 + 2];
  }
#pragma unroll
  for (int j = 0; j < 4; ++j) {
    float p0 = 0.f, p1 = 0.f, p2 = 0.f;
#pragma unroll
    for (int n = 0; n < 16; ++n) {
      float h = fmaxf(acc[n][j] + cb[n], 0.f);
      p0 += h * w0[n]; p1 += h * w1[n]; p2 += h * w2[n];
    }
    p0 = red16(p0); p1 = red16(p1); p2 = red16(p2);
    int gm = bm + wr + fq * 4 + j;
    if (fr == 0 && gm < M) {
      float l0 = p0 + b2h[0], l1 = p1 + b2h[1], l2 = p2 + b2h[2];
      float m = fmaxf(l0, fmaxf(l1, l2));
      float lse = m + logf(__expf(l0 - m) + __expf(l1 - m) + __expf(l2 - m));
      outf[(size_t)gm * 3 + 0] = l0 - lse;
      outf[(size_t)gm * 3 + 1] = l1 - lse;
      outf[(size_t)gm * 3 + 2] = l2 - lse;
    }
  }
}

// ---------------- fused layer MLP: lin1+LN+relu (LDS) -> lin2+res+LN -------
// Phase 1: C1 = A[64][128] @ W1T[256][128]^T + b1 -> LN -> relu -> h1 (LDS)
// Phase 2: C2 = h1[64][256] @ W2T[128][256]^T + b2 (+xres) -> LN path
// MODE 0: write xres + LN->relu->bf16 hb | MODE 1: add+write xres, LN->hb |
// MODE 2: add xres, LN->relu->f32 emb[node*256+half*128+col]
template <int MODE>
__global__ __launch_bounds__(256) void gemm_layer(
    const __bf16* __restrict__ A, const __bf16* __restrict__ W1T,
    const float* __restrict__ b1, const float* __restrict__ g1,
    const float* __restrict__ be1, const __bf16* __restrict__ W2T,
    const float* __restrict__ b2, float* __restrict__ xres,
    const float* __restrict__ dgv, const float* __restrict__ dbv,
    void* __restrict__ lnout) {
  // phase1: As(8K)+Bs1(32K) in smem; phase2: Bs2(16K) aliases smem
  __shared__ char smem[40960];
  __shared__ __bf16 h1[64][264];  // pitch 264 -> phase-2 reads ~2-way banked
  __shared__ float redS[64][2], redS2[64][2];
  auto As = (__bf16(*)[64][32])smem;
  auto Bs1 = (__bf16(*)[256][32])(smem + 8192);
  auto Bs2 = (__bf16(*)[128][32])smem;
  const int tid = threadIdx.x;
  const int lane = tid & 63, w = tid >> 6;
  const int bm = blockIdx.x * 64;
  const int fr = lane & 15, fq = lane >> 4;
  const int rowA = tid >> 2, chA = (tid & 3) * 8;

  // ---------- phase 1: 64x256, K=128 ----------
  {
    const int wr = w * 16;
    const __bf16* Ab = A + (size_t)(bm + rowA) * 128 + chA;
    const __bf16* Bb = W1T + (size_t)rowA * 128 + chA;
    f32x4 acc[16] = {};
#define STG1(buf, k0)                                                 \
  do {                                                                \
    gload_lds16(Ab + (k0), &As[buf][rowA][chA]);                      \
    _Pragma("unroll") for (int r = 0; r < 4; ++r)                     \
        gload_lds16(Bb + (size_t)(r * 64) * 128 + (k0),               \
                    &Bs1[buf][rowA + r * 64][chA]);                   \
  } while (0)
    STG1(0, 0);
    __syncthreads();
    int cur = 0;
    for (int k0 = 0; k0 < 128; k0 += 32) {
      if (k0 + 32 < 128) STG1(cur ^ 1, k0 + 32);
      bf16x8 af = *(const bf16x8*)&As[cur][wr + fr][fq * 8];
#pragma unroll
      for (int n = 0; n < 16; ++n) {
        bf16x8 bq = *(const bf16x8*)&Bs1[cur][n * 16 + fr][fq * 8];
        acc[n] = __builtin_amdgcn_mfma_f32_16x16x32_bf16(af, bq, acc[n], 0, 0, 0);
      }
      __syncthreads();
      cur ^= 1;
    }
#undef STG1
    float cb[16], gv[16], bev[16];
#pragma unroll
    for (int n = 0; n < 16; ++n) {
      int col = n * 16 + fr;
      cb[n] = b1[col]; gv[n] = g1[col]; bev[n] = be1[col];
    }
#pragma unroll
    for (int j = 0; j < 4; ++j) {
      float cj[16], s = 0.f, s2 = 0.f;
#pragma unroll
      for (int n = 0; n < 16; ++n) {
        float c = acc[n][j] + cb[n];
        cj[n] = c; s += c; s2 += c * c;
      }
      s = red16(s); s2 = red16(s2);
      float mu = s * (1.f / 256);
      float var = fmaxf(s2 * (1.f / 256) - mu * mu, 0.f);
      float rr = rsqrtf(var + 1e-5f);
      int r = wr + fq * 4 + j;
#pragma unroll
      for (int n = 0; n < 16; ++n) {
        float y = (cj[n] - mu) * rr * gv[n] + bev[n];
        h1[r][n * 16 + fr] = (__bf16)fmaxf(y, 0.f);
      }
    }
  }
  __syncthreads();  // h1 visible; As/Bs1 reads done -> Bs2 may overwrite

  // ---------- phase 2: 64x128, K=256, A from h1 (LDS) ----------
  {
    const int wr = (w >> 1) * 32, wc = (w & 1) * 64;
    const __bf16* Bb = W2T + (size_t)rowA * 256 + chA;
    const __bf16* Bb2 = Bb + (size_t)64 * 256;
    f32x4 acc[2][4] = {};
#define STG2(buf, k0)                                   \
  do {                                                  \
    gload_lds16(Bb + (k0), &Bs2[buf][rowA][chA]);       \
    gload_lds16(Bb2 + (k0), &Bs2[buf][rowA + 64][chA]); \
  } while (0)
    STG2(0, 0);
    __syncthreads();
    int cur = 0;
    for (int k0 = 0; k0 < 256; k0 += 32) {
      if (k0 + 32 < 256) STG2(cur ^ 1, k0 + 32);
      bf16x8 af[2], bq[4];
#pragma unroll
      for (int m = 0; m < 2; ++m)
        af[m] = *(const bf16x8*)&h1[wr + m * 16 + fr][k0 + fq * 8];
#pragma unroll
      for (int n = 0; n < 4; ++n)
        bq[n] = *(const bf16x8*)&Bs2[cur][wc + n * 16 + fr][fq * 8];
#pragma unroll
      for (int m = 0; m < 2; ++m)
#pragma unroll
        for (int n = 0; n < 4; ++n)
          acc[m][n] =
              __builtin_amdgcn_mfma_f32_16x16x32_bf16(af[m], bq[n], acc[m][n], 0, 0, 0);
      __syncthreads();
      cur ^= 1;
    }
#undef STG2

    float cv[2][4][4];
#pragma unroll
    for (int m = 0; m < 2; ++m) {
      int r0 = wr + m * 16 + fq * 4;
#pragma unroll
      for (int j = 0; j < 4; ++j) {
        int gm = bm + r0 + j;
        float s = 0.f, s2 = 0.f;
#pragma unroll
        for (int n = 0; n < 4; ++n) {
          float c = acc[m][n][j] + b2[wc + n * 16 + fr];
          if (MODE != 0) c += xres[(size_t)gm * 128 + wc + n * 16 + fr];
          cv[m][n][j] = c;
          s += c; s2 += c * c;
        }
        s = red16(s); s2 = red16(s2);
        if (fr == 0) {
          redS[r0 + j][w & 1] = s;
          redS2[r0 + j][w & 1] = s2;
        }
      }
    }
    __syncthreads();
#pragma unroll
    for (int m = 0; m < 2; ++m) {
      int r0 = wr + m * 16 + fq * 4;
#pragma unroll
      for (int j = 0; j < 4; ++j) {
        int r = r0 + j;
        int gm = bm + r;
        float S = redS[r][0] + redS[r][1];
        float S2 = redS2[r][0] + redS2[r][1];
        float mu = S * (1.f / 128);
        float var = fmaxf(S2 * (1.f / 128) - mu * mu, 0.f);
        float rr = rsqrtf(var + 1e-5f);
        if constexpr (MODE < 2) {
          float* xp = xres + (size_t)gm * 128;
          __bf16* hp = (__bf16*)lnout + (size_t)gm * 128;
#pragma unroll
          for (int n = 0; n < 4; ++n) {
            int col = wc + n * 16 + fr;
            float c = cv[m][n][j];
            xp[col] = c;
            float y = (c - mu) * rr * dgv[col] + dbv[col];
            hp[col] = (__bf16)fmaxf(y, 0.f);
          }
        } else {
          int half = gm >= MP;
          int node = gm - half * MP;
          if (node < NN) {
            float* ep = (float*)lnout + (size_t)node * 256 + half * 128;
#pragma unroll
            for (int n = 0; n < 4; ++n) {
              int col = wc + n * 16 + fr;
              float y = (cv[m][n][j] - mu) * rr * dgv[col] + dbv[col];
              ep[col] = fmaxf(y, 0.f);
            }
          }
        }
      }
    }
  }
}

// ---------------- fused prologue (grid-stride, 8 elem/thread) ---------------
struct WtDesc { const float* src; __bf16* dst; int K, N, Kpad, gbase; };
struct WtDescs { WtDesc d[10]; };
#define NFG 1440000  // NN * 576 / 8
#define WTG 50176    // sum(N*Kpad)/8
#define CTG 80000    // 2*EE / 8
#define PREPG 2048   // grid blocks

__global__ __launch_bounds__(256) void prep_kernel(
    const float* __restrict__ nf_src, __bf16* __restrict__ nf_dst, WtDescs descs,
    const int* __restrict__ edge_index, int* __restrict__ deg,
    float* __restrict__ gp_sum) {
  const int tid = threadIdx.x;
  if (blockIdx.x == 0) gp_sum[tid] = 0.f;
  const int TOT = NFG + WTG + CTG;
  for (int g = blockIdx.x * 256 + tid; g < TOT; g += PREPG * 256) {
    if (g < NFG) {
      int row = g / 72, colg = g - row * 72;
      int col0 = colg * 8;
      bf16x8 o;
      if (col0 + 8 <= FF) {
        float v[8];
        __builtin_memcpy(v, nf_src + (size_t)row * FF + col0, 32);
#pragma unroll
        for (int i = 0; i < 8; ++i) o[i] = (__bf16)v[i];
      } else {
#pragma unroll
        for (int i = 0; i < 8; ++i) {
          int col = col0 + i;
          o[i] = (__bf16)((col < FF) ? nf_src[(size_t)row * FF + col] : 0.f);
        }
      }
      *(bf16x8*)(nf_dst + (size_t)row * 576 + col0) = o;
    } else if (g < NFG + WTG) {
      int wb = g - NFG;
      int di = 0;
#pragma unroll
      for (int t = 1; t < 10; ++t)
        if (wb >= descs.d[t].gbase) di = t;
      WtDesc de = descs.d[di];
      int local = wb - de.gbase;
      int kg8 = de.Kpad >> 3;
      int n = local / kg8, k0 = (local - n * kg8) * 8;
      bf16x8 o;
#pragma unroll
      for (int i = 0; i < 8; ++i) {
        int k = k0 + i;
        o[i] = (__bf16)((k < de.K) ? de.src[(size_t)k * de.N + n] : 0.f);
      }
      *(bf16x8*)(de.dst + (size_t)n * de.Kpad + k0) = o;
    } else {
      int i0 = (g - NFG - WTG) * 8;
      int ti = (i0 >= EE) ? 1 : 0;
      int e0 = i0 - ti * EE;
      int dst8[8];
      __builtin_memcpy(dst8, edge_index + (size_t)ti * 2 * EE + EE + e0, 32);
      int* dbase = deg + ti * NN;
#pragma unroll
      for (int j = 0; j < 8; ++j) atomicAdd(&dbase[dst8[j]], 1);
    }
  }
}

// ---------------- CSR scan (block per ti) ----------------
__global__ __launch_bounds__(1024) void scan2_kernel(
    const int* __restrict__ deg_all, int* __restrict__ rowptr,
    int* __restrict__ cursor) {
  const int ti = blockIdx.x;
  const int* deg = deg_all + ti * NN;
  __shared__ int sums[1024];
  int tid = threadIdx.x;
  int chunk = (NN + 1023) / 1024;
  int begin = tid * chunk, end = min(begin + chunk, NN);
  int s = 0;
  for (int i = begin; i < end; ++i) s += deg[i];
  sums[tid] = s;
  __syncthreads();
  for (int off = 1; off < 1024; off <<= 1) {
    int v = (tid >= off) ? sums[tid - off] : 0;
    __syncthreads();
    sums[tid] += v;
    __syncthreads();
  }
  int running = ti * EE + sums[tid] - s;
  for (int i = begin; i < end; ++i) {
    rowptr[ti * NN + i] = running;
    cursor[ti * NN + i] = running;
    running += deg[i];
  }
  if (tid == 0 && ti == 1) rowptr[2 * NN] = 2 * EE;
}

// ---------------- GENConv softmax aggregation + residual -------------------
__global__ __launch_bounds__(256) void agg_kernel(
    const __bf16* __restrict__ xin, const int* __restrict__ rowptr,
    const Edge* __restrict__ edges, const float* __restrict__ Wee,
    const float* __restrict__ bee, const float* __restrict__ tptr, int layer,
    __bf16* __restrict__ out) {
  int wave = threadIdx.x >> 6, lane = threadIdx.x & 63;
  int b = blockIdx.x;  // 625 * 8 blocks
  int x8 = b & 7;
  int q = x8 >> 1;
  int par = x8 & 1;
  int ti = q >> 1, chh = q & 1;
  int group = (b >> 3) * 2 + par;
  int qq = lane >> 4, c15 = lane & 15;
  int node = group * 16 + wave * 4 + qq;
  int gnode = ti * NN + node;
  int xrow = ti * MP + node;
  float t2 = tptr[layer] * 1.4426950408889634f;
  int c0 = chh * 64 + c15 * 4;
  float den[4] = {}, num[4] = {};
  int e = rowptr[gnode];
  const int e1 = rowptr[gnode + 1];

  if (t2 > 0.f) {
    float w0p[4], w1p[4], bvp[4];
#pragma unroll
    for (int i = 0; i < 4; ++i) {
      w0p[i] = Wee[c0 + i] * t2;
      w1p[i] = Wee[HH + c0 + i] * t2;
      bvp[i] = bee[c0 + i] * t2;
    }
#define MLPF(XV, ED)                                                      \
  do {                                                                    \
    float eax = (float)(ED).ea0, eay = (float)(ED).ea1;                   \
    _Pragma("unroll") for (int i = 0; i < 4; ++i) {                       \
      float te = fmaf(eax, w0p[i], fmaf(eay, w1p[i], bvp[i]));            \
      float sm = fmaxf(fmaf((float)(XV)[i], t2, te), 0.f);                \
      float ex = fexp2(sm);                                               \
      den[i] += ex; num[i] = fmaf(sm, ex, num[i]);                        \
    }                                                                     \
  } while (0)
    for (; e + 2 <= e1; e += 2) {
      Edge E0 = edges[e];
      Edge E1 = edges[e + 1];
      bf16x4 x0 = *(const bf16x4*)(xin + (size_t)E0.src * HH + c0);
      bf16x4 x1 = *(const bf16x4*)(xin + (size_t)E1.src * HH + c0);
      MLPF(x0, E0);
      MLPF(x1, E1);
    }
    if (e < e1) {
      Edge E0 = edges[e];
      bf16x4 x0 = *(const bf16x4*)(xin + (size_t)E0.src * HH + c0);
      MLPF(x0, E0);
    }
#undef MLPF
    bf16x4 xr = *(const bf16x4*)(xin + (size_t)xrow * HH + c0);
    bf16x4 o;
#pragma unroll
    for (int i = 0; i < 4; ++i)
      o[i] = (__bf16)(num[i] / (t2 * (den[i] + 1e-16f)) + (float)xr[i]);
    *(bf16x4*)(out + (size_t)xrow * HH + c0) = o;
  } else {
    float w0[4], w1[4], bv[4];
#pragma unroll
    for (int i = 0; i < 4; ++i) {
      w0[i] = Wee[c0 + i];
      w1[i] = Wee[HH + c0 + i];
      bv[i] = bee[c0 + i];
    }
    for (; e < e1; ++e) {
      Edge E0 = edges[e];
      bf16x4 xv = *(const bf16x4*)(xin + (size_t)E0.src * HH + c0);
      float eax = (float)E0.ea0, eay = (float)E0.ea1;
#pragma unroll
      for (int i = 0; i < 4; ++i) {
        float m =
            fmaxf((float)xv[i] + eax * w0[i] + eay * w1[i] + bv[i], 0.f) + 1e-7f;
        float ex = fexp2(m * t2);
        den[i] += ex; num[i] += m * ex;
      }
    }
    bf16x4 xr = *(const bf16x4*)(xin + (size_t)xrow * HH + c0);
    bf16x4 o;
#pragma unroll
    for (int i = 0; i < 4; ++i)
      o[i] = (__bf16)(num[i] / (den[i] + 1e-16f) + (float)xr[i]);
    *(bf16x4*)(out + (size_t)xrow * HH + c0) = o;
  }
}

// ---------------- fused channel attention (node out + graph partial-pool) --
__global__ __launch_bounds__(256) void attn2_kernel(
    const float* __restrict__ emb, const float* __restrict__ Wq_n,
    const float* __restrict__ Wk_n, const float* __restrict__ Wv_n,
    const float* __restrict__ gn, const float* __restrict__ Wq_g,
    const float* __restrict__ Wk_g, const float* __restrict__ Wv_g,
    const float* __restrict__ gg, __bf16* __restrict__ outn,
    float* __restrict__ partial) {
  __shared__ float gsum[4][256];
  int wave = threadIdx.x >> 6, lane = threadIdx.x & 63;
  int tid = threadIdx.x;
  int n = blockIdx.x * 4 + wave;
  int c0 = lane * 2;
  const float* base = emb + (size_t)n * (2 * HH);
  float2 x0 = *(const float2*)(base + c0);
  float2 x1 = *(const float2*)(base + HH + c0);

#define ATTN_BODY(Wq, Wk, Wv, GAM, O0A, O0B, O1A, O1B)                        \
  {                                                                           \
    float gamma = *(GAM);                                                     \
    float wq00 = Wq[0], wq01 = Wq[1], wq10 = Wq[2], wq11 = Wq[3];             \
    float wk00 = Wk[0], wk01 = Wk[1], wk10 = Wk[2], wk11 = Wk[3];             \
    float wv00 = Wv[0], wv01 = Wv[1], wv10 = Wv[2], wv11 = Wv[3];             \
    float q0a = wq00 * x0.x + wq01 * x1.x, q0b = wq00 * x0.y + wq01 * x1.y;   \
    float q1a = wq10 * x0.x + wq11 * x1.x, q1b = wq10 * x0.y + wq11 * x1.y;   \
    float k0a = wk00 * x0.x + wk01 * x1.x, k0b = wk00 * x0.y + wk01 * x1.y;   \
    float k1a = wk10 * x0.x + wk11 * x1.x, k1b = wk10 * x0.y + wk11 * x1.y;   \
    float v0a = wv00 * x0.x + wv01 * x1.x, v0b = wv00 * x0.y + wv01 * x1.y;   \
    float v1a = wv10 * x0.x + wv11 * x1.x, v1b = wv10 * x0.y + wv11 * x1.y;   \
    float s00 = wave_sum(q0a * k0a + q0b * k0b);                              \
    float s01 = wave_sum(q0a * k1a + q0b * k1b);                              \
    float s10 = wave_sum(q1a * k0a + q1b * k0b);                              \
    float s11 = wave_sum(q1a * k1a + q1b * k1b);                              \
    float m0 = fmaxf(s00, s01);                                               \
    float e00 = __expf(s00 - m0), e01 = __expf(s01 - m0);                     \
    float i0 = 1.f / (e00 + e01);                                             \
    float a00 = e00 * i0, a01 = e01 * i0;                                     \
    float m1 = fmaxf(s10, s11);                                               \
    float e10 = __expf(s10 - m1), e11 = __expf(s11 - m1);                     \
    float i1 = 1.f / (e10 + e11);                                             \
    float a10 = e10 * i1, a11 = e11 * i1;                                     \
    O0A = gamma * (a00 * v0a + a01 * v1a) + x0.x;                             \
    O0B = gamma * (a00 * v0b + a01 * v1b) + x0.y;                             \
    O1A = gamma * (a10 * v0a + a11 * v1a) + x1.x;                             \
    O1B = gamma * (a10 * v0b + a11 * v1b) + x1.y;                             \
  }

  float n0a, n0b, n1a, n1b;
  ATTN_BODY(Wq_n, Wk_n, Wv_n, gn, n0a, n0b, n1a, n1b);
  __bf16* opn = outn + (size_t)n * (2 * HH);
  bf16x2 t0; t0[0] = (__bf16)n0a; t0[1] = (__bf16)n0b;
  bf16x2 t1; t1[0] = (__bf16)n1a; t1[1] = (__bf16)n1b;
  *(bf16x2*)(opn + c0) = t0;
  *(bf16x2*)(opn + HH + c0) = t1;

  float g0a, g0b, g1a, g1b;
  ATTN_BODY(Wq_g, Wk_g, Wv_g, gg, g0a, g0b, g1a, g1b);
  gsum[wave][c0] = g0a;
  gsum[wave][c0 + 1] = g0b;
  gsum[wave][128 + c0] = g1a;
  gsum[wave][129 + c0] = g1b;
  __syncthreads();
  partial[(size_t)blockIdx.x * 256 + tid] =
      gsum[0][tid] + gsum[1][tid] + gsum[2][tid] + gsum[3][tid];
#undef ATTN_BODY
}

// ---------------- pool over per-block partials ----------------
__global__ __launch_bounds__(256) void pool_kernel(const float* __restrict__ partial,
                                                   float* __restrict__ gp_sum,
                                                   int nRows) {
  int c = threadIdx.x;
  float s = 0.f;
  for (int r = blockIdx.x; r < nRows; r += gridDim.x)
    s += partial[(size_t)r * 256 + c];
  atomicAdd(&gp_sum[c], s);
}

// ---------------- graph head (single block) ----------------
__global__ __launch_bounds__(256) void graph_head_kernel(
    const float* __restrict__ gp_sum, const float* __restrict__ Wg1,
    const float* __restrict__ bg1, const float* __restrict__ Wg2,
    const float* __restrict__ bg2, float* __restrict__ outp, float invN) {
  __shared__ float gp[256];
  __shared__ float h1[256];
  __shared__ float lg[2];
  int tid = threadIdx.x;
  gp[tid] = gp_sum[tid] * invN;
  __syncthreads();
  float acc = bg1[tid];
  for (int k = 0; k < 256; ++k) acc += gp[k] * Wg1[k * 256 + tid];
  h1[tid] = fmaxf(acc, 0.f);
  __syncthreads();
  if (tid < 2) {
    float l = bg2[tid];
    for (int c = 0; c < 256; ++c) l += h1[c] * Wg2[c * 2 + tid];
    lg[tid] = l;
  }
  __syncthreads();
  if (tid == 0) {
    float m = fmaxf(lg[0], lg[1]);
    float lse = m + logf(__expf(lg[0] - m) + __expf(lg[1] - m));
    outp[0] = lg[0] - lse;
    outp[1] = lg[1] - lse;
  }
}

// ---------------- launch ----------------
extern "C" void kernel_launch(void* const* d_in, const int* in_sizes, int n_in,
                              void* d_out, int out_size, void* d_ws, size_t ws_size,
                              hipStream_t stream) {
  (void)in_sizes; (void)n_in; (void)out_size; (void)ws_size;
  const float* node_feature = (const float*)d_in[0];
  const int* edge_index = (const int*)d_in[1];
  const float* edge_attr = (const float*)d_in[2];
  const float* Wne = (const float*)d_in[3];
  const float* bne = (const float*)d_in[4];
  const float* Wee = (const float*)d_in[5];
  const float* bee = (const float*)d_in[6];
  const float* W1 = (const float*)d_in[7];
  const float* b1 = (const float*)d_in[8];
  const float* g1 = (const float*)d_in[9];
  const float* be1 = (const float*)d_in[10];
  const float* W2 = (const float*)d_in[11];
  const float* b2 = (const float*)d_in[12];
  const float* dg = (const float*)d_in[13];
  const float* db = (const float*)d_in[14];
  const float* tpar = (const float*)d_in[15];
  const float* Wq_n = (const float*)d_in[16];
  const float* Wk_n = (const float*)d_in[17];
  const float* Wv_n = (const float*)d_in[18];
  const float* gamma_n = (const float*)d_in[19];
  const float* Wn1 = (const float*)d_in[20];
  const float* bn1 = (const float*)d_in[21];
  const float* Wn2 = (const float*)d_in[22];
  const float* bn2 = (const float*)d_in[23];
  const float* Wq_g = (const float*)d_in[24];
  const float* Wk_g = (const float*)d_in[25];
  const float* Wv_g = (const float*)d_in[26];
  const float* gamma_g = (const float*)d_in[27];
  const float* Wg1 = (const float*)d_in[28];
  const float* bg1 = (const float*)d_in[29];
  const float* Wg2 = (const float*)d_in[30];
  const float* bg2 = (const float*)d_in[31];
  float* out = (float*)d_out;

  // ---- workspace carve-out (256B-aligned regions) ----
  char* pc = (char*)d_ws;
  auto alloc = [&](size_t bytes) {
    char* r = pc;
    pc += (bytes + 255) & ~(size_t)255;
    return r;
  };
  float* xbuf = (float*)alloc((size_t)2 * MP * HH * 4);       // f32 residual
  __bf16* hbuf_b = (__bf16*)alloc((size_t)2 * MP * HH * 2);   // LN'd agg input
  __bf16* attnb = (__bf16*)alloc((size_t)MP * 256 * 2);       // node-attn out
  float* emb = (float*)alloc((size_t)NN * 2 * HH * 4);        // [N,T,H] f32
  __bf16* aggout_b = (__bf16*)alloc((size_t)2 * MP * HH * 2); // agg out
  __bf16* nf_b = (__bf16*)emb;  // 23.0MB <= emb(20.5)+aggout(10.3)
  float* partial = xbuf;        // alias: graph-attn partials [5000][256]
  __bf16* wt_ne = (__bf16*)alloc((size_t)128 * 576 * 2);
  __bf16* wt1 = (__bf16*)alloc((size_t)4 * 256 * 128 * 2);
  __bf16* wt2 = (__bf16*)alloc((size_t)4 * 128 * 256 * 2);
  __bf16* wtn1 = (__bf16*)alloc((size_t)256 * 256 * 2);
  float* gp_sum = (float*)alloc(256 * 4);
  int* deg = (int*)alloc((size_t)2 * NN * 4);
  int* cursor = (int*)alloc((size_t)2 * NN * 4);
  int* rowptr = (int*)alloc((size_t)(2 * NN + 2) * 4);
  Edge* edges = (Edge*)alloc((size_t)2 * EE * 8);

  const int gRows2 = 2 * MP / 64;  // 628 row-blocks, stacked layer kernel

  WtDescs wd;
  int gb = 0;
  wd.d[0] = {Wne, wt_ne, FF, HH, 576, gb}; gb += HH * 576 / 8;
  for (int l = 0; l < 4; ++l) {
    wd.d[1 + l] = {W1 + (size_t)l * HH * 256, wt1 + (size_t)l * 256 * HH, HH, 256,
                   HH, gb};
    gb += 256 * HH / 8;
  }
  for (int l = 0; l < 4; ++l) {
    wd.d[5 + l] = {W2 + (size_t)l * 256 * HH, wt2 + (size_t)l * HH * 256, 256, HH,
                   256, gb};
    gb += HH * 256 / 8;
  }
  wd.d[9] = {Wn1, wtn1, 256, 256, 256, gb};

  // prologue: deg zero; grid-stride converts + degree count + gp_sum zero
  hipMemsetAsync(deg, 0, 2 * NN * sizeof(int), stream);
  prep_kernel<<<PREPG, 256, 0, stream>>>(node_feature, nf_b, wd, edge_index, deg,
                                         gp_sum);
  scan2_kernel<<<2, 1024, 0, stream>>>(deg, rowptr, cursor);
  // encoder GEMM (dup to both halves) fused with XCD-routed edge scatter
  enc_scatter_kernel<<<ENCB + 8 * SSB, 256, 0, stream>>>(
      nf_b, wt_ne, bne, hbuf_b, edge_index, edge_attr, cursor, edges);

  // layer loop, both ti at once: agg + fused MLP (lin1+LN+relu | lin2+res+LN)
  for (int l = 0; l < LL; ++l) {
    agg_kernel<<<625 * 8, 256, 0, stream>>>(hbuf_b, rowptr, edges, Wee, bee, tpar,
                                            l, aggout_b);
    const __bf16* w1l = wt1 + (size_t)l * 256 * HH;
    const __bf16* w2l = wt2 + (size_t)l * HH * 256;
    if (l == 0)
      gemm_layer<0><<<gRows2, 256, 0, stream>>>(
          aggout_b, w1l, b1 + l * 2 * HH, g1 + l * 2 * HH, be1 + l * 2 * HH, w2l,
          b2 + l * HH, xbuf, dg + 1 * HH, db + 1 * HH, hbuf_b);
    else if (l < LL - 1)
      gemm_layer<1><<<gRows2, 256, 0, stream>>>(
          aggout_b, w1l, b1 + l * 2 * HH, g1 + l * 2 * HH, be1 + l * 2 * HH, w2l,
          b2 + l * HH, xbuf, dg + (l + 1) * HH, db + (l + 1) * HH, hbuf_b);
    else
      gemm_layer<2><<<gRows2, 256, 0, stream>>>(
          aggout_b, w1l, b1 + l * 2 * HH, g1 + l * 2 * HH, be1 + l * 2 * HH, w2l,
          b2 + l * HH, xbuf, dg, db, emb);
  }

  // fused node+graph attention (one emb read; graph branch -> LDS partials)
  attn2_kernel<<<NN / 4, 256, 0, stream>>>(emb, Wq_n, Wk_n, Wv_n, gamma_n, Wq_g,
                                           Wk_g, Wv_g, gamma_g, attnb, partial);
  // node head: lin1+relu+Wn2+log_softmax fused
  gemm256_head<<<MP / 64, 256, 0, stream>>>(attnb, wtn1, bn1, Wn2, bn2, out, NN,
                                            256);
  // graph head
  pool_kernel<<<128, 256, 0, stream>>>(partial, gp_sum, NN / 4);
  graph_head_kernel<<<1, 256, 0, stream>>>(gp_sum, Wg1, bg1, Wg2, bg2,
                                           out + (size_t)NN * CN, 1.0f / NN);
}

// Round 14
// 425.529 us; speedup vs baseline: 1.4020x; 1.0185x over previous
//
#include <hip/hip_runtime.h>

#define NN 20000
#define TT 2
#define HH 128
#define LL 4
#define EE 320000
#define FF 514
#define CN 3
#define CG 2
#define MP 20096  // rows per ti-half, padded to multiple of 128

typedef __bf16 bf16x8 __attribute__((ext_vector_type(8)));
typedef __bf16 bf16x4 __attribute__((ext_vector_type(4)));
typedef __bf16 bf16x2 __attribute__((ext_vector_type(2)));
typedef float f32x4 __attribute__((ext_vector_type(4)));

struct __align__(8) Edge { int src; __bf16 ea0, ea1; };

// ---------------- wave helpers ----------------
__device__ inline float wave_sum(float v) {
#pragma unroll
  for (int off = 32; off; off >>= 1) v += __shfl_xor(v, off);
  return v;
}
__device__ inline float red16(float v) {  // reduce across fr = lane&15
  v += __shfl_xor(v, 1); v += __shfl_xor(v, 2);
  v += __shfl_xor(v, 4); v += __shfl_xor(v, 8);
  return v;
}

__device__ __forceinline__ float fexp2(float x) {
#if __has_builtin(__builtin_amdgcn_exp2f)
  return __builtin_amdgcn_exp2f(x);
#else
  return exp2f(x);
#endif
}

__device__ __forceinline__ void gload_lds16(const void* g, void* l) {
  __builtin_amdgcn_global_load_lds(
      (const __attribute__((address_space(1))) unsigned int*)g,
      (__attribute__((address_space(3))) unsigned int*)l, 16, 0, 0);
}

// ---------------- fused encoder GEMM (f32 A direct) + XCD-routed scatter ----
// GEMM: A = node_feature f32 [NN][514] read directly; reg-staged + converted
// to bf16 in LDS (kills the 64 MB prep convert pass). B = wt_ne bf16 [128][576]
// (zero-padded cols>=514 -> tail products exactly 0).
#define ENCB (MP / 64)
#define SSB 313   // ceil(2*EE / (256*8))
#define CHUNK 5000  // 2*NN/8 gnodes per XCD chunk
__global__ __launch_bounds__(256) void enc_scatter_kernel(
    const float* __restrict__ Af, const __bf16* __restrict__ BT,
    const float* __restrict__ bias, __bf16* __restrict__ C,
    const int* __restrict__ edge_index, const float* __restrict__ edge_attr,
    int* __restrict__ cursor, Edge* __restrict__ edges) {
  __shared__ __bf16 As[2][64][32];
  __shared__ __bf16 Bs[2][128][32];
  const int tid = threadIdx.x;
  if (blockIdx.x >= ENCB) {
    int sb = blockIdx.x - ENCB;
    int chunk = sb & 7;
    int slice = sb >> 3;
    int i0 = slice * 2048 + tid * 8;
    if (i0 >= 2 * EE) return;
    int ti = (i0 >= EE) ? 1 : 0;
    int e0 = i0 - ti * EE;
    const int* srcp = edge_index + (size_t)ti * 2 * EE;
    int dst8[8];
    __builtin_memcpy(dst8, srcp + EE + e0, 32);
#pragma unroll
    for (int j = 0; j < 8; ++j) {
      int gnode = ti * NN + dst8[j];
      if (gnode / CHUNK != chunk) continue;
      int s = srcp[e0 + j];
      float2 ea = ((const float2*)edge_attr)[(size_t)ti * EE + e0 + j];
      int pos = atomicAdd(&cursor[gnode], 1);
      Edge ed;
      ed.src = s + ti * MP;
      ed.ea0 = (__bf16)ea.x; ed.ea1 = (__bf16)ea.y;
      __builtin_memcpy(&edges[pos], &ed, sizeof(Edge));
    }
    return;
  }
  const int K = 576;
  const int lane = tid & 63, w = tid >> 6;
  const int bm = blockIdx.x * 64;
  const int wr = (w >> 1) * 32, wc = (w & 1) * 64;
  const int fr = lane & 15, fq = lane >> 4;
  const int rowA = tid >> 2, chA = (tid & 3) * 8;
  const bool rowOK = (bm + rowA) < NN;
  const float* Arow = Af + (size_t)(bm + rowA) * FF;
  const __bf16* Bb = BT + (size_t)rowA * K + chA;
  const __bf16* Bb2 = Bb + (size_t)64 * K;
  f32x4 acc[2][4] = {};
  float va[8];

#define LOADA(k0)                                                   \
  do {                                                              \
    int c0_ = (k0) + chA;                                           \
    if (rowOK && c0_ + 8 <= FF) {                                   \
      __builtin_memcpy(va, Arow + c0_, 32);                         \
    } else {                                                        \
      _Pragma("unroll") for (int i_ = 0; i_ < 8; ++i_)              \
          va[i_] = (rowOK && c0_ + i_ < FF) ? Arow[c0_ + i_] : 0.f; \
    }                                                               \
  } while (0)
#define WRITEA(buf)                                                 \
  do {                                                              \
    bf16x8 o_;                                                      \
    _Pragma("unroll") for (int i_ = 0; i_ < 8; ++i_)                \
        o_[i_] = (__bf16)va[i_];                                    \
    *(bf16x8*)&As[buf][rowA][chA] = o_;                             \
  } while (0)
#define STAGEB(buf, k0)                                 \
  do {                                                  \
    gload_lds16(Bb + (k0), &Bs[buf][rowA][chA]);        \
    gload_lds16(Bb2 + (k0), &Bs[buf][rowA + 64][chA]);  \
  } while (0)

  LOADA(0); WRITEA(0);
  STAGEB(0, 0);
  __syncthreads();
  int cur = 0;
  for (int k0 = 0; k0 < K; k0 += 32) {
    bool last = (k0 + 32 >= K);
    if (!last) {
      LOADA(k0 + 32);
      STAGEB(cur ^ 1, k0 + 32);
    }
    bf16x8 af[2], bq[4];
#pragma unroll
    for (int m = 0; m < 2; ++m)
      af[m] = *(const bf16x8*)&As[cur][wr + m * 16 + fr][fq * 8];
#pragma unroll
    for (int n = 0; n < 4; ++n)
      bq[n] = *(const bf16x8*)&Bs[cur][wc + n * 16 + fr][fq * 8];
#pragma unroll
    for (int m = 0; m < 2; ++m)
#pragma unroll
      for (int n = 0; n < 4; ++n)
        acc[m][n] =
            __builtin_amdgcn_mfma_f32_16x16x32_bf16(af[m], bq[n], acc[m][n], 0, 0, 0);
    if (!last) WRITEA(cur ^ 1);
    __syncthreads();
    cur ^= 1;
  }
#undef LOADA
#undef WRITEA
#undef STAGEB
#pragma unroll
  for (int m = 0; m < 2; ++m) {
#pragma unroll
    for (int n = 0; n < 4; ++n) {
#pragma unroll
      for (int j = 0; j < 4; ++j) {
        int gm = bm + wr + m * 16 + fq * 4 + j;
        int gn = wc + n * 16 + fr;
        if (gm < NN) {
          __bf16 c = (__bf16)(acc[m][n][j] + bias[gn]);
          C[(size_t)gm * 128 + gn] = c;
          C[(size_t)(gm + MP) * 128 + gn] = c;
        }
      }
    }
  }
}

// ---------------- fused 256-wide GEMM (node head only) ----------------------
__global__ __launch_bounds__(256) void gemm256_head(
    const __bf16* __restrict__ A, const __bf16* __restrict__ BT,
    const float* __restrict__ bias, const float* __restrict__ W2h,
    const float* __restrict__ b2h, float* __restrict__ outf, int M, int K) {
  __shared__ __bf16 As[2][64][32];
  __shared__ __bf16 Bs[2][256][32];
  const int tid = threadIdx.x;
  const int lane = tid & 63, w = tid >> 6;
  const int bm = blockIdx.x * 64;
  const int wr = w * 16;
  const int fr = lane & 15, fq = lane >> 4;
  const int rowA = tid >> 2, chA = (tid & 3) * 8;
  const __bf16* Ab = A + (size_t)(bm + rowA) * K + chA;
  const __bf16* Bb = BT + (size_t)rowA * K + chA;
  f32x4 acc[16] = {};

#define STG(buf, k0)                                                \
  do {                                                              \
    gload_lds16(Ab + (k0), &As[buf][rowA][chA]);                    \
    _Pragma("unroll") for (int r = 0; r < 4; ++r)                   \
        gload_lds16(Bb + (size_t)(r * 64) * K + (k0),               \
                    &Bs[buf][rowA + r * 64][chA]);                  \
  } while (0)

  STG(0, 0);
  __syncthreads();
  int cur = 0;
  for (int k0 = 0; k0 < K; k0 += 32) {
    if (k0 + 32 < K) STG(cur ^ 1, k0 + 32);
    bf16x8 af = *(const bf16x8*)&As[cur][wr + fr][fq * 8];
#pragma unroll
    for (int n = 0; n < 16; ++n) {
      bf16x8 bq = *(const bf16x8*)&Bs[cur][n * 16 + fr][fq * 8];
      acc[n] = __builtin_amdgcn_mfma_f32_16x16x32_bf16(af, bq, acc[n], 0, 0, 0);
    }
    __syncthreads();
    cur ^= 1;
  }
#undef STG

  float cb[16], w0[16], w1[16], w2[16];
#pragma unroll
  for (int n = 0; n < 16; ++n) {
    int col = n * 16 + fr;
    cb[n] = bias[col];
    w0[n] = W2h[col * 3 + 0];
    w1[n] = W2h[col * 3 + 1];
    w2[n] = W2h[col * 3 + 2];
  }
#pragma unroll
  for (int j = 0; j < 4; ++j) {
    float p0 = 0.f, p1 = 0.f, p2 = 0.f;
#pragma unroll
    for (int n = 0; n < 16; ++n) {
      float h = fmaxf(acc[n][j] + cb[n], 0.f);
      p0 += h * w0[n]; p1 += h * w1[n]; p2 += h * w2[n];
    }
    p0 = red16(p0); p1 = red16(p1); p2 = red16(p2);
    int gm = bm + wr + fq * 4 + j;
    if (fr == 0 && gm < M) {
      float l0 = p0 + b2h[0], l1 = p1 + b2h[1], l2 = p2 + b2h[2];
      float m = fmaxf(l0, fmaxf(l1, l2));
      float lse = m + logf(__expf(l0 - m) + __expf(l1 - m) + __expf(l2 - m));
      outf[(size_t)gm * 3 + 0] = l0 - lse;
      outf[(size_t)gm * 3 + 1] = l1 - lse;
      outf[(size_t)gm * 3 + 2] = l2 - lse;
    }
  }
}

// ---------------- fused layer MLP: lin1+LN+relu (LDS) -> lin2+res+LN -------
template <int MODE>
__global__ __launch_bounds__(256) void gemm_layer(
    const __bf16* __restrict__ A, const __bf16* __restrict__ W1T,
    const float* __restrict__ b1, const float* __restrict__ g1,
    const float* __restrict__ be1, const __bf16* __restrict__ W2T,
    const float* __restrict__ b2, float* __restrict__ xres,
    const float* __restrict__ dgv, const float* __restrict__ dbv,
    void* __restrict__ lnout) {
  __shared__ char smem[40960];
  __shared__ __bf16 h1[64][264];
  __shared__ float redS[64][2], redS2[64][2];
  auto As = (__bf16(*)[64][32])smem;
  auto Bs1 = (__bf16(*)[256][32])(smem + 8192);
  auto Bs2 = (__bf16(*)[128][32])smem;
  const int tid = threadIdx.x;
  const int lane = tid & 63, w = tid >> 6;
  const int bm = blockIdx.x * 64;
  const int fr = lane & 15, fq = lane >> 4;
  const int rowA = tid >> 2, chA = (tid & 3) * 8;

  // ---------- phase 1: 64x256, K=128 ----------
  {
    const int wr = w * 16;
    const __bf16* Ab = A + (size_t)(bm + rowA) * 128 + chA;
    const __bf16* Bb = W1T + (size_t)rowA * 128 + chA;
    f32x4 acc[16] = {};
#define STG1(buf, k0)                                                 \
  do {                                                                \
    gload_lds16(Ab + (k0), &As[buf][rowA][chA]);                      \
    _Pragma("unroll") for (int r = 0; r < 4; ++r)                     \
        gload_lds16(Bb + (size_t)(r * 64) * 128 + (k0),               \
                    &Bs1[buf][rowA + r * 64][chA]);                   \
  } while (0)
    STG1(0, 0);
    __syncthreads();
    int cur = 0;
    for (int k0 = 0; k0 < 128; k0 += 32) {
      if (k0 + 32 < 128) STG1(cur ^ 1, k0 + 32);
      bf16x8 af = *(const bf16x8*)&As[cur][wr + fr][fq * 8];
#pragma unroll
      for (int n = 0; n < 16; ++n) {
        bf16x8 bq = *(const bf16x8*)&Bs1[cur][n * 16 + fr][fq * 8];
        acc[n] = __builtin_amdgcn_mfma_f32_16x16x32_bf16(af, bq, acc[n], 0, 0, 0);
      }
      __syncthreads();
      cur ^= 1;
    }
#undef STG1
    float cb[16], gv[16], bev[16];
#pragma unroll
    for (int n = 0; n < 16; ++n) {
      int col = n * 16 + fr;
      cb[n] = b1[col]; gv[n] = g1[col]; bev[n] = be1[col];
    }
#pragma unroll
    for (int j = 0; j < 4; ++j) {
      float cj[16], s = 0.f, s2 = 0.f;
#pragma unroll
      for (int n = 0; n < 16; ++n) {
        float c = acc[n][j] + cb[n];
        cj[n] = c; s += c; s2 += c * c;
      }
      s = red16(s); s2 = red16(s2);
      float mu = s * (1.f / 256);
      float var = fmaxf(s2 * (1.f / 256) - mu * mu, 0.f);
      float rr = rsqrtf(var + 1e-5f);
      int r = wr + fq * 4 + j;
#pragma unroll
      for (int n = 0; n < 16; ++n) {
        float y = (cj[n] - mu) * rr * gv[n] + bev[n];
        h1[r][n * 16 + fr] = (__bf16)fmaxf(y, 0.f);
      }
    }
  }
  __syncthreads();

  // ---------- phase 2: 64x128, K=256, A from h1 (LDS) ----------
  {
    const int wr = (w >> 1) * 32, wc = (w & 1) * 64;
    const __bf16* Bb = W2T + (size_t)rowA * 256 + chA;
    const __bf16* Bb2 = Bb + (size_t)64 * 256;
    f32x4 acc[2][4] = {};
#define STG2(buf, k0)                                   \
  do {                                                  \
    gload_lds16(Bb + (k0), &Bs2[buf][rowA][chA]);       \
    gload_lds16(Bb2 + (k0), &Bs2[buf][rowA + 64][chA]); \
  } while (0)
    STG2(0, 0);
    __syncthreads();
    int cur = 0;
    for (int k0 = 0; k0 < 256; k0 += 32) {
      if (k0 + 32 < 256) STG2(cur ^ 1, k0 + 32);
      bf16x8 af[2], bq[4];
#pragma unroll
      for (int m = 0; m < 2; ++m)
        af[m] = *(const bf16x8*)&h1[wr + m * 16 + fr][k0 + fq * 8];
#pragma unroll
      for (int n = 0; n < 4; ++n)
        bq[n] = *(const bf16x8*)&Bs2[cur][wc + n * 16 + fr][fq * 8];
#pragma unroll
      for (int m = 0; m < 2; ++m)
#pragma unroll
        for (int n = 0; n < 4; ++n)
          acc[m][n] =
              __builtin_amdgcn_mfma_f32_16x16x32_bf16(af[m], bq[n], acc[m][n], 0, 0, 0);
      __syncthreads();
      cur ^= 1;
    }
#undef STG2

    float cv[2][4][4];
#pragma unroll
    for (int m = 0; m < 2; ++m) {
      int r0 = wr + m * 16 + fq * 4;
#pragma unroll
      for (int j = 0; j < 4; ++j) {
        int gm = bm + r0 + j;
        float s = 0.f, s2 = 0.f;
#pragma unroll
        for (int n = 0; n < 4; ++n) {
          float c = acc[m][n][j] + b2[wc + n * 16 + fr];
          if (MODE != 0) c += xres[(size_t)gm * 128 + wc + n * 16 + fr];
          cv[m][n][j] = c;
          s += c; s2 += c * c;
        }
        s = red16(s); s2 = red16(s2);
        if (fr == 0) {
          redS[r0 + j][w & 1] = s;
          redS2[r0 + j][w & 1] = s2;
        }
      }
    }
    __syncthreads();
#pragma unroll
    for (int m = 0; m < 2; ++m) {
      int r0 = wr + m * 16 + fq * 4;
#pragma unroll
      for (int j = 0; j < 4; ++j) {
        int r = r0 + j;
        int gm = bm + r;
        float S = redS[r][0] + redS[r][1];
        float S2 = redS2[r][0] + redS2[r][1];
        float mu = S * (1.f / 128);
        float var = fmaxf(S2 * (1.f / 128) - mu * mu, 0.f);
        float rr = rsqrtf(var + 1e-5f);
        if constexpr (MODE < 2) {
          float* xp = xres + (size_t)gm * 128;
          __bf16* hp = (__bf16*)lnout + (size_t)gm * 128;
#pragma unroll
          for (int n = 0; n < 4; ++n) {
            int col = wc + n * 16 + fr;
            float c = cv[m][n][j];
            xp[col] = c;
            float y = (c - mu) * rr * dgv[col] + dbv[col];
            hp[col] = (__bf16)fmaxf(y, 0.f);
          }
        } else {
          int half = gm >= MP;
          int node = gm - half * MP;
          if (node < NN) {
            float* ep = (float*)lnout + (size_t)node * 256 + half * 128;
#pragma unroll
            for (int n = 0; n < 4; ++n) {
              int col = wc + n * 16 + fr;
              float y = (cv[m][n][j] - mu) * rr * dgv[col] + dbv[col];
              ep[col] = fmaxf(y, 0.f);
            }
          }
        }
      }
    }
  }
}

// ---------------- prologue: weight transpose-convert + degree count --------
struct WtDesc { const float* src; __bf16* dst; int K, N, Kpad, gbase; };
struct WtDescs { WtDesc d[10]; };
#define WTG 50176    // sum(N*Kpad)/8
#define CTG 80000    // 2*EE / 8

__global__ __launch_bounds__(256) void prep_kernel(
    WtDescs descs, const int* __restrict__ edge_index, int* __restrict__ deg,
    float* __restrict__ gp_sum) {
  const int tid = threadIdx.x;
  if (blockIdx.x == 0) gp_sum[tid] = 0.f;
  int g = blockIdx.x * 256 + tid;
  if (g >= WTG + CTG) return;
  if (g < WTG) {
    int wb = g;
    int di = 0;
#pragma unroll
    for (int t = 1; t < 10; ++t)
      if (wb >= descs.d[t].gbase) di = t;
    WtDesc de = descs.d[di];
    int local = wb - de.gbase;
    int kg8 = de.Kpad >> 3;
    int n = local / kg8, k0 = (local - n * kg8) * 8;
    bf16x8 o;
#pragma unroll
    for (int i = 0; i < 8; ++i) {
      int k = k0 + i;
      o[i] = (__bf16)((k < de.K) ? de.src[(size_t)k * de.N + n] : 0.f);
    }
    *(bf16x8*)(de.dst + (size_t)n * de.Kpad + k0) = o;
  } else {
    int i0 = (g - WTG) * 8;
    int ti = (i0 >= EE) ? 1 : 0;
    int e0 = i0 - ti * EE;
    int dst8[8];
    __builtin_memcpy(dst8, edge_index + (size_t)ti * 2 * EE + EE + e0, 32);
    int* dbase = deg + ti * NN;
#pragma unroll
    for (int j = 0; j < 8; ++j) atomicAdd(&dbase[dst8[j]], 1);
  }
}

// ---------------- CSR scan (block per ti) ----------------
__global__ __launch_bounds__(1024) void scan2_kernel(
    const int* __restrict__ deg_all, int* __restrict__ rowptr,
    int* __restrict__ cursor) {
  const int ti = blockIdx.x;
  const int* deg = deg_all + ti * NN;
  __shared__ int sums[1024];
  int tid = threadIdx.x;
  int chunk = (NN + 1023) / 1024;
  int begin = tid * chunk, end = min(begin + chunk, NN);
  int s = 0;
  for (int i = begin; i < end; ++i) s += deg[i];
  sums[tid] = s;
  __syncthreads();
  for (int off = 1; off < 1024; off <<= 1) {
    int v = (tid >= off) ? sums[tid - off] : 0;
    __syncthreads();
    sums[tid] += v;
    __syncthreads();
  }
  int running = ti * EE + sums[tid] - s;
  for (int i = begin; i < end; ++i) {
    rowptr[ti * NN + i] = running;
    cursor[ti * NN + i] = running;
    running += deg[i];
  }
  if (tid == 0 && ti == 1) rowptr[2 * NN] = 2 * EE;
}

// ---------------- GENConv softmax aggregation + residual -------------------
__global__ __launch_bounds__(256) void agg_kernel(
    const __bf16* __restrict__ xin, const int* __restrict__ rowptr,
    const Edge* __restrict__ edges, const float* __restrict__ Wee,
    const float* __restrict__ bee, const float* __restrict__ tptr, int layer,
    __bf16* __restrict__ out) {
  int wave = threadIdx.x >> 6, lane = threadIdx.x & 63;
  int b = blockIdx.x;  // 625 * 8 blocks
  int x8 = b & 7;
  int q = x8 >> 1;
  int par = x8 & 1;
  int ti = q >> 1, chh = q & 1;
  int group = (b >> 3) * 2 + par;
  int qq = lane >> 4, c15 = lane & 15;
  int node = group * 16 + wave * 4 + qq;
  int gnode = ti * NN + node;
  int xrow = ti * MP + node;
  float t2 = tptr[layer] * 1.4426950408889634f;
  int c0 = chh * 64 + c15 * 4;
  float den[4] = {}, num[4] = {};
  int e = rowptr[gnode];
  const int e1 = rowptr[gnode + 1];

  if (t2 > 0.f) {
    float w0p[4], w1p[4], bvp[4];
#pragma unroll
    for (int i = 0; i < 4; ++i) {
      w0p[i] = Wee[c0 + i] * t2;
      w1p[i] = Wee[HH + c0 + i] * t2;
      bvp[i] = bee[c0 + i] * t2;
    }
#define MLPF(XV, ED)                                                      \
  do {                                                                    \
    float eax = (float)(ED).ea0, eay = (float)(ED).ea1;                   \
    _Pragma("unroll") for (int i = 0; i < 4; ++i) {                       \
      float te = fmaf(eax, w0p[i], fmaf(eay, w1p[i], bvp[i]));            \
      float sm = fmaxf(fmaf((float)(XV)[i], t2, te), 0.f);                \
      float ex = fexp2(sm);                                               \
      den[i] += ex; num[i] = fmaf(sm, ex, num[i]);                        \
    }                                                                     \
  } while (0)
    for (; e + 2 <= e1; e += 2) {
      Edge E0 = edges[e];
      Edge E1 = edges[e + 1];
      bf16x4 x0 = *(const bf16x4*)(xin + (size_t)E0.src * HH + c0);
      bf16x4 x1 = *(const bf16x4*)(xin + (size_t)E1.src * HH + c0);
      MLPF(x0, E0);
      MLPF(x1, E1);
    }
    if (e < e1) {
      Edge E0 = edges[e];
      bf16x4 x0 = *(const bf16x4*)(xin + (size_t)E0.src * HH + c0);
      MLPF(x0, E0);
    }
#undef MLPF
    bf16x4 xr = *(const bf16x4*)(xin + (size_t)xrow * HH + c0);
    bf16x4 o;
#pragma unroll
    for (int i = 0; i < 4; ++i)
      o[i] = (__bf16)(num[i] / (t2 * (den[i] + 1e-16f)) + (float)xr[i]);
    *(bf16x4*)(out + (size_t)xrow * HH + c0) = o;
  } else {
    float w0[4], w1[4], bv[4];
#pragma unroll
    for (int i = 0; i < 4; ++i) {
      w0[i] = Wee[c0 + i];
      w1[i] = Wee[HH + c0 + i];
      bv[i] = bee[c0 + i];
    }
    for (; e < e1; ++e) {
      Edge E0 = edges[e];
      bf16x4 xv = *(const bf16x4*)(xin + (size_t)E0.src * HH + c0);
      float eax = (float)E0.ea0, eay = (float)E0.ea1;
#pragma unroll
      for (int i = 0; i < 4; ++i) {
        float m =
            fmaxf((float)xv[i] + eax * w0[i] + eay * w1[i] + bv[i], 0.f) + 1e-7f;
        float ex = fexp2(m * t2);
        den[i] += ex; num[i] += m * ex;
      }
    }
    bf16x4 xr = *(const bf16x4*)(xin + (size_t)xrow * HH + c0);
    bf16x4 o;
#pragma unroll
    for (int i = 0; i < 4; ++i)
      o[i] = (__bf16)(num[i] / (den[i] + 1e-16f) + (float)xr[i]);
    *(bf16x4*)(out + (size_t)xrow * HH + c0) = o;
  }
}

// ---------------- fused channel attention (node out + graph partial-pool) --
__global__ __launch_bounds__(256) void attn2_kernel(
    const float* __restrict__ emb, const float* __restrict__ Wq_n,
    const float* __restrict__ Wk_n, const float* __restrict__ Wv_n,
    const float* __restrict__ gn, const float* __restrict__ Wq_g,
    const float* __restrict__ Wk_g, const float* __restrict__ Wv_g,
    const float* __restrict__ gg, __bf16* __restrict__ outn,
    float* __restrict__ partial) {
  __shared__ float gsum[4][256];
  int wave = threadIdx.x >> 6, lane = threadIdx.x & 63;
  int tid = threadIdx.x;
  int n = blockIdx.x * 4 + wave;
  int c0 = lane * 2;
  const float* base = emb + (size_t)n * (2 * HH);
  float2 x0 = *(const float2*)(base + c0);
  float2 x1 = *(const float2*)(base + HH + c0);

#define ATTN_BODY(Wq, Wk, Wv, GAM, O0A, O0B, O1A, O1B)                        \
  {                                                                           \
    float gamma = *(GAM);                                                     \
    float wq00 = Wq[0], wq01 = Wq[1], wq10 = Wq[2], wq11 = Wq[3];             \
    float wk00 = Wk[0], wk01 = Wk[1], wk10 = Wk[2], wk11 = Wk[3];             \
    float wv00 = Wv[0], wv01 = Wv[1], wv10 = Wv[2], wv11 = Wv[3];             \
    float q0a = wq00 * x0.x + wq01 * x1.x, q0b = wq00 * x0.y + wq01 * x1.y;   \
    float q1a = wq10 * x0.x + wq11 * x1.x, q1b = wq10 * x0.y + wq11 * x1.y;   \
    float k0a = wk00 * x0.x + wk01 * x1.x, k0b = wk00 * x0.y + wk01 * x1.y;   \
    float k1a = wk10 * x0.x + wk11 * x1.x, k1b = wk10 * x0.y + wk11 * x1.y;   \
    float v0a = wv00 * x0.x + wv01 * x1.x, v0b = wv00 * x0.y + wv01 * x1.y;   \
    float v1a = wv10 * x0.x + wv11 * x1.x, v1b = wv10 * x0.y + wv11 * x1.y;   \
    float s00 = wave_sum(q0a * k0a + q0b * k0b);                              \
    float s01 = wave_sum(q0a * k1a + q0b * k1b);                              \
    float s10 = wave_sum(q1a * k0a + q1b * k0b);                              \
    float s11 = wave_sum(q1a * k1a + q1b * k1b);                              \
    float m0 = fmaxf(s00, s01);                                               \
    float e00 = __expf(s00 - m0), e01 = __expf(s01 - m0);                     \
    float i0 = 1.f / (e00 + e01);                                             \
    float a00 = e00 * i0, a01 = e01 * i0;                                     \
    float m1 = fmaxf(s10, s11);                                               \
    float e10 = __expf(s10 - m1), e11 = __expf(s11 - m1);                     \
    float i1 = 1.f / (e10 + e11);                                             \
    float a10 = e10 * i1, a11 = e11 * i1;                                     \
    O0A = gamma * (a00 * v0a + a01 * v1a) + x0.x;                             \
    O0B = gamma * (a00 * v0b + a01 * v1b) + x0.y;                             \
    O1A = gamma * (a10 * v0a + a11 * v1a) + x1.x;                             \
    O1B = gamma * (a10 * v0b + a11 * v1b) + x1.y;                             \
  }

  float n0a, n0b, n1a, n1b;
  ATTN_BODY(Wq_n, Wk_n, Wv_n, gn, n0a, n0b, n1a, n1b);
  __bf16* opn = outn + (size_t)n * (2 * HH);
  bf16x2 t0; t0[0] = (__bf16)n0a; t0[1] = (__bf16)n0b;
  bf16x2 t1; t1[0] = (__bf16)n1a; t1[1] = (__bf16)n1b;
  *(bf16x2*)(opn + c0) = t0;
  *(bf16x2*)(opn + HH + c0) = t1;

  float g0a, g0b, g1a, g1b;
  ATTN_BODY(Wq_g, Wk_g, Wv_g, gg, g0a, g0b, g1a, g1b);
  gsum[wave][c0] = g0a;
  gsum[wave][c0 + 1] = g0b;
  gsum[wave][128 + c0] = g1a;
  gsum[wave][129 + c0] = g1b;
  __syncthreads();
  partial[(size_t)blockIdx.x * 256 + tid] =
      gsum[0][tid] + gsum[1][tid] + gsum[2][tid] + gsum[3][tid];
#undef ATTN_BODY
}

// ---------------- pool over per-block partials ----------------
__global__ __launch_bounds__(256) void pool_kernel(const float* __restrict__ partial,
                                                   float* __restrict__ gp_sum,
                                                   int nRows) {
  int c = threadIdx.x;
  float s = 0.f;
  for (int r = blockIdx.x; r < nRows; r += gridDim.x)
    s += partial[(size_t)r * 256 + c];
  atomicAdd(&gp_sum[c], s);
}

// ---------------- graph head (single block) ----------------
__global__ __launch_bounds__(256) void graph_head_kernel(
    const float* __restrict__ gp_sum, const float* __restrict__ Wg1,
    const float* __restrict__ bg1, const float* __restrict__ Wg2,
    const float* __restrict__ bg2, float* __restrict__ outp, float invN) {
  __shared__ float gp[256];
  __shared__ float h1[256];
  __shared__ float lg[2];
  int tid = threadIdx.x;
  gp[tid] = gp_sum[tid] * invN;
  __syncthreads();
  float acc = bg1[tid];
  for (int k = 0; k < 256; ++k) acc += gp[k] * Wg1[k * 256 + tid];
  h1[tid] = fmaxf(acc, 0.f);
  __syncthreads();
  if (tid < 2) {
    float l = bg2[tid];
    for (int c = 0; c < 256; ++c) l += h1[c] * Wg2[c * 2 + tid];
    lg[tid] = l;
  }
  __syncthreads();
  if (tid == 0) {
    float m = fmaxf(lg[0], lg[1]);
    float lse = m + logf(__expf(lg[0] - m) + __expf(lg[1] - m));
    outp[0] = lg[0] - lse;
    outp[1] = lg[1] - lse;
  }
}

// ---------------- launch ----------------
extern "C" void kernel_launch(void* const* d_in, const int* in_sizes, int n_in,
                              void* d_out, int out_size, void* d_ws, size_t ws_size,
                              hipStream_t stream) {
  (void)in_sizes; (void)n_in; (void)out_size; (void)ws_size;
  const float* node_feature = (const float*)d_in[0];
  const int* edge_index = (const int*)d_in[1];
  const float* edge_attr = (const float*)d_in[2];
  const float* Wne = (const float*)d_in[3];
  const float* bne = (const float*)d_in[4];
  const float* Wee = (const float*)d_in[5];
  const float* bee = (const float*)d_in[6];
  const float* W1 = (const float*)d_in[7];
  const float* b1 = (const float*)d_in[8];
  const float* g1 = (const float*)d_in[9];
  const float* be1 = (const float*)d_in[10];
  const float* W2 = (const float*)d_in[11];
  const float* b2 = (const float*)d_in[12];
  const float* dg = (const float*)d_in[13];
  const float* db = (const float*)d_in[14];
  const float* tpar = (const float*)d_in[15];
  const float* Wq_n = (const float*)d_in[16];
  const float* Wk_n = (const float*)d_in[17];
  const float* Wv_n = (const float*)d_in[18];
  const float* gamma_n = (const float*)d_in[19];
  const float* Wn1 = (const float*)d_in[20];
  const float* bn1 = (const float*)d_in[21];
  const float* Wn2 = (const float*)d_in[22];
  const float* bn2 = (const float*)d_in[23];
  const float* Wq_g = (const float*)d_in[24];
  const float* Wk_g = (const float*)d_in[25];
  const float* Wv_g = (const float*)d_in[26];
  const float* gamma_g = (const float*)d_in[27];
  const float* Wg1 = (const float*)d_in[28];
  const float* bg1 = (const float*)d_in[29];
  const float* Wg2 = (const float*)d_in[30];
  const float* bg2 = (const float*)d_in[31];
  float* out = (float*)d_out;

  // ---- workspace carve-out (256B-aligned regions) ----
  char* pc = (char*)d_ws;
  auto alloc = [&](size_t bytes) {
    char* r = pc;
    pc += (bytes + 255) & ~(size_t)255;
    return r;
  };
  float* xbuf = (float*)alloc((size_t)2 * MP * HH * 4);       // f32 residual
  __bf16* hbuf_b = (__bf16*)alloc((size_t)2 * MP * HH * 2);   // LN'd agg input
  __bf16* attnb = (__bf16*)alloc((size_t)MP * 256 * 2);       // node-attn out
  float* emb = (float*)alloc((size_t)NN * 2 * HH * 4);        // [N,T,H] f32
  __bf16* aggout_b = (__bf16*)alloc((size_t)2 * MP * HH * 2); // agg out
  float* partial = xbuf;        // alias: graph-attn partials [5000][256]
  __bf16* wt_ne = (__bf16*)alloc((size_t)128 * 576 * 2);
  __bf16* wt1 = (__bf16*)alloc((size_t)4 * 256 * 128 * 2);
  __bf16* wt2 = (__bf16*)alloc((size_t)4 * 128 * 256 * 2);
  __bf16* wtn1 = (__bf16*)alloc((size_t)256 * 256 * 2);
  float* gp_sum = (float*)alloc(256 * 4);
  int* deg = (int*)alloc((size_t)2 * NN * 4);
  int* cursor = (int*)alloc((size_t)2 * NN * 4);
  int* rowptr = (int*)alloc((size_t)(2 * NN + 2) * 4);
  Edge* edges = (Edge*)alloc((size_t)2 * EE * 8);

  const int gRows2 = 2 * MP / 64;  // 628 row-blocks, stacked layer kernel

  WtDescs wd;
  int gb = 0;
  wd.d[0] = {Wne, wt_ne, FF, HH, 576, gb}; gb += HH * 576 / 8;
  for (int l = 0; l < 4; ++l) {
    wd.d[1 + l] = {W1 + (size_t)l * HH * 256, wt1 + (size_t)l * 256 * HH, HH, 256,
                   HH, gb};
    gb += 256 * HH / 8;
  }
  for (int l = 0; l < 4; ++l) {
    wd.d[5 + l] = {W2 + (size_t)l * 256 * HH, wt2 + (size_t)l * HH * 256, 256, HH,
                   256, gb};
    gb += HH * 256 / 8;
  }
  wd.d[9] = {Wn1, wtn1, 256, 256, 256, gb};

  // prologue: deg zero; weight converts + degree count + gp_sum zero
  hipMemsetAsync(deg, 0, 2 * NN * sizeof(int), stream);
  prep_kernel<<<(WTG + CTG + 255) / 256, 256, 0, stream>>>(wd, edge_index, deg,
                                                           gp_sum);
  scan2_kernel<<<2, 1024, 0, stream>>>(deg, rowptr, cursor);
  // encoder GEMM (f32 A direct, dup to both halves) + XCD-routed edge scatter
  enc_scatter_kernel<<<ENCB + 8 * SSB, 256, 0, stream>>>(
      node_feature, wt_ne, bne, hbuf_b, edge_index, edge_attr, cursor, edges);

  // layer loop, both ti at once: agg + fused MLP (lin1+LN+relu | lin2+res+LN)
  for (int l = 0; l < LL; ++l) {
    agg_kernel<<<625 * 8, 256, 0, stream>>>(hbuf_b, rowptr, edges, Wee, bee, tpar,
                                            l, aggout_b);
    const __bf16* w1l = wt1 + (size_t)l * 256 * HH;
    const __bf16* w2l = wt2 + (size_t)l * HH * 256;
    if (l == 0)
      gemm_layer<0><<<gRows2, 256, 0, stream>>>(
          aggout_b, w1l, b1 + l * 2 * HH, g1 + l * 2 * HH, be1 + l * 2 * HH, w2l,
          b2 + l * HH, xbuf, dg + 1 * HH, db + 1 * HH, hbuf_b);
    else if (l < LL - 1)
      gemm_layer<1><<<gRows2, 256, 0, stream>>>(
          aggout_b, w1l, b1 + l * 2 * HH, g1 + l * 2 * HH, be1 + l * 2 * HH, w2l,
          b2 + l * HH, xbuf, dg + (l + 1) * HH, db + (l + 1) * HH, hbuf_b);
    else
      gemm_layer<2><<<gRows2, 256, 0, stream>>>(
          aggout_b, w1l, b1 + l * 2 * HH, g1 + l * 2 * HH, be1 + l * 2 * HH, w2l,
          b2 + l * HH, xbuf, dg, db, emb);
  }

  // fused node+graph attention (one emb read; graph branch -> LDS partials)
  attn2_kernel<<<NN / 4, 256, 0, stream>>>(emb, Wq_n, Wk_n, Wv_n, gamma_n, Wq_g,
                                           Wk_g, Wv_g, gamma_g, attnb, partial);
  // node head: lin1+relu+Wn2+log_softmax fused
  gemm256_head<<<MP / 64, 256, 0, stream>>>(attnb, wtn1, bn1, Wn2, bn2, out, NN,
                                            256);
  // graph head
  pool_kernel<<<128, 256, 0, stream>>>(partial, gp_sum, NN / 4);
  graph_head_kernel<<<1, 256, 0, stream>>>(gp_sum, Wg1, bg1, Wg2, bg2,
                                           out + (size_t)NN * CN, 1.0f / NN);
}

// Round 15
// 414.177 us; speedup vs baseline: 1.4404x; 1.0274x over previous
//
#include <hip/hip_runtime.h>

#define NN 20000
#define TT 2
#define HH 128
#define LL 4
#define EE 320000
#define FF 514
#define CN 3
#define CG 2
#define MP 20096  // rows per ti-half, padded to multiple of 128

typedef __bf16 bf16x8 __attribute__((ext_vector_type(8)));
typedef __bf16 bf16x4 __attribute__((ext_vector_type(4)));
typedef __bf16 bf16x2 __attribute__((ext_vector_type(2)));
typedef float f32x4 __attribute__((ext_vector_type(4)));

struct __align__(8) Edge { int src; __bf16 ea0, ea1; };

// ---------------- wave helpers ----------------
__device__ inline float wave_sum(float v) {
#pragma unroll
  for (int off = 32; off; off >>= 1) v += __shfl_xor(v, off);
  return v;
}
__device__ inline float red16(float v) {  // reduce across fr = lane&15
  v += __shfl_xor(v, 1); v += __shfl_xor(v, 2);
  v += __shfl_xor(v, 4); v += __shfl_xor(v, 8);
  return v;
}

__device__ __forceinline__ float fexp2(float x) {
#if __has_builtin(__builtin_amdgcn_exp2f)
  return __builtin_amdgcn_exp2f(x);
#else
  return exp2f(x);
#endif
}

__device__ __forceinline__ void gload_lds16(const void* g, void* l) {
  __builtin_amdgcn_global_load_lds(
      (const __attribute__((address_space(1))) unsigned int*)g,
      (__attribute__((address_space(3))) unsigned int*)l, 16, 0, 0);
}

// ---------------- fused encoder GEMM (f32 A direct) + XCD-routed scatter ----
#define ENCB (MP / 64)
#define SSB 313   // ceil(2*EE / (256*8))
#define CHUNK 5000  // 2*NN/8 gnodes per XCD chunk
__global__ __launch_bounds__(256) void enc_scatter_kernel(
    const float* __restrict__ Af, const __bf16* __restrict__ BT,
    const float* __restrict__ bias, __bf16* __restrict__ C,
    const int* __restrict__ edge_index, const float* __restrict__ edge_attr,
    int* __restrict__ cursor, Edge* __restrict__ edges) {
  __shared__ __bf16 As[2][64][32];
  __shared__ __bf16 Bs[2][128][32];
  const int tid = threadIdx.x;
  if (blockIdx.x >= ENCB) {
    int sb = blockIdx.x - ENCB;
    int chunk = sb & 7;
    int slice = sb >> 3;
    int i0 = slice * 2048 + tid * 8;
    if (i0 >= 2 * EE) return;
    int ti = (i0 >= EE) ? 1 : 0;
    int e0 = i0 - ti * EE;
    const int* srcp = edge_index + (size_t)ti * 2 * EE;
    int dst8[8];
    __builtin_memcpy(dst8, srcp + EE + e0, 32);
#pragma unroll
    for (int j = 0; j < 8; ++j) {
      int gnode = ti * NN + dst8[j];
      if (gnode / CHUNK != chunk) continue;
      int s = srcp[e0 + j];
      float2 ea = ((const float2*)edge_attr)[(size_t)ti * EE + e0 + j];
      int pos = atomicAdd(&cursor[gnode], 1);
      Edge ed;
      ed.src = s + ti * MP;
      ed.ea0 = (__bf16)ea.x; ed.ea1 = (__bf16)ea.y;
      __builtin_memcpy(&edges[pos], &ed, sizeof(Edge));
    }
    return;
  }
  const int K = 576;
  const int lane = tid & 63, w = tid >> 6;
  const int bm = blockIdx.x * 64;
  const int wr = (w >> 1) * 32, wc = (w & 1) * 64;
  const int fr = lane & 15, fq = lane >> 4;
  const int rowA = tid >> 2, chA = (tid & 3) * 8;
  const bool rowOK = (bm + rowA) < NN;
  const float* Arow = Af + (size_t)(bm + rowA) * FF;
  const __bf16* Bb = BT + (size_t)rowA * K + chA;
  const __bf16* Bb2 = Bb + (size_t)64 * K;
  f32x4 acc[2][4] = {};
  float va[8];

#define LOADA(k0)                                                   \
  do {                                                              \
    int c0_ = (k0) + chA;                                           \
    if (rowOK && c0_ + 8 <= FF) {                                   \
      __builtin_memcpy(va, Arow + c0_, 32);                         \
    } else {                                                        \
      _Pragma("unroll") for (int i_ = 0; i_ < 8; ++i_)              \
          va[i_] = (rowOK && c0_ + i_ < FF) ? Arow[c0_ + i_] : 0.f; \
    }                                                               \
  } while (0)
#define WRITEA(buf)                                                 \
  do {                                                              \
    bf16x8 o_;                                                      \
    _Pragma("unroll") for (int i_ = 0; i_ < 8; ++i_)                \
        o_[i_] = (__bf16)va[i_];                                    \
    *(bf16x8*)&As[buf][rowA][chA] = o_;                             \
  } while (0)
#define STAGEB(buf, k0)                                 \
  do {                                                  \
    gload_lds16(Bb + (k0), &Bs[buf][rowA][chA]);        \
    gload_lds16(Bb2 + (k0), &Bs[buf][rowA + 64][chA]);  \
  } while (0)

  LOADA(0); WRITEA(0);
  LOADA(32);  // prefetch next A tile into regs (consumed next iter)
  STAGEB(0, 0);
  __syncthreads();
  int cur = 0;
  for (int k0 = 0; k0 < K; k0 += 32) {
    bool last = (k0 + 32 >= K);
    if (!last) STAGEB(cur ^ 1, k0 + 32);
    bf16x8 af[2], bq[4];
#pragma unroll
    for (int m = 0; m < 2; ++m)
      af[m] = *(const bf16x8*)&As[cur][wr + m * 16 + fr][fq * 8];
#pragma unroll
    for (int n = 0; n < 4; ++n)
      bq[n] = *(const bf16x8*)&Bs[cur][wc + n * 16 + fr][fq * 8];
#pragma unroll
    for (int m = 0; m < 2; ++m)
#pragma unroll
      for (int n = 0; n < 4; ++n)
        acc[m][n] =
            __builtin_amdgcn_mfma_f32_16x16x32_bf16(af[m], bq[n], acc[m][n], 0, 0, 0);
    if (!last) {
      WRITEA(cur ^ 1);              // va holds k0+32 data (issued 1 iter ago)
      if (k0 + 64 < K) LOADA(k0 + 64);  // in flight across sync + next MFMA
    }
    __syncthreads();
    cur ^= 1;
  }
#undef LOADA
#undef WRITEA
#undef STAGEB
#pragma unroll
  for (int m = 0; m < 2; ++m) {
#pragma unroll
    for (int n = 0; n < 4; ++n) {
#pragma unroll
      for (int j = 0; j < 4; ++j) {
        int gm = bm + wr + m * 16 + fq * 4 + j;
        int gn = wc + n * 16 + fr;
        if (gm < NN) {
          __bf16 c = (__bf16)(acc[m][n][j] + bias[gn]);
          C[(size_t)gm * 128 + gn] = c;
          C[(size_t)(gm + MP) * 128 + gn] = c;
        }
      }
    }
  }
}

// ---------------- fused layer MLP: lin1+LN+relu (LDS) -> lin2+res+LN -------
template <int MODE>
__global__ __launch_bounds__(256) void gemm_layer(
    const __bf16* __restrict__ A, const __bf16* __restrict__ W1T,
    const float* __restrict__ b1, const float* __restrict__ g1,
    const float* __restrict__ be1, const __bf16* __restrict__ W2T,
    const float* __restrict__ b2, float* __restrict__ xres,
    const float* __restrict__ dgv, const float* __restrict__ dbv,
    void* __restrict__ lnout) {
  __shared__ char smem[40960];
  __shared__ __bf16 h1[64][264];
  __shared__ float redS[64][2], redS2[64][2];
  auto As = (__bf16(*)[64][32])smem;
  auto Bs1 = (__bf16(*)[256][32])(smem + 8192);
  auto Bs2 = (__bf16(*)[128][32])smem;
  const int tid = threadIdx.x;
  const int lane = tid & 63, w = tid >> 6;
  const int bm = blockIdx.x * 64;
  const int fr = lane & 15, fq = lane >> 4;
  const int rowA = tid >> 2, chA = (tid & 3) * 8;

  // ---------- phase 1: 64x256, K=128 ----------
  {
    const int wr = w * 16;
    const __bf16* Ab = A + (size_t)(bm + rowA) * 128 + chA;
    const __bf16* Bb = W1T + (size_t)rowA * 128 + chA;
    f32x4 acc[16] = {};
#define STG1(buf, k0)                                                 \
  do {                                                                \
    gload_lds16(Ab + (k0), &As[buf][rowA][chA]);                      \
    _Pragma("unroll") for (int r = 0; r < 4; ++r)                     \
        gload_lds16(Bb + (size_t)(r * 64) * 128 + (k0),               \
                    &Bs1[buf][rowA + r * 64][chA]);                   \
  } while (0)
    STG1(0, 0);
    __syncthreads();
    int cur = 0;
    for (int k0 = 0; k0 < 128; k0 += 32) {
      if (k0 + 32 < 128) STG1(cur ^ 1, k0 + 32);
      bf16x8 af = *(const bf16x8*)&As[cur][wr + fr][fq * 8];
#pragma unroll
      for (int n = 0; n < 16; ++n) {
        bf16x8 bq = *(const bf16x8*)&Bs1[cur][n * 16 + fr][fq * 8];
        acc[n] = __builtin_amdgcn_mfma_f32_16x16x32_bf16(af, bq, acc[n], 0, 0, 0);
      }
      __syncthreads();
      cur ^= 1;
    }
#undef STG1
    float cb[16], gv[16], bev[16];
#pragma unroll
    for (int n = 0; n < 16; ++n) {
      int col = n * 16 + fr;
      cb[n] = b1[col]; gv[n] = g1[col]; bev[n] = be1[col];
    }
#pragma unroll
    for (int j = 0; j < 4; ++j) {
      float cj[16], s = 0.f, s2 = 0.f;
#pragma unroll
      for (int n = 0; n < 16; ++n) {
        float c = acc[n][j] + cb[n];
        cj[n] = c; s += c; s2 += c * c;
      }
      s = red16(s); s2 = red16(s2);
      float mu = s * (1.f / 256);
      float var = fmaxf(s2 * (1.f / 256) - mu * mu, 0.f);
      float rr = rsqrtf(var + 1e-5f);
      int r = wr + fq * 4 + j;
#pragma unroll
      for (int n = 0; n < 16; ++n) {
        float y = (cj[n] - mu) * rr * gv[n] + bev[n];
        h1[r][n * 16 + fr] = (__bf16)fmaxf(y, 0.f);
      }
    }
  }
  __syncthreads();

  // ---------- phase 2: 64x128, K=256, A from h1 (LDS) ----------
  {
    const int wr = (w >> 1) * 32, wc = (w & 1) * 64;
    const __bf16* Bb = W2T + (size_t)rowA * 256 + chA;
    const __bf16* Bb2 = Bb + (size_t)64 * 256;
    f32x4 acc[2][4] = {};
#define STG2(buf, k0)                                   \
  do {                                                  \
    gload_lds16(Bb + (k0), &Bs2[buf][rowA][chA]);       \
    gload_lds16(Bb2 + (k0), &Bs2[buf][rowA + 64][chA]); \
  } while (0)
    STG2(0, 0);
    __syncthreads();
    int cur = 0;
    for (int k0 = 0; k0 < 256; k0 += 32) {
      if (k0 + 32 < 256) STG2(cur ^ 1, k0 + 32);
      bf16x8 af[2], bq[4];
#pragma unroll
      for (int m = 0; m < 2; ++m)
        af[m] = *(const bf16x8*)&h1[wr + m * 16 + fr][k0 + fq * 8];
#pragma unroll
      for (int n = 0; n < 4; ++n)
        bq[n] = *(const bf16x8*)&Bs2[cur][wc + n * 16 + fr][fq * 8];
#pragma unroll
      for (int m = 0; m < 2; ++m)
#pragma unroll
        for (int n = 0; n < 4; ++n)
          acc[m][n] =
              __builtin_amdgcn_mfma_f32_16x16x32_bf16(af[m], bq[n], acc[m][n], 0, 0, 0);
      __syncthreads();
      cur ^= 1;
    }
#undef STG2

    float cv[2][4][4];
#pragma unroll
    for (int m = 0; m < 2; ++m) {
      int r0 = wr + m * 16 + fq * 4;
#pragma unroll
      for (int j = 0; j < 4; ++j) {
        int gm = bm + r0 + j;
        float s = 0.f, s2 = 0.f;
#pragma unroll
        for (int n = 0; n < 4; ++n) {
          float c = acc[m][n][j] + b2[wc + n * 16 + fr];
          if (MODE != 0) c += xres[(size_t)gm * 128 + wc + n * 16 + fr];
          cv[m][n][j] = c;
          s += c; s2 += c * c;
        }
        s = red16(s); s2 = red16(s2);
        if (fr == 0) {
          redS[r0 + j][w & 1] = s;
          redS2[r0 + j][w & 1] = s2;
        }
      }
    }
    __syncthreads();
#pragma unroll
    for (int m = 0; m < 2; ++m) {
      int r0 = wr + m * 16 + fq * 4;
#pragma unroll
      for (int j = 0; j < 4; ++j) {
        int r = r0 + j;
        int gm = bm + r;
        float S = redS[r][0] + redS[r][1];
        float S2 = redS2[r][0] + redS2[r][1];
        float mu = S * (1.f / 128);
        float var = fmaxf(S2 * (1.f / 128) - mu * mu, 0.f);
        float rr = rsqrtf(var + 1e-5f);
        if constexpr (MODE < 2) {
          float* xp = xres + (size_t)gm * 128;
          __bf16* hp = (__bf16*)lnout + (size_t)gm * 128;
#pragma unroll
          for (int n = 0; n < 4; ++n) {
            int col = wc + n * 16 + fr;
            float c = cv[m][n][j];
            xp[col] = c;
            float y = (c - mu) * rr * dgv[col] + dbv[col];
            hp[col] = (__bf16)fmaxf(y, 0.f);
          }
        } else {
          int half = gm >= MP;
          int node = gm - half * MP;
          if (node < NN) {
            float* ep = (float*)lnout + (size_t)node * 256 + half * 128;
#pragma unroll
            for (int n = 0; n < 4; ++n) {
              int col = wc + n * 16 + fr;
              float y = (cv[m][n][j] - mu) * rr * dgv[col] + dbv[col];
              ep[col] = fmaxf(y, 0.f);
            }
          }
        }
      }
    }
  }
}

// ---------------- prologue: weight transpose-convert + degree count --------
struct WtDesc { const float* src; __bf16* dst; int K, N, Kpad, gbase; };
struct WtDescs { WtDesc d[10]; };
#define WTG 50176    // sum(N*Kpad)/8
#define CTG 80000    // 2*EE / 8

__global__ __launch_bounds__(256) void prep_kernel(
    WtDescs descs, const int* __restrict__ edge_index, int* __restrict__ deg,
    float* __restrict__ gp_sum) {
  const int tid = threadIdx.x;
  if (blockIdx.x == 0) gp_sum[tid] = 0.f;
  int g = blockIdx.x * 256 + tid;
  if (g >= WTG + CTG) return;
  if (g < WTG) {
    int wb = g;
    int di = 0;
#pragma unroll
    for (int t = 1; t < 10; ++t)
      if (wb >= descs.d[t].gbase) di = t;
    WtDesc de = descs.d[di];
    int local = wb - de.gbase;
    int kg8 = de.Kpad >> 3;
    int n = local / kg8, k0 = (local - n * kg8) * 8;
    bf16x8 o;
#pragma unroll
    for (int i = 0; i < 8; ++i) {
      int k = k0 + i;
      o[i] = (__bf16)((k < de.K) ? de.src[(size_t)k * de.N + n] : 0.f);
    }
    *(bf16x8*)(de.dst + (size_t)n * de.Kpad + k0) = o;
  } else {
    int i0 = (g - WTG) * 8;
    int ti = (i0 >= EE) ? 1 : 0;
    int e0 = i0 - ti * EE;
    int dst8[8];
    __builtin_memcpy(dst8, edge_index + (size_t)ti * 2 * EE + EE + e0, 32);
    int* dbase = deg + ti * NN;
#pragma unroll
    for (int j = 0; j < 8; ++j) atomicAdd(&dbase[dst8[j]], 1);
  }
}

// ---------------- CSR scan (block per ti) ----------------
__global__ __launch_bounds__(1024) void scan2_kernel(
    const int* __restrict__ deg_all, int* __restrict__ rowptr,
    int* __restrict__ cursor) {
  const int ti = blockIdx.x;
  const int* deg = deg_all + ti * NN;
  __shared__ int sums[1024];
  int tid = threadIdx.x;
  int chunk = (NN + 1023) / 1024;
  int begin = tid * chunk, end = min(begin + chunk, NN);
  int s = 0;
  for (int i = begin; i < end; ++i) s += deg[i];
  sums[tid] = s;
  __syncthreads();
  for (int off = 1; off < 1024; off <<= 1) {
    int v = (tid >= off) ? sums[tid - off] : 0;
    __syncthreads();
    sums[tid] += v;
    __syncthreads();
  }
  int running = ti * EE + sums[tid] - s;
  for (int i = begin; i < end; ++i) {
    rowptr[ti * NN + i] = running;
    cursor[ti * NN + i] = running;
    running += deg[i];
  }
  if (tid == 0 && ti == 1) rowptr[2 * NN] = 2 * EE;
}

// ---------------- GENConv softmax aggregation + residual -------------------
// 4 nodes/wave (quarter-wave per node), serial edge walk with 4-edge unroll
// (4 gathers in flight). Channels lane-owned. XCD quadrant pinning via b&7.
__global__ __launch_bounds__(256) void agg_kernel(
    const __bf16* __restrict__ xin, const int* __restrict__ rowptr,
    const Edge* __restrict__ edges, const float* __restrict__ Wee,
    const float* __restrict__ bee, const float* __restrict__ tptr, int layer,
    __bf16* __restrict__ out) {
  int wave = threadIdx.x >> 6, lane = threadIdx.x & 63;
  int b = blockIdx.x;  // 625 * 8 blocks
  int x8 = b & 7;
  int q = x8 >> 1;
  int par = x8 & 1;
  int ti = q >> 1, chh = q & 1;
  int group = (b >> 3) * 2 + par;
  int qq = lane >> 4, c15 = lane & 15;
  int node = group * 16 + wave * 4 + qq;
  int gnode = ti * NN + node;
  int xrow = ti * MP + node;
  float t2 = tptr[layer] * 1.4426950408889634f;
  int c0 = chh * 64 + c15 * 4;
  float den[4] = {}, num[4] = {};
  int e = rowptr[gnode];
  const int e1 = rowptr[gnode + 1];

  if (t2 > 0.f) {
    float w0p[4], w1p[4], bvp[4];
#pragma unroll
    for (int i = 0; i < 4; ++i) {
      w0p[i] = Wee[c0 + i] * t2;
      w1p[i] = Wee[HH + c0 + i] * t2;
      bvp[i] = bee[c0 + i] * t2;
    }
#define MLPF(XV, ED)                                                      \
  do {                                                                    \
    float eax = (float)(ED).ea0, eay = (float)(ED).ea1;                   \
    _Pragma("unroll") for (int i = 0; i < 4; ++i) {                       \
      float te = fmaf(eax, w0p[i], fmaf(eay, w1p[i], bvp[i]));            \
      float sm = fmaxf(fmaf((float)(XV)[i], t2, te), 0.f);                \
      float ex = fexp2(sm);                                               \
      den[i] += ex; num[i] = fmaf(sm, ex, num[i]);                        \
    }                                                                     \
  } while (0)
    for (; e + 4 <= e1; e += 4) {
      Edge E0 = edges[e], E1 = edges[e + 1];
      Edge E2 = edges[e + 2], E3 = edges[e + 3];
      bf16x4 x0 = *(const bf16x4*)(xin + (size_t)E0.src * HH + c0);
      bf16x4 x1 = *(const bf16x4*)(xin + (size_t)E1.src * HH + c0);
      bf16x4 x2 = *(const bf16x4*)(xin + (size_t)E2.src * HH + c0);
      bf16x4 x3 = *(const bf16x4*)(xin + (size_t)E3.src * HH + c0);
      MLPF(x0, E0); MLPF(x1, E1); MLPF(x2, E2); MLPF(x3, E3);
    }
    for (; e < e1; ++e) {
      Edge E0 = edges[e];
      bf16x4 x0 = *(const bf16x4*)(xin + (size_t)E0.src * HH + c0);
      MLPF(x0, E0);
    }
#undef MLPF
    bf16x4 xr = *(const bf16x4*)(xin + (size_t)xrow * HH + c0);
    bf16x4 o;
#pragma unroll
    for (int i = 0; i < 4; ++i)
      o[i] = (__bf16)(num[i] / (t2 * (den[i] + 1e-16f)) + (float)xr[i]);
    *(bf16x4*)(out + (size_t)xrow * HH + c0) = o;
  } else {
    float w0[4], w1[4], bv[4];
#pragma unroll
    for (int i = 0; i < 4; ++i) {
      w0[i] = Wee[c0 + i];
      w1[i] = Wee[HH + c0 + i];
      bv[i] = bee[c0 + i];
    }
    for (; e < e1; ++e) {
      Edge E0 = edges[e];
      bf16x4 xv = *(const bf16x4*)(xin + (size_t)E0.src * HH + c0);
      float eax = (float)E0.ea0, eay = (float)E0.ea1;
#pragma unroll
      for (int i = 0; i < 4; ++i) {
        float m =
            fmaxf((float)xv[i] + eax * w0[i] + eay * w1[i] + bv[i], 0.f) + 1e-7f;
        float ex = fexp2(m * t2);
        den[i] += ex; num[i] += m * ex;
      }
    }
    bf16x4 xr = *(const bf16x4*)(xin + (size_t)xrow * HH + c0);
    bf16x4 o;
#pragma unroll
    for (int i = 0; i < 4; ++i)
      o[i] = (__bf16)(num[i] / (den[i] + 1e-16f) + (float)xr[i]);
    *(bf16x4*)(out + (size_t)xrow * HH + c0) = o;
  }
}

// ---------------- fused attention + node head (+ graph partials) -----------
// Block owns 64 rows. Phase A: both attentions for its nodes; node branch ->
// LDS h1 (bf16), graph branch -> per-block partial. Phase B: head GEMM
// (K=256, A from LDS) + Wn2 projection + log_softmax.
__global__ __launch_bounds__(256) void attn_head_kernel(
    const float* __restrict__ emb, const float* __restrict__ Wq_n,
    const float* __restrict__ Wk_n, const float* __restrict__ Wv_n,
    const float* __restrict__ gn, const float* __restrict__ Wq_g,
    const float* __restrict__ Wk_g, const float* __restrict__ Wv_g,
    const float* __restrict__ gg, const __bf16* __restrict__ WTn1,
    const float* __restrict__ bn1, const float* __restrict__ Wn2,
    const float* __restrict__ b2h, float* __restrict__ outf,
    float* __restrict__ partial) {
  __shared__ __bf16 h1[64][264];
  __shared__ __bf16 Bs[2][256][32];
  __shared__ float gsum[4][256];
  const int tid = threadIdx.x;
  const int lane = tid & 63, wave = tid >> 6;
  const int bm = blockIdx.x * 64;
  const int c0 = lane * 2;
  float ag0 = 0.f, ag1 = 0.f, ag2 = 0.f, ag3 = 0.f;  // graph partial acc

#define ATTN_BODY(Wq, Wk, Wv, GAM, O0A, O0B, O1A, O1B)                        \
  {                                                                           \
    float gamma = *(GAM);                                                     \
    float wq00 = Wq[0], wq01 = Wq[1], wq10 = Wq[2], wq11 = Wq[3];             \
    float wk00 = Wk[0], wk01 = Wk[1], wk10 = Wk[2], wk11 = Wk[3];             \
    float wv00 = Wv[0], wv01 = Wv[1], wv10 = Wv[2], wv11 = Wv[3];             \
    float q0a = wq00 * x0.x + wq01 * x1.x, q0b = wq00 * x0.y + wq01 * x1.y;   \
    float q1a = wq10 * x0.x + wq11 * x1.x, q1b = wq10 * x0.y + wq11 * x1.y;   \
    float k0a = wk00 * x0.x + wk01 * x1.x, k0b = wk00 * x0.y + wk01 * x1.y;   \
    float k1a = wk10 * x0.x + wk11 * x1.x, k1b = wk10 * x0.y + wk11 * x1.y;   \
    float v0a = wv00 * x0.x + wv01 * x1.x, v0b = wv00 * x0.y + wv01 * x1.y;   \
    float v1a = wv10 * x0.x + wv11 * x1.x, v1b = wv10 * x0.y + wv11 * x1.y;   \
    float s00 = wave_sum(q0a * k0a + q0b * k0b);                              \
    float s01 = wave_sum(q0a * k1a + q0b * k1b);                              \
    float s10 = wave_sum(q1a * k0a + q1b * k0b);                              \
    float s11 = wave_sum(q1a * k1a + q1b * k1b);                              \
    float m0 = fmaxf(s00, s01);                                               \
    float e00 = __expf(s00 - m0), e01 = __expf(s01 - m0);                     \
    float i0 = 1.f / (e00 + e01);                                             \
    float a00 = e00 * i0, a01 = e01 * i0;                                     \
    float m1 = fmaxf(s10, s11);                                               \
    float e10 = __expf(s10 - m1), e11 = __expf(s11 - m1);                     \
    float i1 = 1.f / (e10 + e11);                                             \
    float a10 = e10 * i1, a11 = e11 * i1;                                     \
    O0A = gamma * (a00 * v0a + a01 * v1a) + x0.x;                             \
    O0B = gamma * (a00 * v0b + a01 * v1b) + x0.y;                             \
    O1A = gamma * (a10 * v0a + a11 * v1a) + x1.x;                             \
    O1B = gamma * (a10 * v0b + a11 * v1b) + x1.y;                             \
  }

  // ---------- phase A: attention for 64 rows (wave i-loop) ----------
  for (int i = wave; i < 64; i += 4) {
    int n = bm + i;
    if (n < NN) {
      const float* base = emb + (size_t)n * 256;
      float2 x0 = *(const float2*)(base + c0);
      float2 x1 = *(const float2*)(base + 128 + c0);
      float n0a, n0b, n1a, n1b;
      ATTN_BODY(Wq_n, Wk_n, Wv_n, gn, n0a, n0b, n1a, n1b);
      h1[i][c0] = (__bf16)n0a;
      h1[i][c0 + 1] = (__bf16)n0b;
      h1[i][128 + c0] = (__bf16)n1a;
      h1[i][129 + c0] = (__bf16)n1b;
      float g0a, g0b, g1a, g1b;
      ATTN_BODY(Wq_g, Wk_g, Wv_g, gg, g0a, g0b, g1a, g1b);
      ag0 += g0a; ag1 += g0b; ag2 += g1a; ag3 += g1b;
    } else {
      h1[i][c0] = (__bf16)0.f;
      h1[i][c0 + 1] = (__bf16)0.f;
      h1[i][128 + c0] = (__bf16)0.f;
      h1[i][129 + c0] = (__bf16)0.f;
    }
  }
#undef ATTN_BODY
  gsum[wave][c0] = ag0;
  gsum[wave][c0 + 1] = ag1;
  gsum[wave][128 + c0] = ag2;
  gsum[wave][129 + c0] = ag3;
  __syncthreads();
  partial[(size_t)blockIdx.x * 256 + tid] =
      gsum[0][tid] + gsum[1][tid] + gsum[2][tid] + gsum[3][tid];

  // ---------- phase B: head GEMM 64x256, K=256, A from h1 ----------
  const int fr = lane & 15, fq = lane >> 4;
  const int wr = wave * 16;
  const int rowA = tid >> 2, chA = (tid & 3) * 8;
  const __bf16* Bb = WTn1 + (size_t)rowA * 256 + chA;
  f32x4 acc[16] = {};
#define STGH(buf, k0)                                                \
  do {                                                               \
    _Pragma("unroll") for (int r = 0; r < 4; ++r)                    \
        gload_lds16(Bb + (size_t)(r * 64) * 256 + (k0),              \
                    &Bs[buf][rowA + r * 64][chA]);                   \
  } while (0)
  STGH(0, 0);
  __syncthreads();
  int cur = 0;
  for (int k0 = 0; k0 < 256; k0 += 32) {
    if (k0 + 32 < 256) STGH(cur ^ 1, k0 + 32);
    bf16x8 af = *(const bf16x8*)&h1[wr + fr][k0 + fq * 8];
#pragma unroll
    for (int n = 0; n < 16; ++n) {
      bf16x8 bq = *(const bf16x8*)&Bs[cur][n * 16 + fr][fq * 8];
      acc[n] = __builtin_amdgcn_mfma_f32_16x16x32_bf16(af, bq, acc[n], 0, 0, 0);
    }
    __syncthreads();
    cur ^= 1;
  }
#undef STGH
  float cb[16], w0[16], w1[16], w2[16];
#pragma unroll
  for (int n = 0; n < 16; ++n) {
    int col = n * 16 + fr;
    cb[n] = bn1[col];
    w0[n] = Wn2[col * 3 + 0];
    w1[n] = Wn2[col * 3 + 1];
    w2[n] = Wn2[col * 3 + 2];
  }
#pragma unroll
  for (int j = 0; j < 4; ++j) {
    float p0 = 0.f, p1 = 0.f, p2 = 0.f;
#pragma unroll
    for (int n = 0; n < 16; ++n) {
      float h = fmaxf(acc[n][j] + cb[n], 0.f);
      p0 += h * w0[n]; p1 += h * w1[n]; p2 += h * w2[n];
    }
    p0 = red16(p0); p1 = red16(p1); p2 = red16(p2);
    int gm = bm + wr + fq * 4 + j;
    if (fr == 0 && gm < NN) {
      float l0 = p0 + b2h[0], l1 = p1 + b2h[1], l2 = p2 + b2h[2];
      float m = fmaxf(l0, fmaxf(l1, l2));
      float lse = m + logf(__expf(l0 - m) + __expf(l1 - m) + __expf(l2 - m));
      outf[(size_t)gm * 3 + 0] = l0 - lse;
      outf[(size_t)gm * 3 + 1] = l1 - lse;
      outf[(size_t)gm * 3 + 2] = l2 - lse;
    }
  }
}

// ---------------- pool over per-block partials ----------------
__global__ __launch_bounds__(256) void pool_kernel(const float* __restrict__ partial,
                                                   float* __restrict__ gp_sum,
                                                   int nRows) {
  int c = threadIdx.x;
  float s = 0.f;
  for (int r = blockIdx.x; r < nRows; r += gridDim.x)
    s += partial[(size_t)r * 256 + c];
  atomicAdd(&gp_sum[c], s);
}

// ---------------- graph head (single block) ----------------
__global__ __launch_bounds__(256) void graph_head_kernel(
    const float* __restrict__ gp_sum, const float* __restrict__ Wg1,
    const float* __restrict__ bg1, const float* __restrict__ Wg2,
    const float* __restrict__ bg2, float* __restrict__ outp, float invN) {
  __shared__ float gp[256];
  __shared__ float h1[256];
  __shared__ float lg[2];
  int tid = threadIdx.x;
  gp[tid] = gp_sum[tid] * invN;
  __syncthreads();
  float acc = bg1[tid];
  for (int k = 0; k < 256; ++k) acc += gp[k] * Wg1[k * 256 + tid];
  h1[tid] = fmaxf(acc, 0.f);
  __syncthreads();
  if (tid < 2) {
    float l = bg2[tid];
    for (int c = 0; c < 256; ++c) l += h1[c] * Wg2[c * 2 + tid];
    lg[tid] = l;
  }
  __syncthreads();
  if (tid == 0) {
    float m = fmaxf(lg[0], lg[1]);
    float lse = m + logf(__expf(lg[0] - m) + __expf(lg[1] - m));
    outp[0] = lg[0] - lse;
    outp[1] = lg[1] - lse;
  }
}

// ---------------- launch ----------------
extern "C" void kernel_launch(void* const* d_in, const int* in_sizes, int n_in,
                              void* d_out, int out_size, void* d_ws, size_t ws_size,
                              hipStream_t stream) {
  (void)in_sizes; (void)n_in; (void)out_size; (void)ws_size;
  const float* node_feature = (const float*)d_in[0];
  const int* edge_index = (const int*)d_in[1];
  const float* edge_attr = (const float*)d_in[2];
  const float* Wne = (const float*)d_in[3];
  const float* bne = (const float*)d_in[4];
  const float* Wee = (const float*)d_in[5];
  const float* bee = (const float*)d_in[6];
  const float* W1 = (const float*)d_in[7];
  const float* b1 = (const float*)d_in[8];
  const float* g1 = (const float*)d_in[9];
  const float* be1 = (const float*)d_in[10];
  const float* W2 = (const float*)d_in[11];
  const float* b2 = (const float*)d_in[12];
  const float* dg = (const float*)d_in[13];
  const float* db = (const float*)d_in[14];
  const float* tpar = (const float*)d_in[15];
  const float* Wq_n = (const float*)d_in[16];
  const float* Wk_n = (const float*)d_in[17];
  const float* Wv_n = (const float*)d_in[18];
  const float* gamma_n = (const float*)d_in[19];
  const float* Wn1 = (const float*)d_in[20];
  const float* bn1 = (const float*)d_in[21];
  const float* Wn2 = (const float*)d_in[22];
  const float* bn2 = (const float*)d_in[23];
  const float* Wq_g = (const float*)d_in[24];
  const float* Wk_g = (const float*)d_in[25];
  const float* Wv_g = (const float*)d_in[26];
  const float* gamma_g = (const float*)d_in[27];
  const float* Wg1 = (const float*)d_in[28];
  const float* bg1 = (const float*)d_in[29];
  const float* Wg2 = (const float*)d_in[30];
  const float* bg2 = (const float*)d_in[31];
  float* out = (float*)d_out;

  // ---- workspace carve-out (256B-aligned regions) ----
  char* pc = (char*)d_ws;
  auto alloc = [&](size_t bytes) {
    char* r = pc;
    pc += (bytes + 255) & ~(size_t)255;
    return r;
  };
  float* xbuf = (float*)alloc((size_t)2 * MP * HH * 4);       // f32 residual
  __bf16* hbuf_b = (__bf16*)alloc((size_t)2 * MP * HH * 2);   // LN'd agg input
  float* emb = (float*)alloc((size_t)NN * 2 * HH * 4);        // [N,T,H] f32
  __bf16* aggout_b = (__bf16*)alloc((size_t)2 * MP * HH * 2); // agg out
  float* partial = xbuf;        // alias: graph-attn partials [314][256]
  __bf16* wt_ne = (__bf16*)alloc((size_t)128 * 576 * 2);
  __bf16* wt1 = (__bf16*)alloc((size_t)4 * 256 * 128 * 2);
  __bf16* wt2 = (__bf16*)alloc((size_t)4 * 128 * 256 * 2);
  __bf16* wtn1 = (__bf16*)alloc((size_t)256 * 256 * 2);
  float* gp_sum = (float*)alloc(256 * 4);
  int* deg = (int*)alloc((size_t)2 * NN * 4);
  int* cursor = (int*)alloc((size_t)2 * NN * 4);
  int* rowptr = (int*)alloc((size_t)(2 * NN + 2) * 4);
  Edge* edges = (Edge*)alloc((size_t)2 * EE * 8);

  const int gRows2 = 2 * MP / 64;  // 628 row-blocks, stacked layer kernel

  WtDescs wd;
  int gb = 0;
  wd.d[0] = {Wne, wt_ne, FF, HH, 576, gb}; gb += HH * 576 / 8;
  for (int l = 0; l < 4; ++l) {
    wd.d[1 + l] = {W1 + (size_t)l * HH * 256, wt1 + (size_t)l * 256 * HH, HH, 256,
                   HH, gb};
    gb += 256 * HH / 8;
  }
  for (int l = 0; l < 4; ++l) {
    wd.d[5 + l] = {W2 + (size_t)l * 256 * HH, wt2 + (size_t)l * HH * 256, 256, HH,
                   256, gb};
    gb += HH * 256 / 8;
  }
  wd.d[9] = {Wn1, wtn1, 256, 256, 256, gb};

  // prologue: deg zero; weight converts + degree count + gp_sum zero
  hipMemsetAsync(deg, 0, 2 * NN * sizeof(int), stream);
  prep_kernel<<<(WTG + CTG + 255) / 256, 256, 0, stream>>>(wd, edge_index, deg,
                                                           gp_sum);
  scan2_kernel<<<2, 1024, 0, stream>>>(deg, rowptr, cursor);
  // encoder GEMM (f32 A direct, dup to both halves) + XCD-routed edge scatter
  enc_scatter_kernel<<<ENCB + 8 * SSB, 256, 0, stream>>>(
      node_feature, wt_ne, bne, hbuf_b, edge_index, edge_attr, cursor, edges);

  // layer loop, both ti at once: agg + fused MLP (lin1+LN+relu | lin2+res+LN)
  for (int l = 0; l < LL; ++l) {
    agg_kernel<<<625 * 8, 256, 0, stream>>>(hbuf_b, rowptr, edges, Wee, bee, tpar,
                                            l, aggout_b);
    const __bf16* w1l = wt1 + (size_t)l * 256 * HH;
    const __bf16* w2l = wt2 + (size_t)l * HH * 256;
    if (l == 0)
      gemm_layer<0><<<gRows2, 256, 0, stream>>>(
          aggout_b, w1l, b1 + l * 2 * HH, g1 + l * 2 * HH, be1 + l * 2 * HH, w2l,
          b2 + l * HH, xbuf, dg + 1 * HH, db + 1 * HH, hbuf_b);
    else if (l < LL - 1)
      gemm_layer<1><<<gRows2, 256, 0, stream>>>(
          aggout_b, w1l, b1 + l * 2 * HH, g1 + l * 2 * HH, be1 + l * 2 * HH, w2l,
          b2 + l * HH, xbuf, dg + (l + 1) * HH, db + (l + 1) * HH, hbuf_b);
    else
      gemm_layer<2><<<gRows2, 256, 0, stream>>>(
          aggout_b, w1l, b1 + l * 2 * HH, g1 + l * 2 * HH, be1 + l * 2 * HH, w2l,
          b2 + l * HH, xbuf, dg, db, emb);
  }

  // fused attention + node head (+ graph partials in one pass)
  attn_head_kernel<<<MP / 64, 256, 0, stream>>>(
      emb, Wq_n, Wk_n, Wv_n, gamma_n, Wq_g, Wk_g, Wv_g, gamma_g, wtn1, bn1, Wn2,
      bn2, out, partial);
  // graph head
  pool_kernel<<<128, 256, 0, stream>>>(partial, gp_sum, MP / 64);
  graph_head_kernel<<<1, 256, 0, stream>>>(gp_sum, Wg1, bg1, Wg2, bg2,
                                           out + (size_t)NN * CN, 1.0f / NN);
}